// Round 1
// baseline (544.269 us; speedup 1.0000x reference)
//
#include <hip/hip_runtime.h>
#include <hip/hip_bf16.h>
#include <math.h>

#define N_NODES 50000
#define N_EDGES 800000
#define E_TOT   (N_EDGES + N_NODES)   /* 850000 with self loops */
#define HEADS 8
#define NCLS 10
#define NGRP 128

// ---------------------------------------------------------------------------
// GEMM1: h1 = x @ W1   (M=50000, K=256, N=256) fp32 vector ALU
// ---------------------------------------------------------------------------
#define BM 64
#define BN 64
#define BK 16

__global__ __launch_bounds__(256) void gemm1_kernel(const float* __restrict__ A,
                                                    const float* __restrict__ B,
                                                    float* __restrict__ C, int M) {
  __shared__ float As[BK][BM + 4];
  __shared__ float Bs[BK][BN + 4];
  int tid = threadIdx.x;
  int tx = tid & 15, ty = tid >> 4;
  int row0 = blockIdx.x * BM, col0 = blockIdx.y * BN;
  float acc[4][4] = {};
  for (int k0 = 0; k0 < 256; k0 += BK) {
    {
      int ar = tid >> 2;         // 0..63
      int ac4 = tid & 3;         // 0..3
      int row = row0 + ar;
      float4 v = make_float4(0.f, 0.f, 0.f, 0.f);
      if (row < M) v = *reinterpret_cast<const float4*>(&A[row * 256 + k0 + ac4 * 4]);
      As[ac4 * 4 + 0][ar] = v.x;
      As[ac4 * 4 + 1][ar] = v.y;
      As[ac4 * 4 + 2][ar] = v.z;
      As[ac4 * 4 + 3][ar] = v.w;
    }
    {
      int br = tid >> 4;         // 0..15
      int bc4 = tid & 15;        // 0..15
      float4 v = *reinterpret_cast<const float4*>(&B[(k0 + br) * 256 + col0 + bc4 * 4]);
      *reinterpret_cast<float4*>(&Bs[br][bc4 * 4]) = v;
    }
    __syncthreads();
#pragma unroll
    for (int kk = 0; kk < BK; ++kk) {
      float4 a = *reinterpret_cast<const float4*>(&As[kk][ty * 4]);
      float4 b = *reinterpret_cast<const float4*>(&Bs[kk][tx * 4]);
      float av[4] = {a.x, a.y, a.z, a.w};
      float bv[4] = {b.x, b.y, b.z, b.w};
#pragma unroll
      for (int i = 0; i < 4; ++i)
#pragma unroll
        for (int j = 0; j < 4; ++j) acc[i][j] += av[i] * bv[j];
    }
    __syncthreads();
  }
#pragma unroll
  for (int i = 0; i < 4; ++i) {
    int row = row0 + ty * 4 + i;
    if (row < M) {
      float4 v = make_float4(acc[i][0], acc[i][1], acc[i][2], acc[i][3]);
      *reinterpret_cast<float4*>(&C[row * 256 + col0 + tx * 4]) = v;
    }
  }
}

// ---------------------------------------------------------------------------
// attention coefficients layer 1: as1[n,h] = sum_c h1[n,h,c]*a_src[h,c]
// one wave per node; lane -> (head = lane>>3, channels (lane&7)*4 .. +3)
// ---------------------------------------------------------------------------
__global__ __launch_bounds__(256) void attn1_kernel(const float4* __restrict__ h1v,
                                                    const float* __restrict__ a_src,
                                                    const float* __restrict__ a_dst,
                                                    float* __restrict__ as1,
                                                    float* __restrict__ ad1) {
  int n = (blockIdx.x * 256 + threadIdx.x) >> 6;
  int lane = threadIdx.x & 63;
  float4 hv = h1v[n * 64 + lane];
  int h = lane >> 3;
  int cb = (lane & 7) * 4;
  const float* sr = a_src + h * 32 + cb;
  const float* dr = a_dst + h * 32 + cb;
  float ps = hv.x * sr[0] + hv.y * sr[1] + hv.z * sr[2] + hv.w * sr[3];
  float pd = hv.x * dr[0] + hv.y * dr[1] + hv.z * dr[2] + hv.w * dr[3];
  ps += __shfl_xor(ps, 1); ps += __shfl_xor(ps, 2); ps += __shfl_xor(ps, 4);
  pd += __shfl_xor(pd, 1); pd += __shfl_xor(pd, 2); pd += __shfl_xor(pd, 4);
  if ((lane & 7) == 0) {
    as1[n * 8 + h] = ps;
    ad1[n * 8 + h] = pd;
  }
}

// ---------------------------------------------------------------------------
// CSR build (by destination)
// ---------------------------------------------------------------------------
__global__ __launch_bounds__(256) void deg_count_kernel(const int* __restrict__ ei,
                                                        int* __restrict__ deg) {
  int i = blockIdx.x * 256 + threadIdx.x;
  if (i < E_TOT) {
    int d = (i < N_EDGES) ? ei[N_EDGES + i] : (i - N_EDGES);
    atomicAdd(&deg[d], 1);
  }
}

__global__ __launch_bounds__(256) void scan_block_kernel(const int* __restrict__ deg,
                                                         int* __restrict__ off,
                                                         int* __restrict__ bsum) {
  __shared__ int sh[256];
  int tid = threadIdx.x;
  int i = blockIdx.x * 256 + tid;
  int v = (i < N_NODES) ? deg[i] : 0;
  sh[tid] = v;
  __syncthreads();
  for (int d = 1; d < 256; d <<= 1) {
    int t = (tid >= d) ? sh[tid - d] : 0;
    __syncthreads();
    sh[tid] += t;
    __syncthreads();
  }
  if (i < N_NODES) off[i] = sh[tid] - v;
  if (tid == 255) bsum[blockIdx.x] = sh[255];
}

__global__ __launch_bounds__(256) void scan_top_kernel(int* __restrict__ bsum, int NB) {
  __shared__ int sh[256];
  int tid = threadIdx.x;
  int v = (tid < NB) ? bsum[tid] : 0;
  sh[tid] = v;
  __syncthreads();
  for (int d = 1; d < 256; d <<= 1) {
    int t = (tid >= d) ? sh[tid - d] : 0;
    __syncthreads();
    sh[tid] += t;
    __syncthreads();
  }
  bsum[tid] = sh[tid] - v;  // exclusive
}

__global__ __launch_bounds__(256) void scan_add_kernel(int* __restrict__ off,
                                                       const int* __restrict__ bsum,
                                                       int* __restrict__ cursor) {
  int i = blockIdx.x * 256 + threadIdx.x;
  if (i < N_NODES) {
    int v = off[i] + bsum[blockIdx.x];
    off[i] = v;
    cursor[i] = v;
  }
  if (i == 0) off[N_NODES] = E_TOT;
}

__global__ __launch_bounds__(256) void scatter_kernel(const int* __restrict__ ei,
                                                      int* __restrict__ cursor,
                                                      int* __restrict__ csr) {
  int i = blockIdx.x * 256 + threadIdx.x;
  if (i < E_TOT) {
    int s = (i < N_EDGES) ? ei[i] : (i - N_EDGES);
    int d = (i < N_EDGES) ? ei[N_EDGES + i] : (i - N_EDGES);
    int pos = atomicAdd(&cursor[d], 1);
    csr[pos] = s;
  }
}

// ---------------------------------------------------------------------------
// layer-1 aggregation + bias + elu  -> h2
// one wave per dst node; online softmax per head (8 lanes replicate state)
// ---------------------------------------------------------------------------
__global__ __launch_bounds__(256) void agg1_kernel(const float4* __restrict__ h1v,
                                                   const float* __restrict__ as1,
                                                   const float* __restrict__ ad1,
                                                   const int* __restrict__ off,
                                                   const int* __restrict__ csr,
                                                   const float* __restrict__ b1,
                                                   float4* __restrict__ h2v) {
  int n = (blockIdx.x * 256 + threadIdx.x) >> 6;
  int lane = threadIdx.x & 63;
  int h = lane >> 3;
  float ad = ad1[n * 8 + h];
  int p0 = off[n], p1 = off[n + 1];
  float m = -INFINITY, ssum = 0.f;
  float ax = 0.f, ay = 0.f, az = 0.f, aw = 0.f;
  for (int p = p0; p < p1; ++p) {
    int src = csr[p];
    float e = as1[src * 8 + h] + ad;
    e = e > 0.f ? e : 0.2f * e;
    if (e > m) {
      float r = __expf(m - e);
      ssum *= r; ax *= r; ay *= r; az *= r; aw *= r;
      m = e;
    }
    float w = __expf(e - m);
    ssum += w;
    float4 hv = h1v[src * 64 + lane];
    ax += w * hv.x; ay += w * hv.y; az += w * hv.z; aw += w * hv.w;
  }
  float inv = 1.f / ssum;
  float4 bias = reinterpret_cast<const float4*>(b1)[lane];
  float4 o;
  o.x = ax * inv + bias.x;
  o.y = ay * inv + bias.y;
  o.z = az * inv + bias.z;
  o.w = aw * inv + bias.w;
  o.x = o.x > 0.f ? o.x : __expf(o.x) - 1.f;
  o.y = o.y > 0.f ? o.y : __expf(o.y) - 1.f;
  o.z = o.z > 0.f ? o.z : __expf(o.z) - 1.f;
  o.w = o.w > 0.f ? o.w : __expf(o.w) - 1.f;
  h2v[n * 64 + lane] = o;
}

// ---------------------------------------------------------------------------
// layer-2 projection: proj2 = h2 @ W2 (K=256 -> 10), plus as2/ad2 scalars
// ---------------------------------------------------------------------------
__global__ __launch_bounds__(256) void proj2_kernel(const float4* __restrict__ h2v,
                                                    const float* __restrict__ W2,
                                                    const float* __restrict__ asrc2,
                                                    const float* __restrict__ adst2,
                                                    float* __restrict__ pj2,
                                                    float* __restrict__ as2,
                                                    float* __restrict__ ad2) {
  __shared__ float W2t[NCLS][260];
  for (int idx = threadIdx.x; idx < 256 * NCLS; idx += 256) {
    int k = idx / NCLS, c = idx % NCLS;
    W2t[c][k] = W2[idx];
  }
  __syncthreads();
  int n = (blockIdx.x * 256 + threadIdx.x) >> 6;
  int lane = threadIdx.x & 63;
  float4 hv = h2v[n * 64 + lane];
  float s[NCLS];
#pragma unroll
  for (int c = 0; c < NCLS; ++c) {
    float4 w = *reinterpret_cast<const float4*>(&W2t[c][lane * 4]);
    float p = hv.x * w.x + hv.y * w.y + hv.z * w.z + hv.w * w.w;
    p += __shfl_xor(p, 1); p += __shfl_xor(p, 2); p += __shfl_xor(p, 4);
    p += __shfl_xor(p, 8); p += __shfl_xor(p, 16); p += __shfl_xor(p, 32);
    s[c] = p;
  }
  if (lane == 0) {
    float vs = 0.f, vd = 0.f;
#pragma unroll
    for (int c = 0; c < NCLS; ++c) {
      pj2[n * NCLS + c] = s[c];
      vs += s[c] * asrc2[c];
      vd += s[c] * adst2[c];
    }
    as2[n] = vs;
    ad2[n] = vd;
  }
}

// ---------------------------------------------------------------------------
// layer-2 aggregation (H=1, C=10): wave per node, edges across lanes
// ---------------------------------------------------------------------------
__global__ __launch_bounds__(256) void agg2_kernel(const float* __restrict__ pj2,
                                                   const float* __restrict__ as2,
                                                   const float* __restrict__ ad2,
                                                   const int* __restrict__ off,
                                                   const int* __restrict__ csr,
                                                   const float* __restrict__ b2,
                                                   float* __restrict__ out2) {
  int n = (blockIdx.x * 256 + threadIdx.x) >> 6;
  int lane = threadIdx.x & 63;
  int p0 = off[n], p1 = off[n + 1];
  float ad = ad2[n];
  float m = -INFINITY;
  for (int p = p0 + lane; p < p1; p += 64) {
    float e = as2[csr[p]] + ad;
    e = e > 0.f ? e : 0.2f * e;
    m = fmaxf(m, e);
  }
  m = fmaxf(m, __shfl_xor(m, 1));
  m = fmaxf(m, __shfl_xor(m, 2));
  m = fmaxf(m, __shfl_xor(m, 4));
  m = fmaxf(m, __shfl_xor(m, 8));
  m = fmaxf(m, __shfl_xor(m, 16));
  m = fmaxf(m, __shfl_xor(m, 32));
  float ssum = 0.f;
  float acc[NCLS] = {};
  for (int p = p0 + lane; p < p1; p += 64) {
    int src = csr[p];
    float e = as2[src] + ad;
    e = e > 0.f ? e : 0.2f * e;
    float w = __expf(e - m);
    ssum += w;
    const float* pr = pj2 + src * NCLS;
#pragma unroll
    for (int c = 0; c < NCLS; ++c) acc[c] += w * pr[c];
  }
  ssum += __shfl_xor(ssum, 1); ssum += __shfl_xor(ssum, 2); ssum += __shfl_xor(ssum, 4);
  ssum += __shfl_xor(ssum, 8); ssum += __shfl_xor(ssum, 16); ssum += __shfl_xor(ssum, 32);
#pragma unroll
  for (int c = 0; c < NCLS; ++c) {
    acc[c] += __shfl_xor(acc[c], 1); acc[c] += __shfl_xor(acc[c], 2);
    acc[c] += __shfl_xor(acc[c], 4); acc[c] += __shfl_xor(acc[c], 8);
    acc[c] += __shfl_xor(acc[c], 16); acc[c] += __shfl_xor(acc[c], 32);
  }
  if (lane == 0) {
    float inv = 1.f / ssum;
#pragma unroll
    for (int c = 0; c < NCLS; ++c) out2[n * NCLS + c] = acc[c] * inv + b2[c];
  }
}

// ---------------------------------------------------------------------------
// global mean pool: batch is sorted -> binary-search range per graph
// ---------------------------------------------------------------------------
__global__ __launch_bounds__(256) void pool_kernel(const float* __restrict__ out2,
                                                   const int* __restrict__ batch,
                                                   float* __restrict__ outp) {
  __shared__ float red[256];
  int g = blockIdx.x;
  int lo = 0, hi = N_NODES;
  while (lo < hi) { int mid = (lo + hi) >> 1; if (batch[mid] < g) lo = mid + 1; else hi = mid; }
  int start = lo;
  hi = N_NODES;
  while (lo < hi) { int mid = (lo + hi) >> 1; if (batch[mid] < g + 1) lo = mid + 1; else hi = mid; }
  int end = lo;
  float loc[NCLS] = {};
  for (int nn = start + threadIdx.x; nn < end; nn += 256) {
#pragma unroll
    for (int c = 0; c < NCLS; ++c) loc[c] += out2[nn * NCLS + c];
  }
  float denom = fmaxf((float)(end - start), 1.f);
#pragma unroll
  for (int c = 0; c < NCLS; ++c) {
    red[threadIdx.x] = loc[c];
    __syncthreads();
    for (int s2 = 128; s2 > 0; s2 >>= 1) {
      if (threadIdx.x < s2) red[threadIdx.x] += red[threadIdx.x + s2];
      __syncthreads();
    }
    if (threadIdx.x == 0) outp[g * NCLS + c] = red[0] / denom;
    __syncthreads();
  }
}

// ---------------------------------------------------------------------------
extern "C" void kernel_launch(void* const* d_in, const int* in_sizes, int n_in,
                              void* d_out, int out_size, void* d_ws, size_t ws_size,
                              hipStream_t stream) {
  const float* x      = (const float*)d_in[0];
  const float* W1     = (const float*)d_in[1];
  const float* a_src1 = (const float*)d_in[2];
  const float* a_dst1 = (const float*)d_in[3];
  const float* b1     = (const float*)d_in[4];
  const float* W2     = (const float*)d_in[5];
  const float* a_src2 = (const float*)d_in[6];
  const float* a_dst2 = (const float*)d_in[7];
  const float* b2     = (const float*)d_in[8];
  const int*   ei     = (const int*)d_in[9];
  const int*   batch  = (const int*)d_in[10];

  char* ws = (char*)d_ws;
  size_t o = 0;
  auto alloc = [&](size_t bytes) {
    char* p = ws + o;
    o = (o + bytes + 255) & ~(size_t)255;
    return p;
  };
  float* h1   = (float*)alloc((size_t)N_NODES * 256 * 4);
  float* h2   = (float*)alloc((size_t)N_NODES * 256 * 4);
  float* as1  = (float*)alloc((size_t)N_NODES * 8 * 4);
  float* ad1  = (float*)alloc((size_t)N_NODES * 8 * 4);
  float* pj2  = (float*)alloc((size_t)N_NODES * NCLS * 4);
  float* as2  = (float*)alloc((size_t)N_NODES * 4);
  float* ad2  = (float*)alloc((size_t)N_NODES * 4);
  float* out2 = (float*)alloc((size_t)N_NODES * NCLS * 4);
  int*   deg  = (int*)alloc((size_t)N_NODES * 4);
  int*   off  = (int*)alloc((size_t)(N_NODES + 1) * 4);
  int*   cur  = (int*)alloc((size_t)N_NODES * 4);
  int*   csr  = (int*)alloc((size_t)E_TOT * 4);
  int*   bsum = (int*)alloc(256 * 4);

  hipMemsetAsync(deg, 0, (size_t)N_NODES * 4, stream);

  dim3 gg((N_NODES + BM - 1) / BM, 256 / BN);
  gemm1_kernel<<<gg, 256, 0, stream>>>(x, W1, h1, N_NODES);

  attn1_kernel<<<N_NODES / 4, 256, 0, stream>>>((const float4*)h1, a_src1, a_dst1, as1, ad1);

  int egrid = (E_TOT + 255) / 256;
  deg_count_kernel<<<egrid, 256, 0, stream>>>(ei, deg);
  int nb = (N_NODES + 255) / 256;  // 196
  scan_block_kernel<<<nb, 256, 0, stream>>>(deg, off, bsum);
  scan_top_kernel<<<1, 256, 0, stream>>>(bsum, nb);
  scan_add_kernel<<<nb, 256, 0, stream>>>(off, bsum, cur);
  scatter_kernel<<<egrid, 256, 0, stream>>>(ei, cur, csr);

  agg1_kernel<<<N_NODES / 4, 256, 0, stream>>>((const float4*)h1, as1, ad1, off, csr, b1,
                                               (float4*)h2);
  proj2_kernel<<<N_NODES / 4, 256, 0, stream>>>((const float4*)h2, W2, a_src2, a_dst2,
                                                pj2, as2, ad2);
  agg2_kernel<<<N_NODES / 4, 256, 0, stream>>>(pj2, as2, ad2, off, csr, b2, out2);
  pool_kernel<<<NGRP, 256, 0, stream>>>(out2, batch, (float*)d_out);
}

// Round 2
// 416.020 us; speedup vs baseline: 1.3083x; 1.3083x over previous
//
#include <hip/hip_runtime.h>
#include <hip/hip_bf16.h>
#include <math.h>

#define N_NODES 50000
#define N_EDGES 800000
#define E_TOT   (N_EDGES + N_NODES)   /* 850000 with self loops */
#define NCLS 10
#define NGRP 128

typedef __attribute__((ext_vector_type(8))) short bf16x8;
typedef __attribute__((ext_vector_type(4))) float f32x4;

static __device__ __forceinline__ ushort f2bf(float f) {
  union { float f; unsigned u; } v; v.f = f;
  unsigned r = v.u + 0x7fffu + ((v.u >> 16) & 1u);   // round-to-nearest-even
  return (ushort)(r >> 16);
}
static __device__ __forceinline__ float bf2f(ushort u) {
  union { unsigned u; float f; } v; v.u = ((unsigned)u) << 16; return v.f;
}
static __device__ __forceinline__ float bflo(unsigned u) {
  union { unsigned u; float f; } v; v.u = u << 16; return v.f;
}
static __device__ __forceinline__ float bfhi(unsigned u) {
  union { unsigned u; float f; } v; v.u = u & 0xffff0000u; return v.f;
}

// ---------------------------------------------------------------------------
// cast x (fp32) -> bf16
// ---------------------------------------------------------------------------
__global__ __launch_bounds__(256) void cast_x_kernel(const float4* __restrict__ X4,
                                                     ushort4* __restrict__ Xb) {
  int i = blockIdx.x * 256 + threadIdx.x;
  float4 v = X4[i];
  ushort4 o;
  o.x = f2bf(v.x); o.y = f2bf(v.y); o.z = f2bf(v.z); o.w = f2bf(v.w);
  Xb[i] = o;
}

// ---------------------------------------------------------------------------
// W1 [256][256] (k,n) fp32 -> W1t [n][k] bf16
// ---------------------------------------------------------------------------
__global__ __launch_bounds__(256) void w1t_kernel(const float* __restrict__ W1,
                                                  ushort* __restrict__ W1t) {
  __shared__ float t[32][33];
  int k0 = blockIdx.x * 32, n0 = blockIdx.y * 32;
  int tx = threadIdx.x & 31, ty = threadIdx.x >> 5;  // ty 0..7
  for (int r = 0; r < 32; r += 8)
    t[ty + r][tx] = W1[(k0 + ty + r) * 256 + n0 + tx];
  __syncthreads();
  for (int r = 0; r < 32; r += 8)
    W1t[(n0 + ty + r) * 256 + k0 + tx] = f2bf(t[tx][ty + r]);
}

// ---------------------------------------------------------------------------
// GEMM1 MFMA: h1 = x @ W1, M=50000, N=256, K=256, bf16 in, bf16 out
// block = 64 rows x full 256 cols; 4 waves, wave w -> cols [64w, 64w+64)
// fragments loaded directly from global (W1t is L2-resident, x-tile L1-shared)
// ---------------------------------------------------------------------------
__global__ __launch_bounds__(256) void gemm1_mfma(const ushort* __restrict__ Xb,
                                                  const ushort* __restrict__ W1t,
                                                  ushort* __restrict__ H1b) {
  int wid = threadIdx.x >> 6, lane = threadIdx.x & 63;
  int r = lane & 15, kg = lane >> 4;      // A-row/B-col in tile, k-group
  int m0 = blockIdx.x * 64;
  int n0 = wid * 64;
  f32x4 acc[4][4];
#pragma unroll
  for (int mi = 0; mi < 4; ++mi)
#pragma unroll
    for (int ni = 0; ni < 4; ++ni) acc[mi][ni] = 0;

  const ushort* aptr[4];
#pragma unroll
  for (int mi = 0; mi < 4; ++mi) {
    int row = m0 + mi * 16 + r;
    if (row >= N_NODES) row = 0;  // garbage rows never stored
    aptr[mi] = Xb + (size_t)row * 256 + kg * 8;
  }
  const ushort* bptr[4];
#pragma unroll
  for (int ni = 0; ni < 4; ++ni)
    bptr[ni] = W1t + (size_t)(n0 + ni * 16 + r) * 256 + kg * 8;

#pragma unroll 2
  for (int k0 = 0; k0 < 256; k0 += 32) {
    bf16x8 a[4], b[4];
#pragma unroll
    for (int mi = 0; mi < 4; ++mi)
      a[mi] = *reinterpret_cast<const bf16x8*>(aptr[mi] + k0);
#pragma unroll
    for (int ni = 0; ni < 4; ++ni)
      b[ni] = *reinterpret_cast<const bf16x8*>(bptr[ni] + k0);
#pragma unroll
    for (int mi = 0; mi < 4; ++mi)
#pragma unroll
      for (int ni = 0; ni < 4; ++ni)
        acc[mi][ni] = __builtin_amdgcn_mfma_f32_16x16x32_bf16(a[mi], b[ni], acc[mi][ni], 0, 0, 0);
  }

  // C/D: col = lane&15, row = (lane>>4)*4 + q
#pragma unroll
  for (int mi = 0; mi < 4; ++mi) {
#pragma unroll
    for (int q = 0; q < 4; ++q) {
      int row = m0 + mi * 16 + kg * 4 + q;
      if (row < N_NODES) {
#pragma unroll
        for (int ni = 0; ni < 4; ++ni)
          H1b[(size_t)row * 256 + n0 + ni * 16 + r] = f2bf(acc[mi][ni][q]);
      }
    }
  }
}

// ---------------------------------------------------------------------------
// attention coefficients layer 1 from bf16 h1
// ---------------------------------------------------------------------------
__global__ __launch_bounds__(256) void attn1_kernel(const ushort4* __restrict__ h1b4,
                                                    const float* __restrict__ a_src,
                                                    const float* __restrict__ a_dst,
                                                    float* __restrict__ as1,
                                                    float* __restrict__ ad1) {
  int n = (blockIdx.x * 256 + threadIdx.x) >> 6;
  int lane = threadIdx.x & 63;
  ushort4 hv = h1b4[n * 64 + lane];
  float hx = bf2f(hv.x), hy = bf2f(hv.y), hz = bf2f(hv.z), hw = bf2f(hv.w);
  int h = lane >> 3, cb = (lane & 7) * 4;
  const float* sr = a_src + h * 32 + cb;
  const float* dr = a_dst + h * 32 + cb;
  float ps = hx * sr[0] + hy * sr[1] + hz * sr[2] + hw * sr[3];
  float pd = hx * dr[0] + hy * dr[1] + hz * dr[2] + hw * dr[3];
  ps += __shfl_xor(ps, 1); ps += __shfl_xor(ps, 2); ps += __shfl_xor(ps, 4);
  pd += __shfl_xor(pd, 1); pd += __shfl_xor(pd, 2); pd += __shfl_xor(pd, 4);
  if ((lane & 7) == 0) { as1[n * 8 + h] = ps; ad1[n * 8 + h] = pd; }
}

// ---------------------------------------------------------------------------
// CSR build (by destination)
// ---------------------------------------------------------------------------
__global__ __launch_bounds__(256) void deg_count_kernel(const int* __restrict__ ei,
                                                        int* __restrict__ deg) {
  int i = blockIdx.x * 256 + threadIdx.x;
  if (i < E_TOT) {
    int d = (i < N_EDGES) ? ei[N_EDGES + i] : (i - N_EDGES);
    atomicAdd(&deg[d], 1);
  }
}

__global__ __launch_bounds__(256) void scan_block_kernel(const int* __restrict__ deg,
                                                         int* __restrict__ off,
                                                         int* __restrict__ bsum) {
  __shared__ int sh[256];
  int tid = threadIdx.x;
  int i = blockIdx.x * 256 + tid;
  int v = (i < N_NODES) ? deg[i] : 0;
  sh[tid] = v;
  __syncthreads();
  for (int d = 1; d < 256; d <<= 1) {
    int t = (tid >= d) ? sh[tid - d] : 0;
    __syncthreads();
    sh[tid] += t;
    __syncthreads();
  }
  if (i < N_NODES) off[i] = sh[tid] - v;
  if (tid == 255) bsum[blockIdx.x] = sh[255];
}

__global__ __launch_bounds__(256) void scan_top_kernel(int* __restrict__ bsum, int NB) {
  __shared__ int sh[256];
  int tid = threadIdx.x;
  int v = (tid < NB) ? bsum[tid] : 0;
  sh[tid] = v;
  __syncthreads();
  for (int d = 1; d < 256; d <<= 1) {
    int t = (tid >= d) ? sh[tid - d] : 0;
    __syncthreads();
    sh[tid] += t;
    __syncthreads();
  }
  bsum[tid] = sh[tid] - v;  // exclusive
}

__global__ __launch_bounds__(256) void scan_add_kernel(int* __restrict__ off,
                                                       const int* __restrict__ bsum,
                                                       int* __restrict__ cursor) {
  int i = blockIdx.x * 256 + threadIdx.x;
  if (i < N_NODES) {
    int v = off[i] + bsum[blockIdx.x];
    off[i] = v;
    cursor[i] = v;
  }
  if (i == 0) off[N_NODES] = E_TOT;
}

__global__ __launch_bounds__(256) void scatter_kernel(const int* __restrict__ ei,
                                                      int* __restrict__ cursor,
                                                      int* __restrict__ csr) {
  int i = blockIdx.x * 256 + threadIdx.x;
  if (i < E_TOT) {
    int s = (i < N_EDGES) ? ei[i] : (i - N_EDGES);
    int d = (i < N_EDGES) ? ei[N_EDGES + i] : (i - N_EDGES);
    int pos = atomicAdd(&cursor[d], 1);
    csr[pos] = s;
  }
}

// ---------------------------------------------------------------------------
// layer-1 aggregation + bias + elu -> h2 (bf16)
// wave per dst node. pass1: per-head max (lanes = 8 heads x 8 edge-par).
// pass2: 2 edges/iter (half-waves), lane reads 16 B (8 bf16 channels).
// ---------------------------------------------------------------------------
__global__ __launch_bounds__(256) void agg1_kernel(const ushort* __restrict__ h1b,
                                                   const float* __restrict__ as1,
                                                   const float* __restrict__ ad1,
                                                   const int* __restrict__ off,
                                                   const int* __restrict__ csr,
                                                   const float* __restrict__ b1,
                                                   ushort* __restrict__ h2b) {
  int n = (blockIdx.x * 256 + threadIdx.x) >> 6;
  int lane = threadIdx.x & 63;
  int p0 = off[n], p1 = off[n + 1];

  // ---- pass 1: per-head max of leaky(as1[src]+ad1[n]) ----
  int hA = lane >> 3, jA = lane & 7;
  float adA = ad1[n * 8 + hA];
  float m = -INFINITY;
  for (int p = p0 + jA; p < p1; p += 8) {
    float e = as1[csr[p] * 8 + hA] + adA;
    e = e > 0.f ? e : 0.2f * e;
    m = fmaxf(m, e);
  }
  m = fmaxf(m, __shfl_xor(m, 1));
  m = fmaxf(m, __shfl_xor(m, 2));
  m = fmaxf(m, __shfl_xor(m, 4));

  // ---- pass 2 ----
  int hl = lane & 31;          // position within half-wave
  int half = lane >> 5;        // edge slot parity
  int h8 = hl >> 2;            // head for my 8 channels
  int cb = hl * 8;             // channel base
  float mh = __shfl(m, h8 * 8);
  float ad = ad1[n * 8 + h8];

  float ssum = 0.f;
  float acc0 = 0.f, acc1 = 0.f, acc2 = 0.f, acc3 = 0.f;
  float acc4 = 0.f, acc5 = 0.f, acc6 = 0.f, acc7 = 0.f;
  for (int p = p0 + half; p < p1; p += 2) {
    int src = csr[p];
    float e = as1[src * 8 + h8] + ad;
    e = e > 0.f ? e : 0.2f * e;
    float w = __expf(e - mh);
    ssum += w;
    int4 raw = *reinterpret_cast<const int4*>(h1b + (size_t)src * 256 + cb);
    acc0 += w * bflo((unsigned)raw.x); acc1 += w * bfhi((unsigned)raw.x);
    acc2 += w * bflo((unsigned)raw.y); acc3 += w * bfhi((unsigned)raw.y);
    acc4 += w * bflo((unsigned)raw.z); acc5 += w * bfhi((unsigned)raw.z);
    acc6 += w * bflo((unsigned)raw.w); acc7 += w * bfhi((unsigned)raw.w);
  }
  // merge the two half-waves
  ssum += __shfl_xor(ssum, 32);
  acc0 += __shfl_xor(acc0, 32); acc1 += __shfl_xor(acc1, 32);
  acc2 += __shfl_xor(acc2, 32); acc3 += __shfl_xor(acc3, 32);
  acc4 += __shfl_xor(acc4, 32); acc5 += __shfl_xor(acc5, 32);
  acc6 += __shfl_xor(acc6, 32); acc7 += __shfl_xor(acc7, 32);

  if (half == 0) {
    float inv = 1.f / ssum;
    float o[8] = {acc0, acc1, acc2, acc3, acc4, acc5, acc6, acc7};
    float4 bA = *reinterpret_cast<const float4*>(b1 + cb);
    float4 bB = *reinterpret_cast<const float4*>(b1 + cb + 4);
    o[0] = o[0] * inv + bA.x; o[1] = o[1] * inv + bA.y;
    o[2] = o[2] * inv + bA.z; o[3] = o[3] * inv + bA.w;
    o[4] = o[4] * inv + bB.x; o[5] = o[5] * inv + bB.y;
    o[6] = o[6] * inv + bB.z; o[7] = o[7] * inv + bB.w;
#pragma unroll
    for (int c = 0; c < 8; ++c) o[c] = o[c] > 0.f ? o[c] : __expf(o[c]) - 1.f;
    int4 outv;
    outv.x = (int)(((unsigned)f2bf(o[1]) << 16) | f2bf(o[0]));
    outv.y = (int)(((unsigned)f2bf(o[3]) << 16) | f2bf(o[2]));
    outv.z = (int)(((unsigned)f2bf(o[5]) << 16) | f2bf(o[4]));
    outv.w = (int)(((unsigned)f2bf(o[7]) << 16) | f2bf(o[6]));
    *reinterpret_cast<int4*>(h2b + (size_t)n * 256 + cb) = outv;
  }
}

// ---------------------------------------------------------------------------
// layer-2 projection: pj2p (stride 16, padded) = h2 @ W2, plus as2/ad2
// ---------------------------------------------------------------------------
__global__ __launch_bounds__(256) void proj2_kernel(const ushort4* __restrict__ h2b4,
                                                    const float* __restrict__ W2,
                                                    const float* __restrict__ asrc2,
                                                    const float* __restrict__ adst2,
                                                    float* __restrict__ pj2p,
                                                    float* __restrict__ as2,
                                                    float* __restrict__ ad2) {
  __shared__ float W2t[NCLS][260];
  for (int idx = threadIdx.x; idx < 256 * NCLS; idx += 256) {
    int k = idx / NCLS, c = idx % NCLS;
    W2t[c][k] = W2[idx];
  }
  __syncthreads();
  int n = (blockIdx.x * 256 + threadIdx.x) >> 6;
  int lane = threadIdx.x & 63;
  ushort4 hv = h2b4[n * 64 + lane];
  float hx = bf2f(hv.x), hy = bf2f(hv.y), hz = bf2f(hv.z), hw = bf2f(hv.w);
  float s[NCLS];
#pragma unroll
  for (int c = 0; c < NCLS; ++c) {
    float4 w = *reinterpret_cast<const float4*>(&W2t[c][lane * 4]);
    float p = hx * w.x + hy * w.y + hz * w.z + hw * w.w;
    p += __shfl_xor(p, 1); p += __shfl_xor(p, 2); p += __shfl_xor(p, 4);
    p += __shfl_xor(p, 8); p += __shfl_xor(p, 16); p += __shfl_xor(p, 32);
    s[c] = p;
  }
  if (lane == 0) {
    float vs = 0.f, vd = 0.f;
#pragma unroll
    for (int c = 0; c < NCLS; ++c) {
      pj2p[n * 16 + c] = s[c];
      vs += s[c] * asrc2[c];
      vd += s[c] * adst2[c];
    }
#pragma unroll
    for (int c = NCLS; c < 16; ++c) pj2p[n * 16 + c] = 0.f;
    as2[n] = vs;
    ad2[n] = vd;
  }
}

// ---------------------------------------------------------------------------
// layer-2 aggregation: wave per node; pass1 max over lanes; pass2: 4 edge
// slots x 16 channel lanes (coalesced 64 B pj2p row reads)
// ---------------------------------------------------------------------------
__global__ __launch_bounds__(256) void agg2_kernel(const float* __restrict__ pj2p,
                                                   const float* __restrict__ as2,
                                                   const float* __restrict__ ad2,
                                                   const int* __restrict__ off,
                                                   const int* __restrict__ csr,
                                                   const float* __restrict__ b2,
                                                   float* __restrict__ out2p) {
  int n = (blockIdx.x * 256 + threadIdx.x) >> 6;
  int lane = threadIdx.x & 63;
  int p0 = off[n], p1 = off[n + 1];
  float ad = ad2[n];
  float m = -INFINITY;
  for (int p = p0 + lane; p < p1; p += 64) {
    float e = as2[csr[p]] + ad;
    e = e > 0.f ? e : 0.2f * e;
    m = fmaxf(m, e);
  }
  m = fmaxf(m, __shfl_xor(m, 1));
  m = fmaxf(m, __shfl_xor(m, 2));
  m = fmaxf(m, __shfl_xor(m, 4));
  m = fmaxf(m, __shfl_xor(m, 8));
  m = fmaxf(m, __shfl_xor(m, 16));
  m = fmaxf(m, __shfl_xor(m, 32));

  int es = lane >> 4, c = lane & 15;
  float ssum = 0.f, acc = 0.f;
  for (int p = p0 + es; p < p1; p += 4) {
    int src = csr[p];
    float e = as2[src] + ad;
    e = e > 0.f ? e : 0.2f * e;
    float w = __expf(e - m);
    ssum += w;
    acc += w * pj2p[src * 16 + c];
  }
  acc += __shfl_xor(acc, 16); acc += __shfl_xor(acc, 32);
  ssum += __shfl_xor(ssum, 16); ssum += __shfl_xor(ssum, 32);
  if (lane < 16) {
    float bc = (lane < NCLS) ? b2[lane] : 0.f;
    out2p[n * 16 + lane] = acc / ssum + bc;
  }
}

// ---------------------------------------------------------------------------
// global mean pool: batch sorted -> binary-search range per graph
// ---------------------------------------------------------------------------
__global__ __launch_bounds__(256) void pool_kernel(const float* __restrict__ out2p,
                                                   const int* __restrict__ batch,
                                                   float* __restrict__ outp) {
  __shared__ float red[256];
  int g = blockIdx.x;
  int lo = 0, hi = N_NODES;
  while (lo < hi) { int mid = (lo + hi) >> 1; if (batch[mid] < g) lo = mid + 1; else hi = mid; }
  int start = lo;
  hi = N_NODES;
  while (lo < hi) { int mid = (lo + hi) >> 1; if (batch[mid] < g + 1) lo = mid + 1; else hi = mid; }
  int end = lo;
  int t = threadIdx.x;
  int c = t & 15, nsl = t >> 4;
  float loc = 0.f;
  for (int nn = start + nsl; nn < end; nn += 16) loc += out2p[nn * 16 + c];
  red[t] = loc;
  __syncthreads();
  for (int s = 128; s >= 16; s >>= 1) {
    if (t < s) red[t] += red[t + s];
    __syncthreads();
  }
  if (t < NCLS) {
    float denom = fmaxf((float)(end - start), 1.f);
    outp[g * NCLS + t] = red[t] / denom;
  }
}

// ---------------------------------------------------------------------------
extern "C" void kernel_launch(void* const* d_in, const int* in_sizes, int n_in,
                              void* d_out, int out_size, void* d_ws, size_t ws_size,
                              hipStream_t stream) {
  const float* x      = (const float*)d_in[0];
  const float* W1     = (const float*)d_in[1];
  const float* a_src1 = (const float*)d_in[2];
  const float* a_dst1 = (const float*)d_in[3];
  const float* b1     = (const float*)d_in[4];
  const float* W2     = (const float*)d_in[5];
  const float* a_src2 = (const float*)d_in[6];
  const float* a_dst2 = (const float*)d_in[7];
  const float* b2     = (const float*)d_in[8];
  const int*   ei     = (const int*)d_in[9];
  const int*   batch  = (const int*)d_in[10];

  char* ws = (char*)d_ws;
  size_t o = 0;
  auto alloc = [&](size_t bytes) {
    char* p = ws + o;
    o = (o + bytes + 255) & ~(size_t)255;
    return p;
  };
  ushort* xb   = (ushort*)alloc((size_t)N_NODES * 256 * 2);
  ushort* w1t  = (ushort*)alloc((size_t)256 * 256 * 2);
  ushort* h1b  = (ushort*)alloc((size_t)N_NODES * 256 * 2);
  ushort* h2b  = (ushort*)alloc((size_t)N_NODES * 256 * 2);
  float* as1   = (float*)alloc((size_t)N_NODES * 8 * 4);
  float* ad1   = (float*)alloc((size_t)N_NODES * 8 * 4);
  float* pj2p  = (float*)alloc((size_t)N_NODES * 16 * 4);
  float* as2   = (float*)alloc((size_t)N_NODES * 4);
  float* ad2   = (float*)alloc((size_t)N_NODES * 4);
  float* out2p = (float*)alloc((size_t)N_NODES * 16 * 4);
  int*   deg   = (int*)alloc((size_t)N_NODES * 4);
  int*   off   = (int*)alloc((size_t)(N_NODES + 1) * 4);
  int*   cur   = (int*)alloc((size_t)N_NODES * 4);
  int*   csr   = (int*)alloc((size_t)E_TOT * 4);
  int*   bsum  = (int*)alloc(256 * 4);

  hipMemsetAsync(deg, 0, (size_t)N_NODES * 4, stream);

  cast_x_kernel<<<12500, 256, 0, stream>>>((const float4*)x, (ushort4*)xb);
  w1t_kernel<<<dim3(8, 8), 256, 0, stream>>>(W1, w1t);
  gemm1_mfma<<<(N_NODES + 63) / 64, 256, 0, stream>>>(xb, w1t, h1b);

  attn1_kernel<<<N_NODES / 4, 256, 0, stream>>>((const ushort4*)h1b, a_src1, a_dst1, as1, ad1);

  int egrid = (E_TOT + 255) / 256;
  deg_count_kernel<<<egrid, 256, 0, stream>>>(ei, deg);
  int nb = (N_NODES + 255) / 256;  // 196
  scan_block_kernel<<<nb, 256, 0, stream>>>(deg, off, bsum);
  scan_top_kernel<<<1, 256, 0, stream>>>(bsum, nb);
  scan_add_kernel<<<nb, 256, 0, stream>>>(off, bsum, cur);
  scatter_kernel<<<egrid, 256, 0, stream>>>(ei, cur, csr);

  agg1_kernel<<<N_NODES / 4, 256, 0, stream>>>(h1b, as1, ad1, off, csr, b1, h2b);
  proj2_kernel<<<N_NODES / 4, 256, 0, stream>>>((const ushort4*)h2b, W2, a_src2, a_dst2,
                                                pj2p, as2, ad2);
  agg2_kernel<<<N_NODES / 4, 256, 0, stream>>>(pj2p, as2, ad2, off, csr, b2, out2p);
  pool_kernel<<<NGRP, 256, 0, stream>>>(out2p, batch, (float*)d_out);
}

// Round 3
// 357.992 us; speedup vs baseline: 1.5203x; 1.1621x over previous
//
#include <hip/hip_runtime.h>
#include <hip/hip_bf16.h>
#include <math.h>

#define N_NODES 50000
#define N_EDGES 800000
#define E_TOT   (N_EDGES + N_NODES)   /* 850000 with self loops */
#define NCLS 10
#define NGRP 128

typedef __attribute__((ext_vector_type(8))) short bf16x8;
typedef __attribute__((ext_vector_type(4))) float f32x4;

static __device__ __forceinline__ ushort f2bf(float f) {
  union { float f; unsigned u; } v; v.f = f;
  unsigned r = v.u + 0x7fffu + ((v.u >> 16) & 1u);   // round-to-nearest-even
  return (ushort)(r >> 16);
}
static __device__ __forceinline__ float bf2f(ushort u) {
  union { unsigned u; float f; } v; v.u = ((unsigned)u) << 16; return v.f;
}
static __device__ __forceinline__ float bflo(unsigned u) {
  union { unsigned u; float f; } v; v.u = u << 16; return v.f;
}
static __device__ __forceinline__ float bfhi(unsigned u) {
  union { unsigned u; float f; } v; v.u = u & 0xffff0000u; return v.f;
}

// ---------------------------------------------------------------------------
// prep: cast x -> bf16 | W1 -> W1t bf16 | W2 -> W2tp bf16 [16][256] | deg count
// block ranges: [0,12500) cast, [12500,12564) w1t, 12564 w2t, [12565,..) deg
// ---------------------------------------------------------------------------
#define CAST_BLOCKS 12500
#define W1T_BASE 12500
#define W2T_BASE 12564
#define DEG_BASE 12565
#define DEG_BLOCKS ((E_TOT + 255) / 256)
#define PREP_BLOCKS (DEG_BASE + DEG_BLOCKS)

__global__ __launch_bounds__(256) void prep_kernel(const float4* __restrict__ X4,
                                                   ushort4* __restrict__ Xb,
                                                   const float* __restrict__ W1,
                                                   ushort* __restrict__ W1t,
                                                   const float* __restrict__ W2,
                                                   ushort* __restrict__ W2tp,
                                                   const int* __restrict__ ei,
                                                   int* __restrict__ deg) {
  int b = blockIdx.x;
  int tid = threadIdx.x;
  if (b < CAST_BLOCKS) {
    int i = b * 256 + tid;
    float4 v = X4[i];
    ushort4 o;
    o.x = f2bf(v.x); o.y = f2bf(v.y); o.z = f2bf(v.z); o.w = f2bf(v.w);
    Xb[i] = o;
  } else if (b < W2T_BASE) {
    __shared__ float t[32][33];
    int bb = b - W1T_BASE;
    int k0 = (bb >> 3) * 32, n0 = (bb & 7) * 32;
    int tx = tid & 31, ty = tid >> 5;  // ty 0..7
    for (int r = 0; r < 32; r += 8)
      t[ty + r][tx] = W1[(k0 + ty + r) * 256 + n0 + tx];
    __syncthreads();
    for (int r = 0; r < 32; r += 8)
      W1t[(n0 + ty + r) * 256 + k0 + tx] = f2bf(t[tx][ty + r]);
  } else if (b == W2T_BASE) {
    int k = tid;  // 0..255
#pragma unroll
    for (int c = 0; c < 16; ++c)
      W2tp[c * 256 + k] = (c < NCLS) ? f2bf(W2[k * NCLS + c]) : (ushort)0;
  } else {
    int i = (b - DEG_BASE) * 256 + tid;
    if (i < E_TOT) {
      int d = (i < N_EDGES) ? ei[N_EDGES + i] : (i - N_EDGES);
      atomicAdd(&deg[d], 1);
    }
  }
}

// ---------------------------------------------------------------------------
// GEMM1 MFMA: h1 = x @ W1, M=50000, N=256, K=256, bf16 in, bf16 out
// ---------------------------------------------------------------------------
__global__ __launch_bounds__(256) void gemm1_mfma(const ushort* __restrict__ Xb,
                                                  const ushort* __restrict__ W1t,
                                                  ushort* __restrict__ H1b) {
  int wid = threadIdx.x >> 6, lane = threadIdx.x & 63;
  int r = lane & 15, kg = lane >> 4;
  int m0 = blockIdx.x * 64;
  int n0 = wid * 64;
  f32x4 acc[4][4];
#pragma unroll
  for (int mi = 0; mi < 4; ++mi)
#pragma unroll
    for (int ni = 0; ni < 4; ++ni) acc[mi][ni] = 0;

  const ushort* aptr[4];
#pragma unroll
  for (int mi = 0; mi < 4; ++mi) {
    int row = m0 + mi * 16 + r;
    if (row >= N_NODES) row = 0;
    aptr[mi] = Xb + (size_t)row * 256 + kg * 8;
  }
  const ushort* bptr[4];
#pragma unroll
  for (int ni = 0; ni < 4; ++ni)
    bptr[ni] = W1t + (size_t)(n0 + ni * 16 + r) * 256 + kg * 8;

#pragma unroll 2
  for (int k0 = 0; k0 < 256; k0 += 32) {
    bf16x8 a[4], b[4];
#pragma unroll
    for (int mi = 0; mi < 4; ++mi)
      a[mi] = *reinterpret_cast<const bf16x8*>(aptr[mi] + k0);
#pragma unroll
    for (int ni = 0; ni < 4; ++ni)
      b[ni] = *reinterpret_cast<const bf16x8*>(bptr[ni] + k0);
#pragma unroll
    for (int mi = 0; mi < 4; ++mi)
#pragma unroll
      for (int ni = 0; ni < 4; ++ni)
        acc[mi][ni] = __builtin_amdgcn_mfma_f32_16x16x32_bf16(a[mi], b[ni], acc[mi][ni], 0, 0, 0);
  }

#pragma unroll
  for (int mi = 0; mi < 4; ++mi) {
#pragma unroll
    for (int q = 0; q < 4; ++q) {
      int row = m0 + mi * 16 + kg * 4 + q;
      if (row < N_NODES) {
#pragma unroll
        for (int ni = 0; ni < 4; ++ni)
          H1b[(size_t)row * 256 + n0 + ni * 16 + r] = f2bf(acc[mi][ni][q]);
      }
    }
  }
}

// ---------------------------------------------------------------------------
// attention coefficients layer 1 from bf16 h1
// ---------------------------------------------------------------------------
__global__ __launch_bounds__(256) void attn1_kernel(const ushort4* __restrict__ h1b4,
                                                    const float* __restrict__ a_src,
                                                    const float* __restrict__ a_dst,
                                                    float* __restrict__ as1,
                                                    float* __restrict__ ad1) {
  int n = (blockIdx.x * 256 + threadIdx.x) >> 6;
  int lane = threadIdx.x & 63;
  ushort4 hv = h1b4[n * 64 + lane];
  float hx = bf2f(hv.x), hy = bf2f(hv.y), hz = bf2f(hv.z), hw = bf2f(hv.w);
  int h = lane >> 3, cb = (lane & 7) * 4;
  const float* sr = a_src + h * 32 + cb;
  const float* dr = a_dst + h * 32 + cb;
  float ps = hx * sr[0] + hy * sr[1] + hz * sr[2] + hw * sr[3];
  float pd = hx * dr[0] + hy * dr[1] + hz * dr[2] + hw * dr[3];
  ps += __shfl_xor(ps, 1); ps += __shfl_xor(ps, 2); ps += __shfl_xor(ps, 4);
  pd += __shfl_xor(pd, 1); pd += __shfl_xor(pd, 2); pd += __shfl_xor(pd, 4);
  if ((lane & 7) == 0) { as1[n * 8 + h] = ps; ad1[n * 8 + h] = pd; }
}

// ---------------------------------------------------------------------------
// CSR scan + scatter
// ---------------------------------------------------------------------------
__global__ __launch_bounds__(256) void scan_block_kernel(const int* __restrict__ deg,
                                                         int* __restrict__ off,
                                                         int* __restrict__ bsum) {
  __shared__ int sh[256];
  int tid = threadIdx.x;
  int i = blockIdx.x * 256 + tid;
  int v = (i < N_NODES) ? deg[i] : 0;
  sh[tid] = v;
  __syncthreads();
  for (int d = 1; d < 256; d <<= 1) {
    int t = (tid >= d) ? sh[tid - d] : 0;
    __syncthreads();
    sh[tid] += t;
    __syncthreads();
  }
  if (i < N_NODES) off[i] = sh[tid] - v;
  if (tid == 255) bsum[blockIdx.x] = sh[255];
}

__global__ __launch_bounds__(256) void scan_top_kernel(int* __restrict__ bsum, int NB) {
  __shared__ int sh[256];
  int tid = threadIdx.x;
  int v = (tid < NB) ? bsum[tid] : 0;
  sh[tid] = v;
  __syncthreads();
  for (int d = 1; d < 256; d <<= 1) {
    int t = (tid >= d) ? sh[tid - d] : 0;
    __syncthreads();
    sh[tid] += t;
    __syncthreads();
  }
  bsum[tid] = sh[tid] - v;  // exclusive
}

__global__ __launch_bounds__(256) void scan_add_kernel(int* __restrict__ off,
                                                       const int* __restrict__ bsum,
                                                       int* __restrict__ cursor) {
  int i = blockIdx.x * 256 + threadIdx.x;
  if (i < N_NODES) {
    int v = off[i] + bsum[blockIdx.x];
    off[i] = v;
    cursor[i] = v;
  }
  if (i == 0) off[N_NODES] = E_TOT;
}

__global__ __launch_bounds__(256) void scatter_kernel(const int* __restrict__ ei,
                                                      int* __restrict__ cursor,
                                                      int* __restrict__ csr) {
  int i = blockIdx.x * 256 + threadIdx.x;
  if (i < E_TOT) {
    int s = (i < N_EDGES) ? ei[i] : (i - N_EDGES);
    int d = (i < N_EDGES) ? ei[N_EDGES + i] : (i - N_EDGES);
    int pos = atomicAdd(&cursor[d], 1);
    csr[pos] = s;
  }
}

// ---------------------------------------------------------------------------
// layer-1 aggregation + bias + elu -> h2 (bf16). Single pass, no max
// (exp args bounded ~|5|). Wave per dst node, 2 edges x 2-unroll in flight.
// ---------------------------------------------------------------------------
__global__ __launch_bounds__(256) void agg1_kernel(const ushort* __restrict__ h1b,
                                                   const float* __restrict__ as1,
                                                   const float* __restrict__ ad1,
                                                   const int* __restrict__ off,
                                                   const int* __restrict__ csr,
                                                   const float* __restrict__ b1,
                                                   ushort* __restrict__ h2b) {
  int n = (blockIdx.x * 256 + threadIdx.x) >> 6;
  int lane = threadIdx.x & 63;
  int p0 = off[n], p1 = off[n + 1];

  int hl = lane & 31;          // position within half-wave
  int half = lane >> 5;        // edge slot parity
  int h8 = hl >> 2;            // head for my 8 channels
  int cb = hl * 8;             // channel base
  float ad = ad1[n * 8 + h8];

  float ssum = 0.f;
  float acc0 = 0.f, acc1 = 0.f, acc2 = 0.f, acc3 = 0.f;
  float acc4 = 0.f, acc5 = 0.f, acc6 = 0.f, acc7 = 0.f;

  int p = p0 + half;
  for (; p + 2 < p1; p += 4) {
    int sA = csr[p], sB = csr[p + 2];
    float eA = as1[sA * 8 + h8] + ad;
    float eB = as1[sB * 8 + h8] + ad;
    int4 rA = *reinterpret_cast<const int4*>(h1b + (size_t)sA * 256 + cb);
    int4 rB = *reinterpret_cast<const int4*>(h1b + (size_t)sB * 256 + cb);
    eA = eA > 0.f ? eA : 0.2f * eA;
    eB = eB > 0.f ? eB : 0.2f * eB;
    float wA = __expf(eA), wB = __expf(eB);
    ssum += wA + wB;
    acc0 += wA * bflo((unsigned)rA.x) + wB * bflo((unsigned)rB.x);
    acc1 += wA * bfhi((unsigned)rA.x) + wB * bfhi((unsigned)rB.x);
    acc2 += wA * bflo((unsigned)rA.y) + wB * bflo((unsigned)rB.y);
    acc3 += wA * bfhi((unsigned)rA.y) + wB * bfhi((unsigned)rB.y);
    acc4 += wA * bflo((unsigned)rA.z) + wB * bflo((unsigned)rB.z);
    acc5 += wA * bfhi((unsigned)rA.z) + wB * bfhi((unsigned)rB.z);
    acc6 += wA * bflo((unsigned)rA.w) + wB * bflo((unsigned)rB.w);
    acc7 += wA * bfhi((unsigned)rA.w) + wB * bfhi((unsigned)rB.w);
  }
  if (p < p1) {
    int sA = csr[p];
    float eA = as1[sA * 8 + h8] + ad;
    int4 rA = *reinterpret_cast<const int4*>(h1b + (size_t)sA * 256 + cb);
    eA = eA > 0.f ? eA : 0.2f * eA;
    float wA = __expf(eA);
    ssum += wA;
    acc0 += wA * bflo((unsigned)rA.x); acc1 += wA * bfhi((unsigned)rA.x);
    acc2 += wA * bflo((unsigned)rA.y); acc3 += wA * bfhi((unsigned)rA.y);
    acc4 += wA * bflo((unsigned)rA.z); acc5 += wA * bfhi((unsigned)rA.z);
    acc6 += wA * bflo((unsigned)rA.w); acc7 += wA * bfhi((unsigned)rA.w);
  }
  // merge the two half-waves
  ssum += __shfl_xor(ssum, 32);
  acc0 += __shfl_xor(acc0, 32); acc1 += __shfl_xor(acc1, 32);
  acc2 += __shfl_xor(acc2, 32); acc3 += __shfl_xor(acc3, 32);
  acc4 += __shfl_xor(acc4, 32); acc5 += __shfl_xor(acc5, 32);
  acc6 += __shfl_xor(acc6, 32); acc7 += __shfl_xor(acc7, 32);

  if (half == 0) {
    float inv = 1.f / ssum;
    float o[8] = {acc0, acc1, acc2, acc3, acc4, acc5, acc6, acc7};
    float4 bA = *reinterpret_cast<const float4*>(b1 + cb);
    float4 bB = *reinterpret_cast<const float4*>(b1 + cb + 4);
    o[0] = o[0] * inv + bA.x; o[1] = o[1] * inv + bA.y;
    o[2] = o[2] * inv + bA.z; o[3] = o[3] * inv + bA.w;
    o[4] = o[4] * inv + bB.x; o[5] = o[5] * inv + bB.y;
    o[6] = o[6] * inv + bB.z; o[7] = o[7] * inv + bB.w;
#pragma unroll
    for (int c = 0; c < 8; ++c) o[c] = o[c] > 0.f ? o[c] : __expf(o[c]) - 1.f;
    int4 outv;
    outv.x = (int)(((unsigned)f2bf(o[1]) << 16) | f2bf(o[0]));
    outv.y = (int)(((unsigned)f2bf(o[3]) << 16) | f2bf(o[2]));
    outv.z = (int)(((unsigned)f2bf(o[5]) << 16) | f2bf(o[4]));
    outv.w = (int)(((unsigned)f2bf(o[7]) << 16) | f2bf(o[6]));
    *reinterpret_cast<int4*>(h2b + (size_t)n * 256 + cb) = outv;
  }
}

// ---------------------------------------------------------------------------
// layer-2 projection via MFMA: pj2p[50000][16] = h2 @ W2tp^T, + as2/ad2
// wave handles 16 rows x 16 cols, K=256 (8 MFMAs)
// ---------------------------------------------------------------------------
__global__ __launch_bounds__(256) void proj2_mfma(const ushort* __restrict__ h2b,
                                                  const ushort* __restrict__ W2tp,
                                                  const float* __restrict__ asrc2,
                                                  const float* __restrict__ adst2,
                                                  float* __restrict__ pj2p,
                                                  float* __restrict__ as2,
                                                  float* __restrict__ ad2) {
  int wid = threadIdx.x >> 6, lane = threadIdx.x & 63;
  int r = lane & 15, kg = lane >> 4;
  int rb = blockIdx.x * 64 + wid * 16;
  int row_a = rb + r;
  if (row_a >= N_NODES) row_a = 0;
  const ushort* ap = h2b + (size_t)row_a * 256 + kg * 8;
  const ushort* bp = W2tp + (size_t)r * 256 + kg * 8;
  f32x4 acc = 0;
#pragma unroll
  for (int k0 = 0; k0 < 256; k0 += 32)
    acc = __builtin_amdgcn_mfma_f32_16x16x32_bf16(
        *reinterpret_cast<const bf16x8*>(ap + k0),
        *reinterpret_cast<const bf16x8*>(bp + k0), acc, 0, 0, 0);

  float av = (r < NCLS) ? asrc2[r] : 0.f;
  float dv = (r < NCLS) ? adst2[r] : 0.f;
#pragma unroll
  for (int q = 0; q < 4; ++q) {
    int row = rb + kg * 4 + q;
    float v = acc[q];
    if (row < N_NODES) pj2p[row * 16 + r] = v;
    float s = v * av, d = v * dv;
    s += __shfl_xor(s, 1); s += __shfl_xor(s, 2); s += __shfl_xor(s, 4); s += __shfl_xor(s, 8);
    d += __shfl_xor(d, 1); d += __shfl_xor(d, 2); d += __shfl_xor(d, 4); d += __shfl_xor(d, 8);
    if (r == 0 && row < N_NODES) { as2[row] = s; ad2[row] = d; }
  }
}

// ---------------------------------------------------------------------------
// layer-2 aggregation: single pass (no max), 4 edge slots x 16 channel lanes
// ---------------------------------------------------------------------------
__global__ __launch_bounds__(256) void agg2_kernel(const float* __restrict__ pj2p,
                                                   const float* __restrict__ as2,
                                                   const float* __restrict__ ad2,
                                                   const int* __restrict__ off,
                                                   const int* __restrict__ csr,
                                                   const float* __restrict__ b2,
                                                   float* __restrict__ out2p) {
  int n = (blockIdx.x * 256 + threadIdx.x) >> 6;
  int lane = threadIdx.x & 63;
  int p0 = off[n], p1 = off[n + 1];
  float ad = ad2[n];
  int es = lane >> 4, c = lane & 15;
  float ssum = 0.f, acc = 0.f;
  int p = p0 + es;
  for (; p + 4 < p1; p += 8) {
    int sA = csr[p], sB = csr[p + 4];
    float eA = as2[sA] + ad, eB = as2[sB] + ad;
    float vA = pj2p[sA * 16 + c], vB = pj2p[sB * 16 + c];
    eA = eA > 0.f ? eA : 0.2f * eA;
    eB = eB > 0.f ? eB : 0.2f * eB;
    float wA = __expf(eA), wB = __expf(eB);
    ssum += wA + wB;
    acc += wA * vA + wB * vB;
  }
  if (p < p1) {
    int sA = csr[p];
    float eA = as2[sA] + ad;
    float vA = pj2p[sA * 16 + c];
    eA = eA > 0.f ? eA : 0.2f * eA;
    float wA = __expf(eA);
    ssum += wA;
    acc += wA * vA;
  }
  acc += __shfl_xor(acc, 16); acc += __shfl_xor(acc, 32);
  ssum += __shfl_xor(ssum, 16); ssum += __shfl_xor(ssum, 32);
  if (lane < 16) {
    float bc = (lane < NCLS) ? b2[lane] : 0.f;
    out2p[n * 16 + lane] = acc / ssum + bc;
  }
}

// ---------------------------------------------------------------------------
// global mean pool
// ---------------------------------------------------------------------------
__global__ __launch_bounds__(256) void pool_kernel(const float* __restrict__ out2p,
                                                   const int* __restrict__ batch,
                                                   float* __restrict__ outp) {
  __shared__ float red[256];
  int g = blockIdx.x;
  int lo = 0, hi = N_NODES;
  while (lo < hi) { int mid = (lo + hi) >> 1; if (batch[mid] < g) lo = mid + 1; else hi = mid; }
  int start = lo;
  hi = N_NODES;
  while (lo < hi) { int mid = (lo + hi) >> 1; if (batch[mid] < g + 1) lo = mid + 1; else hi = mid; }
  int end = lo;
  int t = threadIdx.x;
  int c = t & 15, nsl = t >> 4;
  float loc = 0.f;
  for (int nn = start + nsl; nn < end; nn += 16) loc += out2p[nn * 16 + c];
  red[t] = loc;
  __syncthreads();
  for (int s = 128; s >= 16; s >>= 1) {
    if (t < s) red[t] += red[t + s];
    __syncthreads();
  }
  if (t < NCLS) {
    float denom = fmaxf((float)(end - start), 1.f);
    outp[g * NCLS + t] = red[t] / denom;
  }
}

// ---------------------------------------------------------------------------
extern "C" void kernel_launch(void* const* d_in, const int* in_sizes, int n_in,
                              void* d_out, int out_size, void* d_ws, size_t ws_size,
                              hipStream_t stream) {
  const float* x      = (const float*)d_in[0];
  const float* W1     = (const float*)d_in[1];
  const float* a_src1 = (const float*)d_in[2];
  const float* a_dst1 = (const float*)d_in[3];
  const float* b1     = (const float*)d_in[4];
  const float* W2     = (const float*)d_in[5];
  const float* a_src2 = (const float*)d_in[6];
  const float* a_dst2 = (const float*)d_in[7];
  const float* b2     = (const float*)d_in[8];
  const int*   ei     = (const int*)d_in[9];
  const int*   batch  = (const int*)d_in[10];

  char* ws = (char*)d_ws;
  size_t o = 0;
  auto alloc = [&](size_t bytes) {
    char* p = ws + o;
    o = (o + bytes + 255) & ~(size_t)255;
    return p;
  };
  ushort* xb   = (ushort*)alloc((size_t)N_NODES * 256 * 2);
  ushort* w1t  = (ushort*)alloc((size_t)256 * 256 * 2);
  ushort* w2tp = (ushort*)alloc((size_t)16 * 256 * 2);
  ushort* h1b  = (ushort*)alloc((size_t)N_NODES * 256 * 2);
  ushort* h2b  = (ushort*)alloc((size_t)N_NODES * 256 * 2);
  float* as1   = (float*)alloc((size_t)N_NODES * 8 * 4);
  float* ad1   = (float*)alloc((size_t)N_NODES * 8 * 4);
  float* pj2p  = (float*)alloc((size_t)N_NODES * 16 * 4);
  float* as2   = (float*)alloc((size_t)N_NODES * 4);
  float* ad2   = (float*)alloc((size_t)N_NODES * 4);
  float* out2p = (float*)alloc((size_t)N_NODES * 16 * 4);
  int*   deg   = (int*)alloc((size_t)N_NODES * 4);
  int*   off   = (int*)alloc((size_t)(N_NODES + 1) * 4);
  int*   cur   = (int*)alloc((size_t)N_NODES * 4);
  int*   csr   = (int*)alloc((size_t)E_TOT * 4);
  int*   bsum  = (int*)alloc(256 * 4);

  hipMemsetAsync(deg, 0, (size_t)N_NODES * 4, stream);

  prep_kernel<<<PREP_BLOCKS, 256, 0, stream>>>((const float4*)x, (ushort4*)xb,
                                               W1, w1t, W2, w2tp, ei, deg);
  gemm1_mfma<<<(N_NODES + 63) / 64, 256, 0, stream>>>(xb, w1t, h1b);
  attn1_kernel<<<N_NODES / 4, 256, 0, stream>>>((const ushort4*)h1b, a_src1, a_dst1, as1, ad1);

  int nb = (N_NODES + 255) / 256;  // 196
  scan_block_kernel<<<nb, 256, 0, stream>>>(deg, off, bsum);
  scan_top_kernel<<<1, 256, 0, stream>>>(bsum, nb);
  scan_add_kernel<<<nb, 256, 0, stream>>>(off, bsum, cur);
  scatter_kernel<<<(E_TOT + 255) / 256, 256, 0, stream>>>(ei, cur, csr);

  agg1_kernel<<<N_NODES / 4, 256, 0, stream>>>(h1b, as1, ad1, off, csr, b1, h2b);
  proj2_mfma<<<(N_NODES + 63) / 64, 256, 0, stream>>>(h2b, w2tp, a_src2, a_dst2,
                                                      pj2p, as2, ad2);
  agg2_kernel<<<N_NODES / 4, 256, 0, stream>>>(pj2p, as2, ad2, off, csr, b2, out2p);
  pool_kernel<<<NGRP, 256, 0, stream>>>(out2p, batch, (float*)d_out);
}

// Round 4
// 348.424 us; speedup vs baseline: 1.5621x; 1.0275x over previous
//
#include <hip/hip_runtime.h>
#include <hip/hip_bf16.h>
#include <math.h>

#define N_NODES 50000
#define N_EDGES 800000
#define E_TOT   (N_EDGES + N_NODES)   /* 850000 with self loops */
#define NCLS 10
#define NGRP 128

typedef __attribute__((ext_vector_type(8))) short bf16x8;
typedef __attribute__((ext_vector_type(4))) float f32x4;

static __device__ __forceinline__ ushort f2bf(float f) {
  union { float f; unsigned u; } v; v.f = f;
  unsigned r = v.u + 0x7fffu + ((v.u >> 16) & 1u);   // round-to-nearest-even
  return (ushort)(r >> 16);
}
static __device__ __forceinline__ float bf2f(ushort u) {
  union { unsigned u; float f; } v; v.u = ((unsigned)u) << 16; return v.f;
}
static __device__ __forceinline__ float bflo(unsigned u) {
  union { unsigned u; float f; } v; v.u = u << 16; return v.f;
}
static __device__ __forceinline__ float bfhi(unsigned u) {
  union { unsigned u; float f; } v; v.u = u & 0xffff0000u; return v.f;
}

// ---------------------------------------------------------------------------
// prep: cast x -> bf16 | W1 -> W1t bf16 rows [0,256) | W2 -> W2tp bf16 [16][256]
//       | Wa = W1 @ a_{src,dst} -> W1t rows [256,272) | deg count
// ---------------------------------------------------------------------------
#define CAST_BLOCKS 12500
#define W1T_BASE 12500
#define W2T_BASE 12564
#define WA_BASE  12565
#define DEG_BASE 12566
#define DEG_BLOCKS ((E_TOT + 255) / 256)
#define PREP_BLOCKS (DEG_BASE + DEG_BLOCKS)

__global__ __launch_bounds__(256) void prep_kernel(const float4* __restrict__ X4,
                                                   ushort4* __restrict__ Xb,
                                                   const float* __restrict__ W1,
                                                   ushort* __restrict__ W1t,
                                                   const float* __restrict__ W2,
                                                   ushort* __restrict__ W2tp,
                                                   const float* __restrict__ asrc1,
                                                   const float* __restrict__ adst1,
                                                   const int* __restrict__ ei,
                                                   int* __restrict__ deg) {
  int b = blockIdx.x;
  int tid = threadIdx.x;
  if (b < CAST_BLOCKS) {
    int i = b * 256 + tid;
    float4 v = X4[i];
    ushort4 o;
    o.x = f2bf(v.x); o.y = f2bf(v.y); o.z = f2bf(v.z); o.w = f2bf(v.w);
    Xb[i] = o;
  } else if (b < W2T_BASE) {
    __shared__ float t[32][33];
    int bb = b - W1T_BASE;
    int k0 = (bb >> 3) * 32, n0 = (bb & 7) * 32;
    int tx = tid & 31, ty = tid >> 5;  // ty 0..7
    for (int r = 0; r < 32; r += 8)
      t[ty + r][tx] = W1[(k0 + ty + r) * 256 + n0 + tx];
    __syncthreads();
    for (int r = 0; r < 32; r += 8)
      W1t[(n0 + ty + r) * 256 + k0 + tx] = f2bf(t[tx][ty + r]);
  } else if (b == W2T_BASE) {
    int k = tid;  // 0..255
#pragma unroll
    for (int c = 0; c < 16; ++c)
      W2tp[c * 256 + k] = (c < NCLS) ? f2bf(W2[k * NCLS + c]) : (ushort)0;
  } else if (b == WA_BASE) {
    int k = tid;  // 0..255
    const float* wrow = W1 + k * 256;
#pragma unroll
    for (int h = 0; h < 8; ++h) {
      float s = 0.f, d = 0.f;
#pragma unroll
      for (int c = 0; c < 32; ++c) {
        float w = wrow[h * 32 + c];
        s += w * asrc1[h * 32 + c];
        d += w * adst1[h * 32 + c];
      }
      W1t[(256 + h) * 256 + k] = f2bf(s);
      W1t[(264 + h) * 256 + k] = f2bf(d);
    }
  } else {
    int i = (b - DEG_BASE) * 256 + tid;
    if (i < E_TOT) {
      int d = (i < N_EDGES) ? ei[N_EDGES + i] : (i - N_EDGES);
      atomicAdd(&deg[d], 1);
    }
  }
}

// ---------------------------------------------------------------------------
// GEMM1 MFMA: h1 = x @ W1 (bf16), plus fused as1/ad1 = x @ Wa (cols 256..271,
// computed by wave 3 as a 5th fragment)
// ---------------------------------------------------------------------------
__global__ __launch_bounds__(256) void gemm1_mfma(const ushort* __restrict__ Xb,
                                                  const ushort* __restrict__ W1t,
                                                  ushort* __restrict__ H1b,
                                                  float* __restrict__ as1,
                                                  float* __restrict__ ad1) {
  int wid = threadIdx.x >> 6, lane = threadIdx.x & 63;
  int r = lane & 15, kg = lane >> 4;
  int m0 = blockIdx.x * 64;
  int n0 = wid * 64;
  bool extra = (wid == 3);
  f32x4 acc[4][4];
  f32x4 accE[4];
#pragma unroll
  for (int mi = 0; mi < 4; ++mi) {
#pragma unroll
    for (int ni = 0; ni < 4; ++ni) acc[mi][ni] = 0;
    accE[mi] = 0;
  }

  const ushort* aptr[4];
#pragma unroll
  for (int mi = 0; mi < 4; ++mi) {
    int row = m0 + mi * 16 + r;
    if (row >= N_NODES) row = 0;
    aptr[mi] = Xb + (size_t)row * 256 + kg * 8;
  }
  const ushort* bptr[4];
#pragma unroll
  for (int ni = 0; ni < 4; ++ni)
    bptr[ni] = W1t + (size_t)(n0 + ni * 16 + r) * 256 + kg * 8;
  const ushort* bptrE = W1t + (size_t)(256 + r) * 256 + kg * 8;

#pragma unroll 2
  for (int k0 = 0; k0 < 256; k0 += 32) {
    bf16x8 a[4], b[4], bE;
#pragma unroll
    for (int mi = 0; mi < 4; ++mi)
      a[mi] = *reinterpret_cast<const bf16x8*>(aptr[mi] + k0);
#pragma unroll
    for (int ni = 0; ni < 4; ++ni)
      b[ni] = *reinterpret_cast<const bf16x8*>(bptr[ni] + k0);
    if (extra) bE = *reinterpret_cast<const bf16x8*>(bptrE + k0);
#pragma unroll
    for (int mi = 0; mi < 4; ++mi) {
#pragma unroll
      for (int ni = 0; ni < 4; ++ni)
        acc[mi][ni] = __builtin_amdgcn_mfma_f32_16x16x32_bf16(a[mi], b[ni], acc[mi][ni], 0, 0, 0);
      if (extra)
        accE[mi] = __builtin_amdgcn_mfma_f32_16x16x32_bf16(a[mi], bE, accE[mi], 0, 0, 0);
    }
  }

#pragma unroll
  for (int mi = 0; mi < 4; ++mi) {
#pragma unroll
    for (int q = 0; q < 4; ++q) {
      int row = m0 + mi * 16 + kg * 4 + q;
      if (row < N_NODES) {
#pragma unroll
        for (int ni = 0; ni < 4; ++ni)
          H1b[(size_t)row * 256 + n0 + ni * 16 + r] = f2bf(acc[mi][ni][q]);
        if (extra) {
          float* dst = (r < 8) ? (as1 + row * 8 + r) : (ad1 + row * 8 + (r & 7));
          *dst = accE[mi][q];
        }
      }
    }
  }
}

// ---------------------------------------------------------------------------
// CSR scan + scatter
// ---------------------------------------------------------------------------
__global__ __launch_bounds__(256) void scan_block_kernel(const int* __restrict__ deg,
                                                         int* __restrict__ off,
                                                         int* __restrict__ bsum) {
  __shared__ int sh[256];
  int tid = threadIdx.x;
  int i = blockIdx.x * 256 + tid;
  int v = (i < N_NODES) ? deg[i] : 0;
  sh[tid] = v;
  __syncthreads();
  for (int d = 1; d < 256; d <<= 1) {
    int t = (tid >= d) ? sh[tid - d] : 0;
    __syncthreads();
    sh[tid] += t;
    __syncthreads();
  }
  if (i < N_NODES) off[i] = sh[tid] - v;
  if (tid == 255) bsum[blockIdx.x] = sh[255];
}

__global__ __launch_bounds__(256) void scan_top_kernel(int* __restrict__ bsum, int NB) {
  __shared__ int sh[256];
  int tid = threadIdx.x;
  int v = (tid < NB) ? bsum[tid] : 0;
  sh[tid] = v;
  __syncthreads();
  for (int d = 1; d < 256; d <<= 1) {
    int t = (tid >= d) ? sh[tid - d] : 0;
    __syncthreads();
    sh[tid] += t;
    __syncthreads();
  }
  bsum[tid] = sh[tid] - v;  // exclusive
}

__global__ __launch_bounds__(256) void scan_add_kernel(int* __restrict__ off,
                                                       const int* __restrict__ bsum,
                                                       int* __restrict__ cursor) {
  int i = blockIdx.x * 256 + threadIdx.x;
  if (i < N_NODES) {
    int v = off[i] + bsum[blockIdx.x];
    off[i] = v;
    cursor[i] = v;
  }
  if (i == 0) off[N_NODES] = E_TOT;
}

__global__ __launch_bounds__(256) void scatter_kernel(const int* __restrict__ ei,
                                                      int* __restrict__ cursor,
                                                      int* __restrict__ csr) {
  int i = blockIdx.x * 256 + threadIdx.x;
  if (i < E_TOT) {
    int s = (i < N_EDGES) ? ei[i] : (i - N_EDGES);
    int d = (i < N_EDGES) ? ei[N_EDGES + i] : (i - N_EDGES);
    int pos = atomicAdd(&cursor[d], 1);
    csr[pos] = s;
  }
}

// ---------------------------------------------------------------------------
// layer-1 aggregation + bias + elu -> h2 (bf16). Single pass, no max.
// Wave per dst node, half-wave = edge slot, 4 edges in flight per half-wave.
// ---------------------------------------------------------------------------
__global__ __launch_bounds__(256) void agg1_kernel(const ushort* __restrict__ h1b,
                                                   const float* __restrict__ as1,
                                                   const float* __restrict__ ad1,
                                                   const int* __restrict__ off,
                                                   const int* __restrict__ csr,
                                                   const float* __restrict__ b1,
                                                   ushort* __restrict__ h2b) {
  int n = (blockIdx.x * 256 + threadIdx.x) >> 6;
  int lane = threadIdx.x & 63;
  int p0 = off[n], p1 = off[n + 1];

  int hl = lane & 31;          // position within half-wave
  int half = lane >> 5;        // edge slot parity
  int h8 = hl >> 2;            // head for my 8 channels
  int cb = hl * 8;             // channel base
  float ad = ad1[n * 8 + h8];

  float ssum = 0.f;
  float acc0 = 0.f, acc1 = 0.f, acc2 = 0.f, acc3 = 0.f;
  float acc4 = 0.f, acc5 = 0.f, acc6 = 0.f, acc7 = 0.f;

  int p = p0 + half;
  for (; p + 6 < p1; p += 8) {
    int s0 = csr[p], s1 = csr[p + 2], s2 = csr[p + 4], s3 = csr[p + 6];
    float e0 = as1[s0 * 8 + h8] + ad;
    float e1 = as1[s1 * 8 + h8] + ad;
    float e2 = as1[s2 * 8 + h8] + ad;
    float e3 = as1[s3 * 8 + h8] + ad;
    int4 r0 = *reinterpret_cast<const int4*>(h1b + (size_t)s0 * 256 + cb);
    int4 r1 = *reinterpret_cast<const int4*>(h1b + (size_t)s1 * 256 + cb);
    int4 r2 = *reinterpret_cast<const int4*>(h1b + (size_t)s2 * 256 + cb);
    int4 r3 = *reinterpret_cast<const int4*>(h1b + (size_t)s3 * 256 + cb);
    e0 = e0 > 0.f ? e0 : 0.2f * e0;
    e1 = e1 > 0.f ? e1 : 0.2f * e1;
    e2 = e2 > 0.f ? e2 : 0.2f * e2;
    e3 = e3 > 0.f ? e3 : 0.2f * e3;
    float w0 = __expf(e0), w1 = __expf(e1), w2 = __expf(e2), w3 = __expf(e3);
    ssum += (w0 + w1) + (w2 + w3);
    acc0 += w0 * bflo((unsigned)r0.x) + w1 * bflo((unsigned)r1.x)
          + w2 * bflo((unsigned)r2.x) + w3 * bflo((unsigned)r3.x);
    acc1 += w0 * bfhi((unsigned)r0.x) + w1 * bfhi((unsigned)r1.x)
          + w2 * bfhi((unsigned)r2.x) + w3 * bfhi((unsigned)r3.x);
    acc2 += w0 * bflo((unsigned)r0.y) + w1 * bflo((unsigned)r1.y)
          + w2 * bflo((unsigned)r2.y) + w3 * bflo((unsigned)r3.y);
    acc3 += w0 * bfhi((unsigned)r0.y) + w1 * bfhi((unsigned)r1.y)
          + w2 * bfhi((unsigned)r2.y) + w3 * bfhi((unsigned)r3.y);
    acc4 += w0 * bflo((unsigned)r0.z) + w1 * bflo((unsigned)r1.z)
          + w2 * bflo((unsigned)r2.z) + w3 * bflo((unsigned)r3.z);
    acc5 += w0 * bfhi((unsigned)r0.z) + w1 * bfhi((unsigned)r1.z)
          + w2 * bfhi((unsigned)r2.z) + w3 * bfhi((unsigned)r3.z);
    acc6 += w0 * bflo((unsigned)r0.w) + w1 * bflo((unsigned)r1.w)
          + w2 * bflo((unsigned)r2.w) + w3 * bflo((unsigned)r3.w);
    acc7 += w0 * bfhi((unsigned)r0.w) + w1 * bfhi((unsigned)r1.w)
          + w2 * bfhi((unsigned)r2.w) + w3 * bfhi((unsigned)r3.w);
  }
  for (; p < p1; p += 2) {
    int sA = csr[p];
    float eA = as1[sA * 8 + h8] + ad;
    int4 rA = *reinterpret_cast<const int4*>(h1b + (size_t)sA * 256 + cb);
    eA = eA > 0.f ? eA : 0.2f * eA;
    float wA = __expf(eA);
    ssum += wA;
    acc0 += wA * bflo((unsigned)rA.x); acc1 += wA * bfhi((unsigned)rA.x);
    acc2 += wA * bflo((unsigned)rA.y); acc3 += wA * bfhi((unsigned)rA.y);
    acc4 += wA * bflo((unsigned)rA.z); acc5 += wA * bfhi((unsigned)rA.z);
    acc6 += wA * bflo((unsigned)rA.w); acc7 += wA * bfhi((unsigned)rA.w);
  }
  // merge the two half-waves
  ssum += __shfl_xor(ssum, 32);
  acc0 += __shfl_xor(acc0, 32); acc1 += __shfl_xor(acc1, 32);
  acc2 += __shfl_xor(acc2, 32); acc3 += __shfl_xor(acc3, 32);
  acc4 += __shfl_xor(acc4, 32); acc5 += __shfl_xor(acc5, 32);
  acc6 += __shfl_xor(acc6, 32); acc7 += __shfl_xor(acc7, 32);

  if (half == 0) {
    float inv = 1.f / ssum;
    float o[8] = {acc0, acc1, acc2, acc3, acc4, acc5, acc6, acc7};
    float4 bA = *reinterpret_cast<const float4*>(b1 + cb);
    float4 bB = *reinterpret_cast<const float4*>(b1 + cb + 4);
    o[0] = o[0] * inv + bA.x; o[1] = o[1] * inv + bA.y;
    o[2] = o[2] * inv + bA.z; o[3] = o[3] * inv + bA.w;
    o[4] = o[4] * inv + bB.x; o[5] = o[5] * inv + bB.y;
    o[6] = o[6] * inv + bB.z; o[7] = o[7] * inv + bB.w;
#pragma unroll
    for (int c = 0; c < 8; ++c) o[c] = o[c] > 0.f ? o[c] : __expf(o[c]) - 1.f;
    int4 outv;
    outv.x = (int)(((unsigned)f2bf(o[1]) << 16) | f2bf(o[0]));
    outv.y = (int)(((unsigned)f2bf(o[3]) << 16) | f2bf(o[2]));
    outv.z = (int)(((unsigned)f2bf(o[5]) << 16) | f2bf(o[4]));
    outv.w = (int)(((unsigned)f2bf(o[7]) << 16) | f2bf(o[6]));
    *reinterpret_cast<int4*>(h2b + (size_t)n * 256 + cb) = outv;
  }
}

// ---------------------------------------------------------------------------
// layer-2 projection via MFMA: pj2p[50000][16] = h2 @ W2tp^T, + as2/ad2
// ---------------------------------------------------------------------------
__global__ __launch_bounds__(256) void proj2_mfma(const ushort* __restrict__ h2b,
                                                  const ushort* __restrict__ W2tp,
                                                  const float* __restrict__ asrc2,
                                                  const float* __restrict__ adst2,
                                                  float* __restrict__ pj2p,
                                                  float* __restrict__ as2,
                                                  float* __restrict__ ad2) {
  int wid = threadIdx.x >> 6, lane = threadIdx.x & 63;
  int r = lane & 15, kg = lane >> 4;
  int rb = blockIdx.x * 64 + wid * 16;
  int row_a = rb + r;
  if (row_a >= N_NODES) row_a = 0;
  const ushort* ap = h2b + (size_t)row_a * 256 + kg * 8;
  const ushort* bp = W2tp + (size_t)r * 256 + kg * 8;
  f32x4 acc = 0;
#pragma unroll
  for (int k0 = 0; k0 < 256; k0 += 32)
    acc = __builtin_amdgcn_mfma_f32_16x16x32_bf16(
        *reinterpret_cast<const bf16x8*>(ap + k0),
        *reinterpret_cast<const bf16x8*>(bp + k0), acc, 0, 0, 0);

  float av = (r < NCLS) ? asrc2[r] : 0.f;
  float dv = (r < NCLS) ? adst2[r] : 0.f;
#pragma unroll
  for (int q = 0; q < 4; ++q) {
    int row = rb + kg * 4 + q;
    float v = acc[q];
    if (row < N_NODES) pj2p[row * 16 + r] = v;
    float s = v * av, d = v * dv;
    s += __shfl_xor(s, 1); s += __shfl_xor(s, 2); s += __shfl_xor(s, 4); s += __shfl_xor(s, 8);
    d += __shfl_xor(d, 1); d += __shfl_xor(d, 2); d += __shfl_xor(d, 4); d += __shfl_xor(d, 8);
    if (r == 0 && row < N_NODES) { as2[row] = s; ad2[row] = d; }
  }
}

// ---------------------------------------------------------------------------
// layer-2 aggregation: single pass (no max), 4 edge slots x 16 channel lanes,
// 4 edges in flight per slot
// ---------------------------------------------------------------------------
__global__ __launch_bounds__(256) void agg2_kernel(const float* __restrict__ pj2p,
                                                   const float* __restrict__ as2,
                                                   const float* __restrict__ ad2,
                                                   const int* __restrict__ off,
                                                   const int* __restrict__ csr,
                                                   const float* __restrict__ b2,
                                                   float* __restrict__ out2p) {
  int n = (blockIdx.x * 256 + threadIdx.x) >> 6;
  int lane = threadIdx.x & 63;
  int p0 = off[n], p1 = off[n + 1];
  float ad = ad2[n];
  int es = lane >> 4, c = lane & 15;
  float ssum = 0.f, acc = 0.f;
  int p = p0 + es;
  for (; p + 12 < p1; p += 16) {
    int s0 = csr[p], s1 = csr[p + 4], s2 = csr[p + 8], s3 = csr[p + 12];
    float e0 = as2[s0] + ad, e1 = as2[s1] + ad, e2 = as2[s2] + ad, e3 = as2[s3] + ad;
    float v0 = pj2p[s0 * 16 + c], v1 = pj2p[s1 * 16 + c];
    float v2 = pj2p[s2 * 16 + c], v3 = pj2p[s3 * 16 + c];
    e0 = e0 > 0.f ? e0 : 0.2f * e0;
    e1 = e1 > 0.f ? e1 : 0.2f * e1;
    e2 = e2 > 0.f ? e2 : 0.2f * e2;
    e3 = e3 > 0.f ? e3 : 0.2f * e3;
    float w0 = __expf(e0), w1 = __expf(e1), w2 = __expf(e2), w3 = __expf(e3);
    ssum += (w0 + w1) + (w2 + w3);
    acc += (w0 * v0 + w1 * v1) + (w2 * v2 + w3 * v3);
  }
  for (; p < p1; p += 4) {
    int sA = csr[p];
    float eA = as2[sA] + ad;
    float vA = pj2p[sA * 16 + c];
    eA = eA > 0.f ? eA : 0.2f * eA;
    float wA = __expf(eA);
    ssum += wA;
    acc += wA * vA;
  }
  acc += __shfl_xor(acc, 16); acc += __shfl_xor(acc, 32);
  ssum += __shfl_xor(ssum, 16); ssum += __shfl_xor(ssum, 32);
  if (lane < 16) {
    float bc = (lane < NCLS) ? b2[lane] : 0.f;
    out2p[n * 16 + lane] = acc / ssum + bc;
  }
}

// ---------------------------------------------------------------------------
// global mean pool
// ---------------------------------------------------------------------------
__global__ __launch_bounds__(256) void pool_kernel(const float* __restrict__ out2p,
                                                   const int* __restrict__ batch,
                                                   float* __restrict__ outp) {
  __shared__ float red[256];
  int g = blockIdx.x;
  int lo = 0, hi = N_NODES;
  while (lo < hi) { int mid = (lo + hi) >> 1; if (batch[mid] < g) lo = mid + 1; else hi = mid; }
  int start = lo;
  hi = N_NODES;
  while (lo < hi) { int mid = (lo + hi) >> 1; if (batch[mid] < g + 1) lo = mid + 1; else hi = mid; }
  int end = lo;
  int t = threadIdx.x;
  int c = t & 15, nsl = t >> 4;
  float loc = 0.f;
  for (int nn = start + nsl; nn < end; nn += 16) loc += out2p[nn * 16 + c];
  red[t] = loc;
  __syncthreads();
  for (int s = 128; s >= 16; s >>= 1) {
    if (t < s) red[t] += red[t + s];
    __syncthreads();
  }
  if (t < NCLS) {
    float denom = fmaxf((float)(end - start), 1.f);
    outp[g * NCLS + t] = red[t] / denom;
  }
}

// ---------------------------------------------------------------------------
extern "C" void kernel_launch(void* const* d_in, const int* in_sizes, int n_in,
                              void* d_out, int out_size, void* d_ws, size_t ws_size,
                              hipStream_t stream) {
  const float* x      = (const float*)d_in[0];
  const float* W1     = (const float*)d_in[1];
  const float* a_src1 = (const float*)d_in[2];
  const float* a_dst1 = (const float*)d_in[3];
  const float* b1     = (const float*)d_in[4];
  const float* W2     = (const float*)d_in[5];
  const float* a_src2 = (const float*)d_in[6];
  const float* a_dst2 = (const float*)d_in[7];
  const float* b2     = (const float*)d_in[8];
  const int*   ei     = (const int*)d_in[9];
  const int*   batch  = (const int*)d_in[10];

  char* ws = (char*)d_ws;
  size_t o = 0;
  auto alloc = [&](size_t bytes) {
    char* p = ws + o;
    o = (o + bytes + 255) & ~(size_t)255;
    return p;
  };
  ushort* xb   = (ushort*)alloc((size_t)N_NODES * 256 * 2);
  ushort* w1t  = (ushort*)alloc((size_t)272 * 256 * 2);
  ushort* w2tp = (ushort*)alloc((size_t)16 * 256 * 2);
  ushort* h1b  = (ushort*)alloc((size_t)N_NODES * 256 * 2);
  ushort* h2b  = (ushort*)alloc((size_t)N_NODES * 256 * 2);
  float* as1   = (float*)alloc((size_t)N_NODES * 8 * 4);
  float* ad1   = (float*)alloc((size_t)N_NODES * 8 * 4);
  float* pj2p  = (float*)alloc((size_t)N_NODES * 16 * 4);
  float* as2   = (float*)alloc((size_t)N_NODES * 4);
  float* ad2   = (float*)alloc((size_t)N_NODES * 4);
  float* out2p = (float*)alloc((size_t)N_NODES * 16 * 4);
  int*   deg   = (int*)alloc((size_t)N_NODES * 4);
  int*   off   = (int*)alloc((size_t)(N_NODES + 1) * 4);
  int*   cur   = (int*)alloc((size_t)N_NODES * 4);
  int*   csr   = (int*)alloc((size_t)E_TOT * 4);
  int*   bsum  = (int*)alloc(256 * 4);

  hipMemsetAsync(deg, 0, (size_t)N_NODES * 4, stream);

  prep_kernel<<<PREP_BLOCKS, 256, 0, stream>>>((const float4*)x, (ushort4*)xb,
                                               W1, w1t, W2, w2tp, a_src1, a_dst1, ei, deg);
  gemm1_mfma<<<(N_NODES + 63) / 64, 256, 0, stream>>>(xb, w1t, h1b, as1, ad1);

  int nb = (N_NODES + 255) / 256;  // 196
  scan_block_kernel<<<nb, 256, 0, stream>>>(deg, off, bsum);
  scan_top_kernel<<<1, 256, 0, stream>>>(bsum, nb);
  scan_add_kernel<<<nb, 256, 0, stream>>>(off, bsum, cur);
  scatter_kernel<<<(E_TOT + 255) / 256, 256, 0, stream>>>(ei, cur, csr);

  agg1_kernel<<<N_NODES / 4, 256, 0, stream>>>(h1b, as1, ad1, off, csr, b1, h2b);
  proj2_mfma<<<(N_NODES + 63) / 64, 256, 0, stream>>>(h2b, w2tp, a_src2, a_dst2,
                                                      pj2p, as2, ad2);
  agg2_kernel<<<N_NODES / 4, 256, 0, stream>>>(pj2p, as2, ad2, off, csr, b2, out2p);
  pool_kernel<<<NGRP, 256, 0, stream>>>(out2p, batch, (float*)d_out);
}

// Round 5
// 329.860 us; speedup vs baseline: 1.6500x; 1.0563x over previous
//
#include <hip/hip_runtime.h>
#include <hip/hip_bf16.h>
#include <hip/hip_fp8.h>
#include <math.h>

#define N_NODES 50000
#define N_EDGES 800000
#define E_TOT   (N_EDGES + N_NODES)   /* 850000 with self loops */
#define NCLS 10
#define NGRP 128

typedef __attribute__((ext_vector_type(8))) short bf16x8;
typedef __attribute__((ext_vector_type(4))) float f32x4;

static __device__ __forceinline__ ushort f2bf(float f) {
  union { float f; unsigned u; } v; v.f = f;
  unsigned r = v.u + 0x7fffu + ((v.u >> 16) & 1u);   // round-to-nearest-even
  return (ushort)(r >> 16);
}
static __device__ __forceinline__ float bf2f(ushort u) {
  union { unsigned u; float f; } v; v.u = ((unsigned)u) << 16; return v.f;
}
static __device__ __forceinline__ unsigned char enc8(float v) {
  __hip_fp8_e4m3 t(v);
  return (unsigned char)t.__x;
}
static __device__ __forceinline__ float4 dec4(unsigned u) {
  __hip_fp8x4_e4m3 q; q.__x = u;
  return (float4)q;
}

// ---------------------------------------------------------------------------
// prep: cast x -> bf16 | W1 -> W1t bf16 rows [0,256) | W2 -> W2tp bf16 [16][256]
//       | Wa = W1 @ a_{src,dst} -> W1t rows [256,272) | deg count
// ---------------------------------------------------------------------------
#define CAST_BLOCKS 12500
#define W1T_BASE 12500
#define W2T_BASE 12564
#define WA_BASE  12565
#define DEG_BASE 12566
#define DEG_BLOCKS ((E_TOT + 255) / 256)
#define PREP_BLOCKS (DEG_BASE + DEG_BLOCKS)

__global__ __launch_bounds__(256) void prep_kernel(const float4* __restrict__ X4,
                                                   ushort4* __restrict__ Xb,
                                                   const float* __restrict__ W1,
                                                   ushort* __restrict__ W1t,
                                                   const float* __restrict__ W2,
                                                   ushort* __restrict__ W2tp,
                                                   const float* __restrict__ asrc1,
                                                   const float* __restrict__ adst1,
                                                   const int* __restrict__ ei,
                                                   int* __restrict__ deg) {
  int b = blockIdx.x;
  int tid = threadIdx.x;
  if (b < CAST_BLOCKS) {
    int i = b * 256 + tid;
    float4 v = X4[i];
    ushort4 o;
    o.x = f2bf(v.x); o.y = f2bf(v.y); o.z = f2bf(v.z); o.w = f2bf(v.w);
    Xb[i] = o;
  } else if (b < W2T_BASE) {
    __shared__ float t[32][33];
    int bb = b - W1T_BASE;
    int k0 = (bb >> 3) * 32, n0 = (bb & 7) * 32;
    int tx = tid & 31, ty = tid >> 5;  // ty 0..7
    for (int r = 0; r < 32; r += 8)
      t[ty + r][tx] = W1[(k0 + ty + r) * 256 + n0 + tx];
    __syncthreads();
    for (int r = 0; r < 32; r += 8)
      W1t[(n0 + ty + r) * 256 + k0 + tx] = f2bf(t[tx][ty + r]);
  } else if (b == W2T_BASE) {
    int k = tid;  // 0..255
#pragma unroll
    for (int c = 0; c < 16; ++c)
      W2tp[c * 256 + k] = (c < NCLS) ? f2bf(W2[k * NCLS + c]) : (ushort)0;
  } else if (b == WA_BASE) {
    int k = tid;  // 0..255
    const float* wrow = W1 + k * 256;
#pragma unroll
    for (int h = 0; h < 8; ++h) {
      float s = 0.f, d = 0.f;
#pragma unroll
      for (int c = 0; c < 32; ++c) {
        float w = wrow[h * 32 + c];
        s += w * asrc1[h * 32 + c];
        d += w * adst1[h * 32 + c];
      }
      W1t[(256 + h) * 256 + k] = f2bf(s);
      W1t[(264 + h) * 256 + k] = f2bf(d);
    }
  } else {
    int i = (b - DEG_BASE) * 256 + tid;
    if (i < E_TOT) {
      int d = (i < N_EDGES) ? ei[N_EDGES + i] : (i - N_EDGES);
      atomicAdd(&deg[d], 1);
    }
  }
}

// ---------------------------------------------------------------------------
// GEMM1 MFMA: h1 = x @ W1 (bf16 in, FP8 e4m3 out for the gather), plus fused
// as1/ad1 = x @ Wa (cols 256..271, computed by wave 3 as a 5th fragment)
// ---------------------------------------------------------------------------
__global__ __launch_bounds__(256) void gemm1_mfma(const ushort* __restrict__ Xb,
                                                  const ushort* __restrict__ W1t,
                                                  unsigned char* __restrict__ h1f8,
                                                  float* __restrict__ as1,
                                                  float* __restrict__ ad1) {
  int wid = threadIdx.x >> 6, lane = threadIdx.x & 63;
  int r = lane & 15, kg = lane >> 4;
  int m0 = blockIdx.x * 64;
  int n0 = wid * 64;
  bool extra = (wid == 3);
  f32x4 acc[4][4];
  f32x4 accE[4];
#pragma unroll
  for (int mi = 0; mi < 4; ++mi) {
#pragma unroll
    for (int ni = 0; ni < 4; ++ni) acc[mi][ni] = 0;
    accE[mi] = 0;
  }

  const ushort* aptr[4];
#pragma unroll
  for (int mi = 0; mi < 4; ++mi) {
    int row = m0 + mi * 16 + r;
    if (row >= N_NODES) row = 0;
    aptr[mi] = Xb + (size_t)row * 256 + kg * 8;
  }
  const ushort* bptr[4];
#pragma unroll
  for (int ni = 0; ni < 4; ++ni)
    bptr[ni] = W1t + (size_t)(n0 + ni * 16 + r) * 256 + kg * 8;
  const ushort* bptrE = W1t + (size_t)(256 + r) * 256 + kg * 8;

#pragma unroll 2
  for (int k0 = 0; k0 < 256; k0 += 32) {
    bf16x8 a[4], b[4], bE;
#pragma unroll
    for (int mi = 0; mi < 4; ++mi)
      a[mi] = *reinterpret_cast<const bf16x8*>(aptr[mi] + k0);
#pragma unroll
    for (int ni = 0; ni < 4; ++ni)
      b[ni] = *reinterpret_cast<const bf16x8*>(bptr[ni] + k0);
    if (extra) bE = *reinterpret_cast<const bf16x8*>(bptrE + k0);
#pragma unroll
    for (int mi = 0; mi < 4; ++mi) {
#pragma unroll
      for (int ni = 0; ni < 4; ++ni)
        acc[mi][ni] = __builtin_amdgcn_mfma_f32_16x16x32_bf16(a[mi], b[ni], acc[mi][ni], 0, 0, 0);
      if (extra)
        accE[mi] = __builtin_amdgcn_mfma_f32_16x16x32_bf16(a[mi], bE, accE[mi], 0, 0, 0);
    }
  }

#pragma unroll
  for (int mi = 0; mi < 4; ++mi) {
#pragma unroll
    for (int q = 0; q < 4; ++q) {
      int row = m0 + mi * 16 + kg * 4 + q;
      if (row < N_NODES) {
#pragma unroll
        for (int ni = 0; ni < 4; ++ni)
          h1f8[(size_t)row * 256 + n0 + ni * 16 + r] = enc8(acc[mi][ni][q]);
        if (extra) {
          float* dst = (r < 8) ? (as1 + row * 8 + r) : (ad1 + row * 8 + (r & 7));
          *dst = accE[mi][q];
        }
      }
    }
  }
}

// ---------------------------------------------------------------------------
// CSR scan + scatter (scan_top fused into scan_add: every block redundantly
// scans the 196 block sums in LDS)
// ---------------------------------------------------------------------------
__global__ __launch_bounds__(256) void scan_block_kernel(const int* __restrict__ deg,
                                                         int* __restrict__ off,
                                                         int* __restrict__ bsum) {
  __shared__ int sh[256];
  int tid = threadIdx.x;
  int i = blockIdx.x * 256 + tid;
  int v = (i < N_NODES) ? deg[i] : 0;
  sh[tid] = v;
  __syncthreads();
  for (int d = 1; d < 256; d <<= 1) {
    int t = (tid >= d) ? sh[tid - d] : 0;
    __syncthreads();
    sh[tid] += t;
    __syncthreads();
  }
  if (i < N_NODES) off[i] = sh[tid] - v;
  if (tid == 255) bsum[blockIdx.x] = sh[255];
}

__global__ __launch_bounds__(256) void scan_addtop_kernel(int* __restrict__ off,
                                                          const int* __restrict__ bsum,
                                                          int* __restrict__ cursor,
                                                          int NB) {
  __shared__ int sh[256];
  int tid = threadIdx.x;
  int v = (tid < NB) ? bsum[tid] : 0;
  sh[tid] = v;
  __syncthreads();
  for (int d = 1; d < 256; d <<= 1) {
    int t = (tid >= d) ? sh[tid - d] : 0;
    __syncthreads();
    sh[tid] += t;
    __syncthreads();
  }
  int pfx = sh[blockIdx.x] - bsum[blockIdx.x];  // exclusive prefix of this block
  int i = blockIdx.x * 256 + tid;
  if (i < N_NODES) {
    int val = off[i] + pfx;
    off[i] = val;
    cursor[i] = val;
  }
  if (i == 0) off[N_NODES] = E_TOT;
}

__global__ __launch_bounds__(256) void scatter_kernel(const int* __restrict__ ei,
                                                      int* __restrict__ cursor,
                                                      int* __restrict__ csr) {
  int i = blockIdx.x * 256 + threadIdx.x;
  if (i < E_TOT) {
    int s = (i < N_EDGES) ? ei[i] : (i - N_EDGES);
    int d = (i < N_EDGES) ? ei[N_EDGES + i] : (i - N_EDGES);
    int pos = atomicAdd(&cursor[d], 1);
    csr[pos] = s;
  }
}

// ---------------------------------------------------------------------------
// layer-1 aggregation + bias + elu -> h2 (bf16). h1 gathered as FP8 e4m3.
// Wave per dst node: 4 edge slots x 16 channel lanes (16 ch each), 2-unroll
// => 8 edges in flight.
// ---------------------------------------------------------------------------
__global__ __launch_bounds__(256) void agg1_kernel(const unsigned char* __restrict__ h1f8,
                                                   const float* __restrict__ as1,
                                                   const float* __restrict__ ad1,
                                                   const int* __restrict__ off,
                                                   const int* __restrict__ csr,
                                                   const float* __restrict__ b1,
                                                   ushort* __restrict__ h2b) {
  int n = (blockIdx.x * 256 + threadIdx.x) >> 6;
  int lane = threadIdx.x & 63;
  int p0 = off[n], p1 = off[n + 1];

  int sl = lane >> 4;          // edge slot 0..3
  int cl = lane & 15;          // channel group
  int cb = cl * 16;            // channel base (16 channels per lane)
  int h = cl >> 1;             // head = channel/32
  float ad = ad1[n * 8 + h];

  float ssum = 0.f;
  float acc[16] = {};

  int p = p0 + sl;
  for (; p + 4 < p1; p += 8) {
    int sA = csr[p], sB = csr[p + 4];
    float eA = as1[sA * 8 + h] + ad;
    float eB = as1[sB * 8 + h] + ad;
    uint4 rA = *reinterpret_cast<const uint4*>(h1f8 + (size_t)sA * 256 + cb);
    uint4 rB = *reinterpret_cast<const uint4*>(h1f8 + (size_t)sB * 256 + cb);
    eA = eA > 0.f ? eA : 0.2f * eA;
    eB = eB > 0.f ? eB : 0.2f * eB;
    float wA = __expf(eA), wB = __expf(eB);
    ssum += wA + wB;
    float4 a0 = dec4(rA.x), a1 = dec4(rA.y), a2 = dec4(rA.z), a3 = dec4(rA.w);
    float4 c0 = dec4(rB.x), c1 = dec4(rB.y), c2 = dec4(rB.z), c3 = dec4(rB.w);
    acc[0]  += wA * a0.x + wB * c0.x;  acc[1]  += wA * a0.y + wB * c0.y;
    acc[2]  += wA * a0.z + wB * c0.z;  acc[3]  += wA * a0.w + wB * c0.w;
    acc[4]  += wA * a1.x + wB * c1.x;  acc[5]  += wA * a1.y + wB * c1.y;
    acc[6]  += wA * a1.z + wB * c1.z;  acc[7]  += wA * a1.w + wB * c1.w;
    acc[8]  += wA * a2.x + wB * c2.x;  acc[9]  += wA * a2.y + wB * c2.y;
    acc[10] += wA * a2.z + wB * c2.z;  acc[11] += wA * a2.w + wB * c2.w;
    acc[12] += wA * a3.x + wB * c3.x;  acc[13] += wA * a3.y + wB * c3.y;
    acc[14] += wA * a3.z + wB * c3.z;  acc[15] += wA * a3.w + wB * c3.w;
  }
  for (; p < p1; p += 4) {
    int sA = csr[p];
    float eA = as1[sA * 8 + h] + ad;
    uint4 rA = *reinterpret_cast<const uint4*>(h1f8 + (size_t)sA * 256 + cb);
    eA = eA > 0.f ? eA : 0.2f * eA;
    float wA = __expf(eA);
    ssum += wA;
    float4 a0 = dec4(rA.x), a1 = dec4(rA.y), a2 = dec4(rA.z), a3 = dec4(rA.w);
    acc[0]  += wA * a0.x;  acc[1]  += wA * a0.y;
    acc[2]  += wA * a0.z;  acc[3]  += wA * a0.w;
    acc[4]  += wA * a1.x;  acc[5]  += wA * a1.y;
    acc[6]  += wA * a1.z;  acc[7]  += wA * a1.w;
    acc[8]  += wA * a2.x;  acc[9]  += wA * a2.y;
    acc[10] += wA * a2.z;  acc[11] += wA * a2.w;
    acc[12] += wA * a3.x;  acc[13] += wA * a3.y;
    acc[14] += wA * a3.z;  acc[15] += wA * a3.w;
  }

  // reduce across the 4 edge slots
  ssum += __shfl_xor(ssum, 16); ssum += __shfl_xor(ssum, 32);
#pragma unroll
  for (int c = 0; c < 16; ++c) {
    acc[c] += __shfl_xor(acc[c], 16);
    acc[c] += __shfl_xor(acc[c], 32);
  }

  if (sl == 0) {
    float inv = 1.f / ssum;
    float o[16];
    float4 b0 = *reinterpret_cast<const float4*>(b1 + cb);
    float4 b1v = *reinterpret_cast<const float4*>(b1 + cb + 4);
    float4 b2v = *reinterpret_cast<const float4*>(b1 + cb + 8);
    float4 b3v = *reinterpret_cast<const float4*>(b1 + cb + 12);
    float bb[16] = {b0.x, b0.y, b0.z, b0.w, b1v.x, b1v.y, b1v.z, b1v.w,
                    b2v.x, b2v.y, b2v.z, b2v.w, b3v.x, b3v.y, b3v.z, b3v.w};
#pragma unroll
    for (int c = 0; c < 16; ++c) {
      float v = acc[c] * inv + bb[c];
      o[c] = v > 0.f ? v : __expf(v) - 1.f;
    }
    int4 o0, o1;
    o0.x = (int)(((unsigned)f2bf(o[1]) << 16) | f2bf(o[0]));
    o0.y = (int)(((unsigned)f2bf(o[3]) << 16) | f2bf(o[2]));
    o0.z = (int)(((unsigned)f2bf(o[5]) << 16) | f2bf(o[4]));
    o0.w = (int)(((unsigned)f2bf(o[7]) << 16) | f2bf(o[6]));
    o1.x = (int)(((unsigned)f2bf(o[9]) << 16) | f2bf(o[8]));
    o1.y = (int)(((unsigned)f2bf(o[11]) << 16) | f2bf(o[10]));
    o1.z = (int)(((unsigned)f2bf(o[13]) << 16) | f2bf(o[12]));
    o1.w = (int)(((unsigned)f2bf(o[15]) << 16) | f2bf(o[14]));
    *reinterpret_cast<int4*>(h2b + (size_t)n * 256 + cb) = o0;
    *reinterpret_cast<int4*>(h2b + (size_t)n * 256 + cb + 8) = o1;
  }
}

// ---------------------------------------------------------------------------
// layer-2 projection via MFMA: pj2p[50000][16] = h2 @ W2tp^T, + as2/ad2
// ---------------------------------------------------------------------------
__global__ __launch_bounds__(256) void proj2_mfma(const ushort* __restrict__ h2b,
                                                  const ushort* __restrict__ W2tp,
                                                  const float* __restrict__ asrc2,
                                                  const float* __restrict__ adst2,
                                                  float* __restrict__ pj2p,
                                                  float* __restrict__ as2,
                                                  float* __restrict__ ad2) {
  int wid = threadIdx.x >> 6, lane = threadIdx.x & 63;
  int r = lane & 15, kg = lane >> 4;
  int rb = blockIdx.x * 64 + wid * 16;
  int row_a = rb + r;
  if (row_a >= N_NODES) row_a = 0;
  const ushort* ap = h2b + (size_t)row_a * 256 + kg * 8;
  const ushort* bp = W2tp + (size_t)r * 256 + kg * 8;
  f32x4 acc = 0;
#pragma unroll
  for (int k0 = 0; k0 < 256; k0 += 32)
    acc = __builtin_amdgcn_mfma_f32_16x16x32_bf16(
        *reinterpret_cast<const bf16x8*>(ap + k0),
        *reinterpret_cast<const bf16x8*>(bp + k0), acc, 0, 0, 0);

  float av = (r < NCLS) ? asrc2[r] : 0.f;
  float dv = (r < NCLS) ? adst2[r] : 0.f;
#pragma unroll
  for (int q = 0; q < 4; ++q) {
    int row = rb + kg * 4 + q;
    float v = acc[q];
    if (row < N_NODES) pj2p[row * 16 + r] = v;
    float s = v * av, d = v * dv;
    s += __shfl_xor(s, 1); s += __shfl_xor(s, 2); s += __shfl_xor(s, 4); s += __shfl_xor(s, 8);
    d += __shfl_xor(d, 1); d += __shfl_xor(d, 2); d += __shfl_xor(d, 4); d += __shfl_xor(d, 8);
    if (r == 0 && row < N_NODES) { as2[row] = s; ad2[row] = d; }
  }
}

// ---------------------------------------------------------------------------
// layer-2 aggregation: single pass (no max), 4 edge slots x 16 channel lanes,
// 4 edges in flight per slot
// ---------------------------------------------------------------------------
__global__ __launch_bounds__(256) void agg2_kernel(const float* __restrict__ pj2p,
                                                   const float* __restrict__ as2,
                                                   const float* __restrict__ ad2,
                                                   const int* __restrict__ off,
                                                   const int* __restrict__ csr,
                                                   const float* __restrict__ b2,
                                                   float* __restrict__ out2p) {
  int n = (blockIdx.x * 256 + threadIdx.x) >> 6;
  int lane = threadIdx.x & 63;
  int p0 = off[n], p1 = off[n + 1];
  float ad = ad2[n];
  int es = lane >> 4, c = lane & 15;
  float ssum = 0.f, acc = 0.f;
  int p = p0 + es;
  for (; p + 12 < p1; p += 16) {
    int s0 = csr[p], s1 = csr[p + 4], s2 = csr[p + 8], s3 = csr[p + 12];
    float e0 = as2[s0] + ad, e1 = as2[s1] + ad, e2 = as2[s2] + ad, e3 = as2[s3] + ad;
    float v0 = pj2p[s0 * 16 + c], v1 = pj2p[s1 * 16 + c];
    float v2 = pj2p[s2 * 16 + c], v3 = pj2p[s3 * 16 + c];
    e0 = e0 > 0.f ? e0 : 0.2f * e0;
    e1 = e1 > 0.f ? e1 : 0.2f * e1;
    e2 = e2 > 0.f ? e2 : 0.2f * e2;
    e3 = e3 > 0.f ? e3 : 0.2f * e3;
    float w0 = __expf(e0), w1 = __expf(e1), w2 = __expf(e2), w3 = __expf(e3);
    ssum += (w0 + w1) + (w2 + w3);
    acc += (w0 * v0 + w1 * v1) + (w2 * v2 + w3 * v3);
  }
  for (; p < p1; p += 4) {
    int sA = csr[p];
    float eA = as2[sA] + ad;
    float vA = pj2p[sA * 16 + c];
    eA = eA > 0.f ? eA : 0.2f * eA;
    float wA = __expf(eA);
    ssum += wA;
    acc += wA * vA;
  }
  acc += __shfl_xor(acc, 16); acc += __shfl_xor(acc, 32);
  ssum += __shfl_xor(ssum, 16); ssum += __shfl_xor(ssum, 32);
  if (lane < 16) {
    float bc = (lane < NCLS) ? b2[lane] : 0.f;
    out2p[n * 16 + lane] = acc / ssum + bc;
  }
}

// ---------------------------------------------------------------------------
// global mean pool
// ---------------------------------------------------------------------------
__global__ __launch_bounds__(256) void pool_kernel(const float* __restrict__ out2p,
                                                   const int* __restrict__ batch,
                                                   float* __restrict__ outp) {
  __shared__ float red[256];
  int g = blockIdx.x;
  int lo = 0, hi = N_NODES;
  while (lo < hi) { int mid = (lo + hi) >> 1; if (batch[mid] < g) lo = mid + 1; else hi = mid; }
  int start = lo;
  hi = N_NODES;
  while (lo < hi) { int mid = (lo + hi) >> 1; if (batch[mid] < g + 1) lo = mid + 1; else hi = mid; }
  int end = lo;
  int t = threadIdx.x;
  int c = t & 15, nsl = t >> 4;
  float loc = 0.f;
  for (int nn = start + nsl; nn < end; nn += 16) loc += out2p[nn * 16 + c];
  red[t] = loc;
  __syncthreads();
  for (int s = 128; s >= 16; s >>= 1) {
    if (t < s) red[t] += red[t + s];
    __syncthreads();
  }
  if (t < NCLS) {
    float denom = fmaxf((float)(end - start), 1.f);
    outp[g * NCLS + t] = red[t] / denom;
  }
}

// ---------------------------------------------------------------------------
extern "C" void kernel_launch(void* const* d_in, const int* in_sizes, int n_in,
                              void* d_out, int out_size, void* d_ws, size_t ws_size,
                              hipStream_t stream) {
  const float* x      = (const float*)d_in[0];
  const float* W1     = (const float*)d_in[1];
  const float* a_src1 = (const float*)d_in[2];
  const float* a_dst1 = (const float*)d_in[3];
  const float* b1     = (const float*)d_in[4];
  const float* W2     = (const float*)d_in[5];
  const float* a_src2 = (const float*)d_in[6];
  const float* a_dst2 = (const float*)d_in[7];
  const float* b2     = (const float*)d_in[8];
  const int*   ei     = (const int*)d_in[9];
  const int*   batch  = (const int*)d_in[10];

  char* ws = (char*)d_ws;
  size_t o = 0;
  auto alloc = [&](size_t bytes) {
    char* p = ws + o;
    o = (o + bytes + 255) & ~(size_t)255;
    return p;
  };
  ushort* xb   = (ushort*)alloc((size_t)N_NODES * 256 * 2);
  ushort* w1t  = (ushort*)alloc((size_t)272 * 256 * 2);
  ushort* w2tp = (ushort*)alloc((size_t)16 * 256 * 2);
  unsigned char* h1f8 = (unsigned char*)alloc((size_t)N_NODES * 256);
  ushort* h2b  = (ushort*)alloc((size_t)N_NODES * 256 * 2);
  float* as1   = (float*)alloc((size_t)N_NODES * 8 * 4);
  float* ad1   = (float*)alloc((size_t)N_NODES * 8 * 4);
  float* pj2p  = (float*)alloc((size_t)N_NODES * 16 * 4);
  float* as2   = (float*)alloc((size_t)N_NODES * 4);
  float* ad2   = (float*)alloc((size_t)N_NODES * 4);
  float* out2p = (float*)alloc((size_t)N_NODES * 16 * 4);
  int*   deg   = (int*)alloc((size_t)N_NODES * 4);
  int*   off   = (int*)alloc((size_t)(N_NODES + 1) * 4);
  int*   cur   = (int*)alloc((size_t)N_NODES * 4);
  int*   csr   = (int*)alloc((size_t)E_TOT * 4);
  int*   bsum  = (int*)alloc(256 * 4);

  hipMemsetAsync(deg, 0, (size_t)N_NODES * 4, stream);

  prep_kernel<<<PREP_BLOCKS, 256, 0, stream>>>((const float4*)x, (ushort4*)xb,
                                               W1, w1t, W2, w2tp, a_src1, a_dst1, ei, deg);
  gemm1_mfma<<<(N_NODES + 63) / 64, 256, 0, stream>>>(xb, w1t, h1f8, as1, ad1);

  int nb = (N_NODES + 255) / 256;  // 196
  scan_block_kernel<<<nb, 256, 0, stream>>>(deg, off, bsum);
  scan_addtop_kernel<<<nb, 256, 0, stream>>>(off, bsum, cur, nb);
  scatter_kernel<<<(E_TOT + 255) / 256, 256, 0, stream>>>(ei, cur, csr);

  agg1_kernel<<<N_NODES / 4, 256, 0, stream>>>(h1f8, as1, ad1, off, csr, b1, h2b);
  proj2_mfma<<<(N_NODES + 63) / 64, 256, 0, stream>>>(h2b, w2tp, a_src2, a_dst2,
                                                      pj2p, as2, ad2);
  agg2_kernel<<<N_NODES / 4, 256, 0, stream>>>(pj2p, as2, ad2, off, csr, b2, out2p);
  pool_kernel<<<NGRP, 256, 0, stream>>>(out2p, batch, (float*)d_out);
}

// Round 6
// 289.841 us; speedup vs baseline: 1.8778x; 1.1381x over previous
//
#include <hip/hip_runtime.h>
#include <hip/hip_bf16.h>
#include <hip/hip_fp8.h>
#include <math.h>

#define N_NODES 50000
#define N_EDGES 800000
#define E_TOT   (N_EDGES + N_NODES)   /* 850000 with self loops */
#define NCLS 10
#define NGRP 128
#define BCAP 64                        /* bucket capacity; P(deg>64) ~ 1e-20 */

typedef __attribute__((ext_vector_type(8))) short bf16x8;
typedef __attribute__((ext_vector_type(4))) float f32x4;

static __device__ __forceinline__ ushort f2bf(float f) {
  union { float f; unsigned u; } v; v.f = f;
  unsigned r = v.u + 0x7fffu + ((v.u >> 16) & 1u);   // round-to-nearest-even
  return (ushort)(r >> 16);
}
static __device__ __forceinline__ float bf2f(ushort u) {
  union { unsigned u; float f; } v; v.u = ((unsigned)u) << 16; return v.f;
}
static __device__ __forceinline__ unsigned char enc8(float v) {
  __hip_fp8_e4m3 t(v);
  return (unsigned char)t.__x;
}
static __device__ __forceinline__ float4 dec4(unsigned u) {
  __hip_fp8x4_e4m3 q; q.__x = u;
  return (float4)q;
}

// ---------------------------------------------------------------------------
// prep: cast x -> bf16 | W1 -> W1t bf16 rows [0,256) | W2 -> W2tp bf16 [16][256]
//       | Wa = W1 @ a_{src,dst} -> W1t rows [256,272)
// ---------------------------------------------------------------------------
#define CAST_BLOCKS 12500
#define W1T_BASE 12500
#define W2T_BASE 12564
#define WA_BASE  12565
#define PREP_BLOCKS 12566

__global__ __launch_bounds__(256) void prep_kernel(const float4* __restrict__ X4,
                                                   ushort4* __restrict__ Xb,
                                                   const float* __restrict__ W1,
                                                   ushort* __restrict__ W1t,
                                                   const float* __restrict__ W2,
                                                   ushort* __restrict__ W2tp,
                                                   const float* __restrict__ asrc1,
                                                   const float* __restrict__ adst1) {
  int b = blockIdx.x;
  int tid = threadIdx.x;
  if (b < CAST_BLOCKS) {
    int i = b * 256 + tid;
    float4 v = X4[i];
    ushort4 o;
    o.x = f2bf(v.x); o.y = f2bf(v.y); o.z = f2bf(v.z); o.w = f2bf(v.w);
    Xb[i] = o;
  } else if (b < W2T_BASE) {
    __shared__ float t[32][33];
    int bb = b - W1T_BASE;
    int k0 = (bb >> 3) * 32, n0 = (bb & 7) * 32;
    int tx = tid & 31, ty = tid >> 5;  // ty 0..7
    for (int r = 0; r < 32; r += 8)
      t[ty + r][tx] = W1[(k0 + ty + r) * 256 + n0 + tx];
    __syncthreads();
    for (int r = 0; r < 32; r += 8)
      W1t[(n0 + ty + r) * 256 + k0 + tx] = f2bf(t[tx][ty + r]);
  } else if (b == W2T_BASE) {
    int k = tid;  // 0..255
#pragma unroll
    for (int c = 0; c < 16; ++c)
      W2tp[c * 256 + k] = (c < NCLS) ? f2bf(W2[k * NCLS + c]) : (ushort)0;
  } else {
    int k = tid;  // 0..255
    const float* wrow = W1 + k * 256;
#pragma unroll
    for (int h = 0; h < 8; ++h) {
      float s = 0.f, d = 0.f;
#pragma unroll
      for (int c = 0; c < 32; ++c) {
        float w = wrow[h * 32 + c];
        s += w * asrc1[h * 32 + c];
        d += w * adst1[h * 32 + c];
      }
      W1t[(256 + h) * 256 + k] = f2bf(s);
      W1t[(264 + h) * 256 + k] = f2bf(d);
    }
  }
}

// ---------------------------------------------------------------------------
// fused: [0, SCAT_BLOCKS) scatter edges into fixed-capacity buckets
//        [SCAT_BLOCKS, +GEMM_BLOCKS) gemm1 MFMA (h1 fp8 out + fused as1/ad1)
// scatter is latency/atomic-bound and mostly idle -> hides under gemm compute
// ---------------------------------------------------------------------------
#define SCAT_BLOCKS 768
#define GEMM_BLOCKS ((N_NODES + 63) / 64)

__global__ __launch_bounds__(256) void gemm1_scatter(const ushort* __restrict__ Xb,
                                                     const ushort* __restrict__ W1t,
                                                     unsigned char* __restrict__ h1f8,
                                                     float* __restrict__ as1,
                                                     float* __restrict__ ad1,
                                                     const int* __restrict__ ei,
                                                     int* __restrict__ cnt,
                                                     int* __restrict__ bkt) {
  if (blockIdx.x < SCAT_BLOCKS) {
    for (int i = blockIdx.x * 256 + threadIdx.x; i < E_TOT; i += SCAT_BLOCKS * 256) {
      int s = (i < N_EDGES) ? ei[i] : (i - N_EDGES);
      int d = (i < N_EDGES) ? ei[N_EDGES + i] : (i - N_EDGES);
      int slot = atomicAdd(&cnt[d], 1);
      if (slot < BCAP) bkt[(size_t)d * BCAP + slot] = s;
    }
    return;
  }
  int blk = blockIdx.x - SCAT_BLOCKS;
  int wid = threadIdx.x >> 6, lane = threadIdx.x & 63;
  int r = lane & 15, kg = lane >> 4;
  int m0 = blk * 64;
  int n0 = wid * 64;
  bool extra = (wid == 3);
  f32x4 acc[4][4];
  f32x4 accE[4];
#pragma unroll
  for (int mi = 0; mi < 4; ++mi) {
#pragma unroll
    for (int ni = 0; ni < 4; ++ni) acc[mi][ni] = 0;
    accE[mi] = 0;
  }

  const ushort* aptr[4];
#pragma unroll
  for (int mi = 0; mi < 4; ++mi) {
    int row = m0 + mi * 16 + r;
    if (row >= N_NODES) row = 0;
    aptr[mi] = Xb + (size_t)row * 256 + kg * 8;
  }
  const ushort* bptr[4];
#pragma unroll
  for (int ni = 0; ni < 4; ++ni)
    bptr[ni] = W1t + (size_t)(n0 + ni * 16 + r) * 256 + kg * 8;
  const ushort* bptrE = W1t + (size_t)(256 + r) * 256 + kg * 8;

#pragma unroll 2
  for (int k0 = 0; k0 < 256; k0 += 32) {
    bf16x8 a[4], b[4], bE;
#pragma unroll
    for (int mi = 0; mi < 4; ++mi)
      a[mi] = *reinterpret_cast<const bf16x8*>(aptr[mi] + k0);
#pragma unroll
    for (int ni = 0; ni < 4; ++ni)
      b[ni] = *reinterpret_cast<const bf16x8*>(bptr[ni] + k0);
    if (extra) bE = *reinterpret_cast<const bf16x8*>(bptrE + k0);
#pragma unroll
    for (int mi = 0; mi < 4; ++mi) {
#pragma unroll
      for (int ni = 0; ni < 4; ++ni)
        acc[mi][ni] = __builtin_amdgcn_mfma_f32_16x16x32_bf16(a[mi], b[ni], acc[mi][ni], 0, 0, 0);
      if (extra)
        accE[mi] = __builtin_amdgcn_mfma_f32_16x16x32_bf16(a[mi], bE, accE[mi], 0, 0, 0);
    }
  }

#pragma unroll
  for (int mi = 0; mi < 4; ++mi) {
#pragma unroll
    for (int q = 0; q < 4; ++q) {
      int row = m0 + mi * 16 + kg * 4 + q;
      if (row < N_NODES) {
#pragma unroll
        for (int ni = 0; ni < 4; ++ni)
          h1f8[(size_t)row * 256 + n0 + ni * 16 + r] = enc8(acc[mi][ni][q]);
        if (extra) {
          float* dst = (r < 8) ? (as1 + row * 8 + r) : (ad1 + row * 8 + (r & 7));
          *dst = accE[mi][q];
        }
      }
    }
  }
}

// ---------------------------------------------------------------------------
// layer-1 aggregation + bias + elu -> h2 (bf16). h1 gathered as FP8 e4m3
// from fixed-capacity buckets. 4 edge slots x 16 channel lanes, 2-unroll.
// ---------------------------------------------------------------------------
__global__ __launch_bounds__(256) void agg1_kernel(const unsigned char* __restrict__ h1f8,
                                                   const float* __restrict__ as1,
                                                   const float* __restrict__ ad1,
                                                   const int* __restrict__ cnt,
                                                   const int* __restrict__ bkt,
                                                   const float* __restrict__ b1,
                                                   ushort* __restrict__ h2b) {
  int n = (blockIdx.x * 256 + threadIdx.x) >> 6;
  int lane = threadIdx.x & 63;
  int deg = cnt[n];
  if (deg > BCAP) deg = BCAP;
  const int* lst = bkt + (size_t)n * BCAP;

  int sl = lane >> 4;          // edge slot 0..3
  int cl = lane & 15;          // channel group
  int cb = cl * 16;            // channel base (16 channels per lane)
  int h = cl >> 1;             // head = channel/32
  float ad = ad1[n * 8 + h];

  float ssum = 0.f;
  float acc[16] = {};

  int p = sl;
  for (; p + 4 < deg; p += 8) {
    int sA = lst[p], sB = lst[p + 4];
    float eA = as1[sA * 8 + h] + ad;
    float eB = as1[sB * 8 + h] + ad;
    uint4 rA = *reinterpret_cast<const uint4*>(h1f8 + (size_t)sA * 256 + cb);
    uint4 rB = *reinterpret_cast<const uint4*>(h1f8 + (size_t)sB * 256 + cb);
    eA = eA > 0.f ? eA : 0.2f * eA;
    eB = eB > 0.f ? eB : 0.2f * eB;
    float wA = __expf(eA), wB = __expf(eB);
    ssum += wA + wB;
    float4 a0 = dec4(rA.x), a1 = dec4(rA.y), a2 = dec4(rA.z), a3 = dec4(rA.w);
    float4 c0 = dec4(rB.x), c1 = dec4(rB.y), c2 = dec4(rB.z), c3 = dec4(rB.w);
    acc[0]  += wA * a0.x + wB * c0.x;  acc[1]  += wA * a0.y + wB * c0.y;
    acc[2]  += wA * a0.z + wB * c0.z;  acc[3]  += wA * a0.w + wB * c0.w;
    acc[4]  += wA * a1.x + wB * c1.x;  acc[5]  += wA * a1.y + wB * c1.y;
    acc[6]  += wA * a1.z + wB * c1.z;  acc[7]  += wA * a1.w + wB * c1.w;
    acc[8]  += wA * a2.x + wB * c2.x;  acc[9]  += wA * a2.y + wB * c2.y;
    acc[10] += wA * a2.z + wB * c2.z;  acc[11] += wA * a2.w + wB * c2.w;
    acc[12] += wA * a3.x + wB * c3.x;  acc[13] += wA * a3.y + wB * c3.y;
    acc[14] += wA * a3.z + wB * c3.z;  acc[15] += wA * a3.w + wB * c3.w;
  }
  for (; p < deg; p += 4) {
    int sA = lst[p];
    float eA = as1[sA * 8 + h] + ad;
    uint4 rA = *reinterpret_cast<const uint4*>(h1f8 + (size_t)sA * 256 + cb);
    eA = eA > 0.f ? eA : 0.2f * eA;
    float wA = __expf(eA);
    ssum += wA;
    float4 a0 = dec4(rA.x), a1 = dec4(rA.y), a2 = dec4(rA.z), a3 = dec4(rA.w);
    acc[0]  += wA * a0.x;  acc[1]  += wA * a0.y;
    acc[2]  += wA * a0.z;  acc[3]  += wA * a0.w;
    acc[4]  += wA * a1.x;  acc[5]  += wA * a1.y;
    acc[6]  += wA * a1.z;  acc[7]  += wA * a1.w;
    acc[8]  += wA * a2.x;  acc[9]  += wA * a2.y;
    acc[10] += wA * a2.z;  acc[11] += wA * a2.w;
    acc[12] += wA * a3.x;  acc[13] += wA * a3.y;
    acc[14] += wA * a3.z;  acc[15] += wA * a3.w;
  }

  // reduce across the 4 edge slots
  ssum += __shfl_xor(ssum, 16); ssum += __shfl_xor(ssum, 32);
#pragma unroll
  for (int c = 0; c < 16; ++c) {
    acc[c] += __shfl_xor(acc[c], 16);
    acc[c] += __shfl_xor(acc[c], 32);
  }

  if (sl == 0) {
    float inv = 1.f / ssum;
    float o[16];
    float4 b0 = *reinterpret_cast<const float4*>(b1 + cb);
    float4 b1v = *reinterpret_cast<const float4*>(b1 + cb + 4);
    float4 b2v = *reinterpret_cast<const float4*>(b1 + cb + 8);
    float4 b3v = *reinterpret_cast<const float4*>(b1 + cb + 12);
    float bb[16] = {b0.x, b0.y, b0.z, b0.w, b1v.x, b1v.y, b1v.z, b1v.w,
                    b2v.x, b2v.y, b2v.z, b2v.w, b3v.x, b3v.y, b3v.z, b3v.w};
#pragma unroll
    for (int c = 0; c < 16; ++c) {
      float v = acc[c] * inv + bb[c];
      o[c] = v > 0.f ? v : __expf(v) - 1.f;
    }
    int4 o0, o1;
    o0.x = (int)(((unsigned)f2bf(o[1]) << 16) | f2bf(o[0]));
    o0.y = (int)(((unsigned)f2bf(o[3]) << 16) | f2bf(o[2]));
    o0.z = (int)(((unsigned)f2bf(o[5]) << 16) | f2bf(o[4]));
    o0.w = (int)(((unsigned)f2bf(o[7]) << 16) | f2bf(o[6]));
    o1.x = (int)(((unsigned)f2bf(o[9]) << 16) | f2bf(o[8]));
    o1.y = (int)(((unsigned)f2bf(o[11]) << 16) | f2bf(o[10]));
    o1.z = (int)(((unsigned)f2bf(o[13]) << 16) | f2bf(o[12]));
    o1.w = (int)(((unsigned)f2bf(o[15]) << 16) | f2bf(o[14]));
    *reinterpret_cast<int4*>(h2b + (size_t)n * 256 + cb) = o0;
    *reinterpret_cast<int4*>(h2b + (size_t)n * 256 + cb + 8) = o1;
  }
}

// ---------------------------------------------------------------------------
// layer-2 projection via MFMA: pj2p[50000][16] = h2 @ W2tp^T, + as2/ad2
// ---------------------------------------------------------------------------
__global__ __launch_bounds__(256) void proj2_mfma(const ushort* __restrict__ h2b,
                                                  const ushort* __restrict__ W2tp,
                                                  const float* __restrict__ asrc2,
                                                  const float* __restrict__ adst2,
                                                  float* __restrict__ pj2p,
                                                  float* __restrict__ as2,
                                                  float* __restrict__ ad2) {
  int wid = threadIdx.x >> 6, lane = threadIdx.x & 63;
  int r = lane & 15, kg = lane >> 4;
  int rb = blockIdx.x * 64 + wid * 16;
  int row_a = rb + r;
  if (row_a >= N_NODES) row_a = 0;
  const ushort* ap = h2b + (size_t)row_a * 256 + kg * 8;
  const ushort* bp = W2tp + (size_t)r * 256 + kg * 8;
  f32x4 acc = 0;
#pragma unroll
  for (int k0 = 0; k0 < 256; k0 += 32)
    acc = __builtin_amdgcn_mfma_f32_16x16x32_bf16(
        *reinterpret_cast<const bf16x8*>(ap + k0),
        *reinterpret_cast<const bf16x8*>(bp + k0), acc, 0, 0, 0);

  float av = (r < NCLS) ? asrc2[r] : 0.f;
  float dv = (r < NCLS) ? adst2[r] : 0.f;
#pragma unroll
  for (int q = 0; q < 4; ++q) {
    int row = rb + kg * 4 + q;
    float v = acc[q];
    if (row < N_NODES) pj2p[row * 16 + r] = v;
    float s = v * av, d = v * dv;
    s += __shfl_xor(s, 1); s += __shfl_xor(s, 2); s += __shfl_xor(s, 4); s += __shfl_xor(s, 8);
    d += __shfl_xor(d, 1); d += __shfl_xor(d, 2); d += __shfl_xor(d, 4); d += __shfl_xor(d, 8);
    if (r == 0 && row < N_NODES) { as2[row] = s; ad2[row] = d; }
  }
}

// ---------------------------------------------------------------------------
// layer-2 aggregation: single pass, 4 edge slots x 16 channel lanes,
// 4 edges in flight per slot, from fixed-capacity buckets
// ---------------------------------------------------------------------------
__global__ __launch_bounds__(256) void agg2_kernel(const float* __restrict__ pj2p,
                                                   const float* __restrict__ as2,
                                                   const float* __restrict__ ad2,
                                                   const int* __restrict__ cnt,
                                                   const int* __restrict__ bkt,
                                                   const float* __restrict__ b2,
                                                   float* __restrict__ out2p) {
  int n = (blockIdx.x * 256 + threadIdx.x) >> 6;
  int lane = threadIdx.x & 63;
  int deg = cnt[n];
  if (deg > BCAP) deg = BCAP;
  const int* lst = bkt + (size_t)n * BCAP;
  float ad = ad2[n];
  int es = lane >> 4, c = lane & 15;
  float ssum = 0.f, acc = 0.f;
  int p = es;
  for (; p + 12 < deg; p += 16) {
    int s0 = lst[p], s1 = lst[p + 4], s2 = lst[p + 8], s3 = lst[p + 12];
    float e0 = as2[s0] + ad, e1 = as2[s1] + ad, e2 = as2[s2] + ad, e3 = as2[s3] + ad;
    float v0 = pj2p[s0 * 16 + c], v1 = pj2p[s1 * 16 + c];
    float v2 = pj2p[s2 * 16 + c], v3 = pj2p[s3 * 16 + c];
    e0 = e0 > 0.f ? e0 : 0.2f * e0;
    e1 = e1 > 0.f ? e1 : 0.2f * e1;
    e2 = e2 > 0.f ? e2 : 0.2f * e2;
    e3 = e3 > 0.f ? e3 : 0.2f * e3;
    float w0 = __expf(e0), w1 = __expf(e1), w2 = __expf(e2), w3 = __expf(e3);
    ssum += (w0 + w1) + (w2 + w3);
    acc += (w0 * v0 + w1 * v1) + (w2 * v2 + w3 * v3);
  }
  for (; p < deg; p += 4) {
    int sA = lst[p];
    float eA = as2[sA] + ad;
    float vA = pj2p[sA * 16 + c];
    eA = eA > 0.f ? eA : 0.2f * eA;
    float wA = __expf(eA);
    ssum += wA;
    acc += wA * vA;
  }
  acc += __shfl_xor(acc, 16); acc += __shfl_xor(acc, 32);
  ssum += __shfl_xor(ssum, 16); ssum += __shfl_xor(ssum, 32);
  if (lane < 16) {
    float bc = (lane < NCLS) ? b2[lane] : 0.f;
    out2p[n * 16 + lane] = acc / ssum + bc;
  }
}

// ---------------------------------------------------------------------------
// global mean pool
// ---------------------------------------------------------------------------
__global__ __launch_bounds__(256) void pool_kernel(const float* __restrict__ out2p,
                                                   const int* __restrict__ batch,
                                                   float* __restrict__ outp) {
  __shared__ float red[256];
  int g = blockIdx.x;
  int lo = 0, hi = N_NODES;
  while (lo < hi) { int mid = (lo + hi) >> 1; if (batch[mid] < g) lo = mid + 1; else hi = mid; }
  int start = lo;
  hi = N_NODES;
  while (lo < hi) { int mid = (lo + hi) >> 1; if (batch[mid] < g + 1) lo = mid + 1; else hi = mid; }
  int end = lo;
  int t = threadIdx.x;
  int c = t & 15, nsl = t >> 4;
  float loc = 0.f;
  for (int nn = start + nsl; nn < end; nn += 16) loc += out2p[nn * 16 + c];
  red[t] = loc;
  __syncthreads();
  for (int s = 128; s >= 16; s >>= 1) {
    if (t < s) red[t] += red[t + s];
    __syncthreads();
  }
  if (t < NCLS) {
    float denom = fmaxf((float)(end - start), 1.f);
    outp[g * NCLS + t] = red[t] / denom;
  }
}

// ---------------------------------------------------------------------------
extern "C" void kernel_launch(void* const* d_in, const int* in_sizes, int n_in,
                              void* d_out, int out_size, void* d_ws, size_t ws_size,
                              hipStream_t stream) {
  const float* x      = (const float*)d_in[0];
  const float* W1     = (const float*)d_in[1];
  const float* a_src1 = (const float*)d_in[2];
  const float* a_dst1 = (const float*)d_in[3];
  const float* b1     = (const float*)d_in[4];
  const float* W2     = (const float*)d_in[5];
  const float* a_src2 = (const float*)d_in[6];
  const float* a_dst2 = (const float*)d_in[7];
  const float* b2     = (const float*)d_in[8];
  const int*   ei     = (const int*)d_in[9];
  const int*   batch  = (const int*)d_in[10];

  char* ws = (char*)d_ws;
  size_t o = 0;
  auto alloc = [&](size_t bytes) {
    char* p = ws + o;
    o = (o + bytes + 255) & ~(size_t)255;
    return p;
  };
  ushort* xb   = (ushort*)alloc((size_t)N_NODES * 256 * 2);
  ushort* w1t  = (ushort*)alloc((size_t)272 * 256 * 2);
  ushort* w2tp = (ushort*)alloc((size_t)16 * 256 * 2);
  unsigned char* h1f8 = (unsigned char*)alloc((size_t)N_NODES * 256);
  ushort* h2b  = (ushort*)alloc((size_t)N_NODES * 256 * 2);
  float* as1   = (float*)alloc((size_t)N_NODES * 8 * 4);
  float* ad1   = (float*)alloc((size_t)N_NODES * 8 * 4);
  float* pj2p  = (float*)alloc((size_t)N_NODES * 16 * 4);
  float* as2   = (float*)alloc((size_t)N_NODES * 4);
  float* ad2   = (float*)alloc((size_t)N_NODES * 4);
  float* out2p = (float*)alloc((size_t)N_NODES * 16 * 4);
  int*   cnt   = (int*)alloc((size_t)N_NODES * 4);
  int*   bkt   = (int*)alloc((size_t)N_NODES * BCAP * 4);

  hipMemsetAsync(cnt, 0, (size_t)N_NODES * 4, stream);

  prep_kernel<<<PREP_BLOCKS, 256, 0, stream>>>((const float4*)x, (ushort4*)xb,
                                               W1, w1t, W2, w2tp, a_src1, a_dst1);
  gemm1_scatter<<<SCAT_BLOCKS + GEMM_BLOCKS, 256, 0, stream>>>(xb, w1t, h1f8, as1, ad1,
                                                               ei, cnt, bkt);
  agg1_kernel<<<N_NODES / 4, 256, 0, stream>>>(h1f8, as1, ad1, cnt, bkt, b1, h2b);
  proj2_mfma<<<GEMM_BLOCKS, 256, 0, stream>>>(h2b, w2tp, a_src2, a_dst2,
                                              pj2p, as2, ad2);
  agg2_kernel<<<N_NODES / 4, 256, 0, stream>>>(pj2p, as2, ad2, cnt, bkt, b2, out2p);
  pool_kernel<<<NGRP, 256, 0, stream>>>(out2p, batch, (float*)d_out);
}

// Round 7
// 284.932 us; speedup vs baseline: 1.9102x; 1.0172x over previous
//
#include <hip/hip_runtime.h>
#include <hip/hip_bf16.h>
#include <hip/hip_fp8.h>
#include <math.h>

#define N_NODES 50000
#define N_EDGES 800000
#define E_TOT   (N_EDGES + N_NODES)   /* 850000 with self loops */
#define NCLS 10
#define NGRP 128

#define NBKT 196                       /* coarse buckets: dst>>8, dst<50000 */
#define EPB  1024                      /* edges per hist/place block */
#define NB1  ((E_TOT + EPB - 1) / EPB) /* 831 */

typedef __attribute__((ext_vector_type(8))) short bf16x8;
typedef __attribute__((ext_vector_type(4))) float f32x4;

static __device__ __forceinline__ ushort f2bf(float f) {
  union { float f; unsigned u; } v; v.f = f;
  unsigned r = v.u + 0x7fffu + ((v.u >> 16) & 1u);   // round-to-nearest-even
  return (ushort)(r >> 16);
}
static __device__ __forceinline__ unsigned char enc8(float v) {
  __hip_fp8_e4m3 t(v);
  return (unsigned char)t.__x;
}
static __device__ __forceinline__ float4 dec4(unsigned u) {
  __hip_fp8x4_e4m3 q; q.__x = u;
  return (float4)q;
}

// ---------------------------------------------------------------------------
// prep: cast x -> bf16 | W1 -> W1t bf16 rows [0,256) | W2 -> W2tp bf16 [16][256]
//       | Wa = W1 @ a_{src,dst} -> W1t rows [256,272)
// ---------------------------------------------------------------------------
#define CAST_BLOCKS 12500
#define W1T_BASE 12500
#define W2T_BASE 12564
#define WA_BASE  12565
#define PREP_BLOCKS 12566

__global__ __launch_bounds__(256) void prep_kernel(const float4* __restrict__ X4,
                                                   ushort4* __restrict__ Xb,
                                                   const float* __restrict__ W1,
                                                   ushort* __restrict__ W1t,
                                                   const float* __restrict__ W2,
                                                   ushort* __restrict__ W2tp,
                                                   const float* __restrict__ asrc1,
                                                   const float* __restrict__ adst1) {
  int b = blockIdx.x;
  int tid = threadIdx.x;
  if (b < CAST_BLOCKS) {
    int i = b * 256 + tid;
    float4 v = X4[i];
    ushort4 o;
    o.x = f2bf(v.x); o.y = f2bf(v.y); o.z = f2bf(v.z); o.w = f2bf(v.w);
    Xb[i] = o;
  } else if (b < W2T_BASE) {
    __shared__ float t[32][33];
    int bb = b - W1T_BASE;
    int k0 = (bb >> 3) * 32, n0 = (bb & 7) * 32;
    int tx = tid & 31, ty = tid >> 5;  // ty 0..7
    for (int r = 0; r < 32; r += 8)
      t[ty + r][tx] = W1[(k0 + ty + r) * 256 + n0 + tx];
    __syncthreads();
    for (int r = 0; r < 32; r += 8)
      W1t[(n0 + ty + r) * 256 + k0 + tx] = f2bf(t[tx][ty + r]);
  } else if (b == W2T_BASE) {
    int k = tid;  // 0..255
#pragma unroll
    for (int c = 0; c < 16; ++c)
      W2tp[c * 256 + k] = (c < NCLS) ? f2bf(W2[k * NCLS + c]) : (ushort)0;
  } else {
    int k = tid;  // 0..255
    const float* wrow = W1 + k * 256;
#pragma unroll
    for (int h = 0; h < 8; ++h) {
      float s = 0.f, d = 0.f;
#pragma unroll
      for (int c = 0; c < 32; ++c) {
        float w = wrow[h * 32 + c];
        s += w * asrc1[h * 32 + c];
        d += w * adst1[h * 32 + c];
      }
      W1t[(256 + h) * 256 + k] = f2bf(s);
      W1t[(264 + h) * 256 + k] = f2bf(d);
    }
  }
}

// ---------------------------------------------------------------------------
// GEMM1 MFMA: h1 = x @ W1 (bf16 in, FP8 e4m3 out), + fused as1/ad1 = x @ Wa
// ---------------------------------------------------------------------------
#define GEMM_BLOCKS ((N_NODES + 63) / 64)

__global__ __launch_bounds__(256) void gemm1_mfma(const ushort* __restrict__ Xb,
                                                  const ushort* __restrict__ W1t,
                                                  unsigned char* __restrict__ h1f8,
                                                  float* __restrict__ as1,
                                                  float* __restrict__ ad1) {
  int wid = threadIdx.x >> 6, lane = threadIdx.x & 63;
  int r = lane & 15, kg = lane >> 4;
  int m0 = blockIdx.x * 64;
  int n0 = wid * 64;
  bool extra = (wid == 3);
  f32x4 acc[4][4];
  f32x4 accE[4];
#pragma unroll
  for (int mi = 0; mi < 4; ++mi) {
#pragma unroll
    for (int ni = 0; ni < 4; ++ni) acc[mi][ni] = 0;
    accE[mi] = 0;
  }

  const ushort* aptr[4];
#pragma unroll
  for (int mi = 0; mi < 4; ++mi) {
    int row = m0 + mi * 16 + r;
    if (row >= N_NODES) row = 0;
    aptr[mi] = Xb + (size_t)row * 256 + kg * 8;
  }
  const ushort* bptr[4];
#pragma unroll
  for (int ni = 0; ni < 4; ++ni)
    bptr[ni] = W1t + (size_t)(n0 + ni * 16 + r) * 256 + kg * 8;
  const ushort* bptrE = W1t + (size_t)(256 + r) * 256 + kg * 8;

#pragma unroll 2
  for (int k0 = 0; k0 < 256; k0 += 32) {
    bf16x8 a[4], b[4], bE;
#pragma unroll
    for (int mi = 0; mi < 4; ++mi)
      a[mi] = *reinterpret_cast<const bf16x8*>(aptr[mi] + k0);
#pragma unroll
    for (int ni = 0; ni < 4; ++ni)
      b[ni] = *reinterpret_cast<const bf16x8*>(bptr[ni] + k0);
    if (extra) bE = *reinterpret_cast<const bf16x8*>(bptrE + k0);
#pragma unroll
    for (int mi = 0; mi < 4; ++mi) {
#pragma unroll
      for (int ni = 0; ni < 4; ++ni)
        acc[mi][ni] = __builtin_amdgcn_mfma_f32_16x16x32_bf16(a[mi], b[ni], acc[mi][ni], 0, 0, 0);
      if (extra)
        accE[mi] = __builtin_amdgcn_mfma_f32_16x16x32_bf16(a[mi], bE, accE[mi], 0, 0, 0);
    }
  }

#pragma unroll
  for (int mi = 0; mi < 4; ++mi) {
#pragma unroll
    for (int q = 0; q < 4; ++q) {
      int row = m0 + mi * 16 + kg * 4 + q;
      if (row < N_NODES) {
#pragma unroll
        for (int ni = 0; ni < 4; ++ni)
          h1f8[(size_t)row * 256 + n0 + ni * 16 + r] = enc8(acc[mi][ni][q]);
        if (extra) {
          float* dst = (r < 8) ? (as1 + row * 8 + r) : (ad1 + row * 8 + (r & 7));
          *dst = accE[mi][q];
        }
      }
    }
  }
}

// ---------------------------------------------------------------------------
// Atomic-free CSR build: two-level counting sort (LDS atomics only)
// ---------------------------------------------------------------------------
__global__ __launch_bounds__(256) void k_hist(const int* __restrict__ ei,
                                              int* __restrict__ histg) {
  __shared__ int h[NBKT];
  int tid = threadIdx.x;
  for (int j = tid; j < NBKT; j += 256) h[j] = 0;
  __syncthreads();
  int base = blockIdx.x * EPB;
#pragma unroll
  for (int t = 0; t < 4; ++t) {
    int i = base + t * 256 + tid;
    if (i < E_TOT) {
      int d = (i < N_EDGES) ? ei[N_EDGES + i] : (i - N_EDGES);
      atomicAdd(&h[d >> 8], 1);
    }
  }
  __syncthreads();
  for (int j = tid; j < NBKT; j += 256) histg[j * NB1 + blockIdx.x] = h[j];
}

// per-bucket exclusive scan over the NB1 block counts (in place) + totals
__global__ __launch_bounds__(256) void k_scan(int* __restrict__ histg,
                                              int* __restrict__ tot) {
  __shared__ int sh[256];
  int b = blockIdx.x, tid = threadIdx.x;
  int carry = 0;
  for (int c = 0; c < (NB1 + 255) / 256; ++c) {
    int j = c * 256 + tid;
    int v = (j < NB1) ? histg[b * NB1 + j] : 0;
    sh[tid] = v;
    __syncthreads();
    for (int d = 1; d < 256; d <<= 1) {
      int t = (tid >= d) ? sh[tid - d] : 0;
      __syncthreads();
      sh[tid] += t;
      __syncthreads();
    }
    if (j < NB1) histg[b * NB1 + j] = carry + sh[tid] - v;  // exclusive
    carry += sh[255];
    __syncthreads();
  }
  if (tid == 0) tot[b] = carry;
}

__global__ __launch_bounds__(256) void k_base(const int* __restrict__ tot,
                                              int* __restrict__ baseg) {
  __shared__ int sh[256];
  int tid = threadIdx.x;
  int v = (tid < NBKT) ? tot[tid] : 0;
  sh[tid] = v;
  __syncthreads();
  for (int d = 1; d < 256; d <<= 1) {
    int t = (tid >= d) ? sh[tid - d] : 0;
    __syncthreads();
    sh[tid] += t;
    __syncthreads();
  }
  if (tid < NBKT) baseg[tid] = sh[tid] - v;
  if (tid == 255) baseg[NBKT] = sh[255];
}

// place edges into coarse-sorted array, packed (dst<<16)|src (both < 65536)
__global__ __launch_bounds__(256) void k_place(const int* __restrict__ ei,
                                               const int* __restrict__ histg,
                                               const int* __restrict__ baseg,
                                               unsigned int* __restrict__ cs) {
  __shared__ int h[NBKT];
  __shared__ int basec[NBKT];
  int tid = threadIdx.x;
  for (int j = tid; j < NBKT; j += 256) {
    h[j] = 0;
    basec[j] = baseg[j] + histg[j * NB1 + blockIdx.x];
  }
  __syncthreads();
  int base = blockIdx.x * EPB;
#pragma unroll
  for (int t = 0; t < 4; ++t) {
    int i = base + t * 256 + tid;
    if (i < E_TOT) {
      int s = (i < N_EDGES) ? ei[i] : (i - N_EDGES);
      int d = (i < N_EDGES) ? ei[N_EDGES + i] : (i - N_EDGES);
      int bk = d >> 8;
      int r = atomicAdd(&h[bk], 1);
      cs[basec[bk] + r] = ((unsigned)d << 16) | (unsigned)s;
    }
  }
}

// fine pass: one block per coarse bucket; emit off[] and csr[]
__global__ __launch_bounds__(256) void k_fine(const unsigned int* __restrict__ cs,
                                              const int* __restrict__ baseg,
                                              int* __restrict__ csr,
                                              int* __restrict__ off) {
  __shared__ int cnt[256];
  __shared__ int sh[256];
  __shared__ int scn[256];
  __shared__ int cur[256];
  int b = blockIdx.x, tid = threadIdx.x;
  int lo = baseg[b], hi = baseg[b + 1];
  cnt[tid] = 0;
  cur[tid] = 0;
  __syncthreads();
  for (int i = lo + tid; i < hi; i += 256) atomicAdd(&cnt[(cs[i] >> 16) & 255], 1);
  __syncthreads();
  int v = cnt[tid];
  sh[tid] = v;
  __syncthreads();
  for (int d = 1; d < 256; d <<= 1) {
    int t = (tid >= d) ? sh[tid - d] : 0;
    __syncthreads();
    sh[tid] += t;
    __syncthreads();
  }
  scn[tid] = sh[tid] - v;  // exclusive scan of dst-low-byte counts
  int idx = b * 256 + tid;
  if (idx <= N_NODES) off[idx] = lo + scn[tid];
  __syncthreads();
  for (int i = lo + tid; i < hi; i += 256) {
    unsigned e = cs[i];
    int dl = (e >> 16) & 255;
    int r = atomicAdd(&cur[dl], 1);
    csr[lo + scn[dl] + r] = (int)(e & 0xFFFFu);
  }
}

// ---------------------------------------------------------------------------
// layer-1 aggregation + bias + elu -> h2 (bf16). h1 gathered as FP8 e4m3.
// Wave per dst node: 4 edge slots x 16 channel lanes, 2-unroll (8 in flight).
// ---------------------------------------------------------------------------
__global__ __launch_bounds__(256) void agg1_kernel(const unsigned char* __restrict__ h1f8,
                                                   const float* __restrict__ as1,
                                                   const float* __restrict__ ad1,
                                                   const int* __restrict__ off,
                                                   const int* __restrict__ csr,
                                                   const float* __restrict__ b1,
                                                   ushort* __restrict__ h2b) {
  int n = (blockIdx.x * 256 + threadIdx.x) >> 6;
  int lane = threadIdx.x & 63;
  int p0 = off[n], p1 = off[n + 1];

  int sl = lane >> 4;          // edge slot 0..3
  int cl = lane & 15;          // channel group
  int cb = cl * 16;            // channel base (16 channels per lane)
  int h = cl >> 1;             // head = channel/32
  float ad = ad1[n * 8 + h];

  float ssum = 0.f;
  float acc[16] = {};

  int p = p0 + sl;
  for (; p + 4 < p1; p += 8) {
    int sA = csr[p], sB = csr[p + 4];
    float eA = as1[sA * 8 + h] + ad;
    float eB = as1[sB * 8 + h] + ad;
    uint4 rA = *reinterpret_cast<const uint4*>(h1f8 + (size_t)sA * 256 + cb);
    uint4 rB = *reinterpret_cast<const uint4*>(h1f8 + (size_t)sB * 256 + cb);
    eA = eA > 0.f ? eA : 0.2f * eA;
    eB = eB > 0.f ? eB : 0.2f * eB;
    float wA = __expf(eA), wB = __expf(eB);
    ssum += wA + wB;
    float4 a0 = dec4(rA.x), a1 = dec4(rA.y), a2 = dec4(rA.z), a3 = dec4(rA.w);
    float4 c0 = dec4(rB.x), c1 = dec4(rB.y), c2 = dec4(rB.z), c3 = dec4(rB.w);
    acc[0]  += wA * a0.x + wB * c0.x;  acc[1]  += wA * a0.y + wB * c0.y;
    acc[2]  += wA * a0.z + wB * c0.z;  acc[3]  += wA * a0.w + wB * c0.w;
    acc[4]  += wA * a1.x + wB * c1.x;  acc[5]  += wA * a1.y + wB * c1.y;
    acc[6]  += wA * a1.z + wB * c1.z;  acc[7]  += wA * a1.w + wB * c1.w;
    acc[8]  += wA * a2.x + wB * c2.x;  acc[9]  += wA * a2.y + wB * c2.y;
    acc[10] += wA * a2.z + wB * c2.z;  acc[11] += wA * a2.w + wB * c2.w;
    acc[12] += wA * a3.x + wB * c3.x;  acc[13] += wA * a3.y + wB * c3.y;
    acc[14] += wA * a3.z + wB * c3.z;  acc[15] += wA * a3.w + wB * c3.w;
  }
  for (; p < p1; p += 4) {
    int sA = csr[p];
    float eA = as1[sA * 8 + h] + ad;
    uint4 rA = *reinterpret_cast<const uint4*>(h1f8 + (size_t)sA * 256 + cb);
    eA = eA > 0.f ? eA : 0.2f * eA;
    float wA = __expf(eA);
    ssum += wA;
    float4 a0 = dec4(rA.x), a1 = dec4(rA.y), a2 = dec4(rA.z), a3 = dec4(rA.w);
    acc[0]  += wA * a0.x;  acc[1]  += wA * a0.y;
    acc[2]  += wA * a0.z;  acc[3]  += wA * a0.w;
    acc[4]  += wA * a1.x;  acc[5]  += wA * a1.y;
    acc[6]  += wA * a1.z;  acc[7]  += wA * a1.w;
    acc[8]  += wA * a2.x;  acc[9]  += wA * a2.y;
    acc[10] += wA * a2.z;  acc[11] += wA * a2.w;
    acc[12] += wA * a3.x;  acc[13] += wA * a3.y;
    acc[14] += wA * a3.z;  acc[15] += wA * a3.w;
  }

  // reduce across the 4 edge slots
  ssum += __shfl_xor(ssum, 16); ssum += __shfl_xor(ssum, 32);
#pragma unroll
  for (int c = 0; c < 16; ++c) {
    acc[c] += __shfl_xor(acc[c], 16);
    acc[c] += __shfl_xor(acc[c], 32);
  }

  if (sl == 0) {
    float inv = 1.f / ssum;
    float o[16];
    float4 b0 = *reinterpret_cast<const float4*>(b1 + cb);
    float4 b1v = *reinterpret_cast<const float4*>(b1 + cb + 4);
    float4 b2v = *reinterpret_cast<const float4*>(b1 + cb + 8);
    float4 b3v = *reinterpret_cast<const float4*>(b1 + cb + 12);
    float bb[16] = {b0.x, b0.y, b0.z, b0.w, b1v.x, b1v.y, b1v.z, b1v.w,
                    b2v.x, b2v.y, b2v.z, b2v.w, b3v.x, b3v.y, b3v.z, b3v.w};
#pragma unroll
    for (int c = 0; c < 16; ++c) {
      float v = acc[c] * inv + bb[c];
      o[c] = v > 0.f ? v : __expf(v) - 1.f;
    }
    int4 o0, o1;
    o0.x = (int)(((unsigned)f2bf(o[1]) << 16) | f2bf(o[0]));
    o0.y = (int)(((unsigned)f2bf(o[3]) << 16) | f2bf(o[2]));
    o0.z = (int)(((unsigned)f2bf(o[5]) << 16) | f2bf(o[4]));
    o0.w = (int)(((unsigned)f2bf(o[7]) << 16) | f2bf(o[6]));
    o1.x = (int)(((unsigned)f2bf(o[9]) << 16) | f2bf(o[8]));
    o1.y = (int)(((unsigned)f2bf(o[11]) << 16) | f2bf(o[10]));
    o1.z = (int)(((unsigned)f2bf(o[13]) << 16) | f2bf(o[12]));
    o1.w = (int)(((unsigned)f2bf(o[15]) << 16) | f2bf(o[14]));
    *reinterpret_cast<int4*>(h2b + (size_t)n * 256 + cb) = o0;
    *reinterpret_cast<int4*>(h2b + (size_t)n * 256 + cb + 8) = o1;
  }
}

// ---------------------------------------------------------------------------
// layer-2 projection via MFMA: pj2p[50000][16] = h2 @ W2tp^T, + as2/ad2
// ---------------------------------------------------------------------------
__global__ __launch_bounds__(256) void proj2_mfma(const ushort* __restrict__ h2b,
                                                  const ushort* __restrict__ W2tp,
                                                  const float* __restrict__ asrc2,
                                                  const float* __restrict__ adst2,
                                                  float* __restrict__ pj2p,
                                                  float* __restrict__ as2,
                                                  float* __restrict__ ad2) {
  int wid = threadIdx.x >> 6, lane = threadIdx.x & 63;
  int r = lane & 15, kg = lane >> 4;
  int rb = blockIdx.x * 64 + wid * 16;
  int row_a = rb + r;
  if (row_a >= N_NODES) row_a = 0;
  const ushort* ap = h2b + (size_t)row_a * 256 + kg * 8;
  const ushort* bp = W2tp + (size_t)r * 256 + kg * 8;
  f32x4 acc = 0;
#pragma unroll
  for (int k0 = 0; k0 < 256; k0 += 32)
    acc = __builtin_amdgcn_mfma_f32_16x16x32_bf16(
        *reinterpret_cast<const bf16x8*>(ap + k0),
        *reinterpret_cast<const bf16x8*>(bp + k0), acc, 0, 0, 0);

  float av = (r < NCLS) ? asrc2[r] : 0.f;
  float dv = (r < NCLS) ? adst2[r] : 0.f;
#pragma unroll
  for (int q = 0; q < 4; ++q) {
    int row = rb + kg * 4 + q;
    float v = acc[q];
    if (row < N_NODES) pj2p[row * 16 + r] = v;
    float s = v * av, d = v * dv;
    s += __shfl_xor(s, 1); s += __shfl_xor(s, 2); s += __shfl_xor(s, 4); s += __shfl_xor(s, 8);
    d += __shfl_xor(d, 1); d += __shfl_xor(d, 2); d += __shfl_xor(d, 4); d += __shfl_xor(d, 8);
    if (r == 0 && row < N_NODES) { as2[row] = s; ad2[row] = d; }
  }
}

// ---------------------------------------------------------------------------
// layer-2 aggregation: single pass, 4 edge slots x 16 channel lanes, 4-deep
// ---------------------------------------------------------------------------
__global__ __launch_bounds__(256) void agg2_kernel(const float* __restrict__ pj2p,
                                                   const float* __restrict__ as2,
                                                   const float* __restrict__ ad2,
                                                   const int* __restrict__ off,
                                                   const int* __restrict__ csr,
                                                   const float* __restrict__ b2,
                                                   float* __restrict__ out2p) {
  int n = (blockIdx.x * 256 + threadIdx.x) >> 6;
  int lane = threadIdx.x & 63;
  int p0 = off[n], p1 = off[n + 1];
  float ad = ad2[n];
  int es = lane >> 4, c = lane & 15;
  float ssum = 0.f, acc = 0.f;
  int p = p0 + es;
  for (; p + 12 < p1; p += 16) {
    int s0 = csr[p], s1 = csr[p + 4], s2 = csr[p + 8], s3 = csr[p + 12];
    float e0 = as2[s0] + ad, e1 = as2[s1] + ad, e2 = as2[s2] + ad, e3 = as2[s3] + ad;
    float v0 = pj2p[s0 * 16 + c], v1 = pj2p[s1 * 16 + c];
    float v2 = pj2p[s2 * 16 + c], v3 = pj2p[s3 * 16 + c];
    e0 = e0 > 0.f ? e0 : 0.2f * e0;
    e1 = e1 > 0.f ? e1 : 0.2f * e1;
    e2 = e2 > 0.f ? e2 : 0.2f * e2;
    e3 = e3 > 0.f ? e3 : 0.2f * e3;
    float w0 = __expf(e0), w1 = __expf(e1), w2 = __expf(e2), w3 = __expf(e3);
    ssum += (w0 + w1) + (w2 + w3);
    acc += (w0 * v0 + w1 * v1) + (w2 * v2 + w3 * v3);
  }
  for (; p < p1; p += 4) {
    int sA = csr[p];
    float eA = as2[sA] + ad;
    float vA = pj2p[sA * 16 + c];
    eA = eA > 0.f ? eA : 0.2f * eA;
    float wA = __expf(eA);
    ssum += wA;
    acc += wA * vA;
  }
  acc += __shfl_xor(acc, 16); acc += __shfl_xor(acc, 32);
  ssum += __shfl_xor(ssum, 16); ssum += __shfl_xor(ssum, 32);
  if (lane < 16) {
    float bc = (lane < NCLS) ? b2[lane] : 0.f;
    out2p[n * 16 + lane] = acc / ssum + bc;
  }
}

// ---------------------------------------------------------------------------
// global mean pool
// ---------------------------------------------------------------------------
__global__ __launch_bounds__(256) void pool_kernel(const float* __restrict__ out2p,
                                                   const int* __restrict__ batch,
                                                   float* __restrict__ outp) {
  __shared__ float red[256];
  int g = blockIdx.x;
  int lo = 0, hi = N_NODES;
  while (lo < hi) { int mid = (lo + hi) >> 1; if (batch[mid] < g) lo = mid + 1; else hi = mid; }
  int start = lo;
  hi = N_NODES;
  while (lo < hi) { int mid = (lo + hi) >> 1; if (batch[mid] < g + 1) lo = mid + 1; else hi = mid; }
  int end = lo;
  int t = threadIdx.x;
  int c = t & 15, nsl = t >> 4;
  float loc = 0.f;
  for (int nn = start + nsl; nn < end; nn += 16) loc += out2p[nn * 16 + c];
  red[t] = loc;
  __syncthreads();
  for (int s = 128; s >= 16; s >>= 1) {
    if (t < s) red[t] += red[t + s];
    __syncthreads();
  }
  if (t < NCLS) {
    float denom = fmaxf((float)(end - start), 1.f);
    outp[g * NCLS + t] = red[t] / denom;
  }
}

// ---------------------------------------------------------------------------
extern "C" void kernel_launch(void* const* d_in, const int* in_sizes, int n_in,
                              void* d_out, int out_size, void* d_ws, size_t ws_size,
                              hipStream_t stream) {
  const float* x      = (const float*)d_in[0];
  const float* W1     = (const float*)d_in[1];
  const float* a_src1 = (const float*)d_in[2];
  const float* a_dst1 = (const float*)d_in[3];
  const float* b1     = (const float*)d_in[4];
  const float* W2     = (const float*)d_in[5];
  const float* a_src2 = (const float*)d_in[6];
  const float* a_dst2 = (const float*)d_in[7];
  const float* b2     = (const float*)d_in[8];
  const int*   ei     = (const int*)d_in[9];
  const int*   batch  = (const int*)d_in[10];

  char* ws = (char*)d_ws;
  size_t o = 0;
  auto alloc = [&](size_t bytes) {
    char* p = ws + o;
    o = (o + bytes + 255) & ~(size_t)255;
    return p;
  };
  ushort* xb   = (ushort*)alloc((size_t)N_NODES * 256 * 2);
  ushort* w1t  = (ushort*)alloc((size_t)272 * 256 * 2);
  ushort* w2tp = (ushort*)alloc((size_t)16 * 256 * 2);
  unsigned char* h1f8 = (unsigned char*)alloc((size_t)N_NODES * 256);
  ushort* h2b  = (ushort*)alloc((size_t)N_NODES * 256 * 2);
  float* as1   = (float*)alloc((size_t)N_NODES * 8 * 4);
  float* ad1   = (float*)alloc((size_t)N_NODES * 8 * 4);
  float* pj2p  = (float*)alloc((size_t)N_NODES * 16 * 4);
  float* as2   = (float*)alloc((size_t)N_NODES * 4);
  float* ad2   = (float*)alloc((size_t)N_NODES * 4);
  float* out2p = (float*)alloc((size_t)N_NODES * 16 * 4);
  int*   histg = (int*)alloc((size_t)NBKT * NB1 * 4);
  int*   tot   = (int*)alloc((size_t)NBKT * 4);
  int*   baseg = (int*)alloc((size_t)(NBKT + 1) * 4);
  unsigned int* cs = (unsigned int*)alloc((size_t)E_TOT * 4);
  int*   csr   = (int*)alloc((size_t)E_TOT * 4);
  int*   off   = (int*)alloc((size_t)(N_NODES + 1) * 4);

  prep_kernel<<<PREP_BLOCKS, 256, 0, stream>>>((const float4*)x, (ushort4*)xb,
                                               W1, w1t, W2, w2tp, a_src1, a_dst1);
  gemm1_mfma<<<GEMM_BLOCKS, 256, 0, stream>>>(xb, w1t, h1f8, as1, ad1);

  k_hist<<<NB1, 256, 0, stream>>>(ei, histg);
  k_scan<<<NBKT, 256, 0, stream>>>(histg, tot);
  k_base<<<1, 256, 0, stream>>>(tot, baseg);
  k_place<<<NB1, 256, 0, stream>>>(ei, histg, baseg, cs);
  k_fine<<<NBKT, 256, 0, stream>>>(cs, baseg, csr, off);

  agg1_kernel<<<N_NODES / 4, 256, 0, stream>>>(h1f8, as1, ad1, off, csr, b1, h2b);
  proj2_mfma<<<GEMM_BLOCKS, 256, 0, stream>>>(h2b, w2tp, a_src2, a_dst2,
                                              pj2p, as2, ad2);
  agg2_kernel<<<N_NODES / 4, 256, 0, stream>>>(pj2p, as2, ad2, off, csr, b2, out2p);
  pool_kernel<<<NGRP, 256, 0, stream>>>(out2p, batch, (float*)d_out);
}

// Round 9
// 269.759 us; speedup vs baseline: 2.0176x; 1.0562x over previous
//
#include <hip/hip_runtime.h>
#include <hip/hip_bf16.h>
#include <math.h>

#define N_NODES 50000
#define N_EDGES 800000
#define E_TOT   (N_EDGES + N_NODES)   /* 850000 with self loops */
#define NCLS 10
#define NGRP 128

#define NBKT 196                       /* coarse buckets: dst>>8, dst<50000 */
#define EPB  1024                      /* edges per hist/place block */
#define NB1  ((E_TOT + EPB - 1) / EPB) /* 831 */

typedef __attribute__((ext_vector_type(8))) short bf16x8;
typedef __attribute__((ext_vector_type(4))) float f32x4;
typedef __attribute__((ext_vector_type(2))) float f32x2;

static __device__ __forceinline__ ushort f2bf(float f) {
  union { float f; unsigned u; } v; v.f = f;
  unsigned r = v.u + 0x7fffu + ((v.u >> 16) & 1u);   // round-to-nearest-even
  return (ushort)(r >> 16);
}
// hardware OCP e4m3 encode: 1 inst + extract
static __device__ __forceinline__ unsigned char enc8(float v) {
  int p = __builtin_amdgcn_cvt_pk_fp8_f32(v, v, 0, false);
  return (unsigned char)(p & 0xFF);
}
// hardware decode of 4 packed fp8 -> 4 floats, fma into acc
static __device__ __forceinline__ void fma4(float w, unsigned u, float* a) {
  f32x2 lo = __builtin_amdgcn_cvt_pk_f32_fp8(u, false);
  f32x2 hi = __builtin_amdgcn_cvt_pk_f32_fp8(u, true);
  a[0] += w * lo[0]; a[1] += w * lo[1]; a[2] += w * hi[0]; a[3] += w * hi[1];
}

// ---------------------------------------------------------------------------
// prep: cast x -> bf16 | W1 -> W1t bf16 rows [0,256) | W2 -> W2tp bf16 [16][256]
//       | Wa = W1 @ a_{src,dst} -> W1t rows [256,272)
// ---------------------------------------------------------------------------
#define CAST_BLOCKS 12500
#define W1T_BASE 12500
#define W2T_BASE 12564
#define WA_BASE  12565
#define PREP_BLOCKS 12566

__global__ __launch_bounds__(256) void prep_kernel(const float4* __restrict__ X4,
                                                   ushort4* __restrict__ Xb,
                                                   const float* __restrict__ W1,
                                                   ushort* __restrict__ W1t,
                                                   const float* __restrict__ W2,
                                                   ushort* __restrict__ W2tp,
                                                   const float* __restrict__ asrc1,
                                                   const float* __restrict__ adst1) {
  int b = blockIdx.x;
  int tid = threadIdx.x;
  if (b < CAST_BLOCKS) {
    int i = b * 256 + tid;
    float4 v = X4[i];
    ushort4 o;
    o.x = f2bf(v.x); o.y = f2bf(v.y); o.z = f2bf(v.z); o.w = f2bf(v.w);
    Xb[i] = o;
  } else if (b < W2T_BASE) {
    __shared__ float t[32][33];
    int bb = b - W1T_BASE;
    int k0 = (bb >> 3) * 32, n0 = (bb & 7) * 32;
    int tx = tid & 31, ty = tid >> 5;  // ty 0..7
    for (int r = 0; r < 32; r += 8)
      t[ty + r][tx] = W1[(k0 + ty + r) * 256 + n0 + tx];
    __syncthreads();
    for (int r = 0; r < 32; r += 8)
      W1t[(n0 + ty + r) * 256 + k0 + tx] = f2bf(t[tx][ty + r]);
  } else if (b == W2T_BASE) {
    int k = tid;  // 0..255
#pragma unroll
    for (int c = 0; c < 16; ++c)
      W2tp[c * 256 + k] = (c < NCLS) ? f2bf(W2[k * NCLS + c]) : (ushort)0;
  } else {
    int k = tid;  // 0..255
    const float* wrow = W1 + k * 256;
#pragma unroll
    for (int h = 0; h < 8; ++h) {
      float s = 0.f, d = 0.f;
#pragma unroll
      for (int c = 0; c < 32; ++c) {
        float w = wrow[h * 32 + c];
        s += w * asrc1[h * 32 + c];
        d += w * adst1[h * 32 + c];
      }
      W1t[(256 + h) * 256 + k] = f2bf(s);
      W1t[(264 + h) * 256 + k] = f2bf(d);
    }
  }
}

// ---------------------------------------------------------------------------
// GEMM1 MFMA: h1 = x @ W1 (bf16 in, FP8 e4m3 out), + fused as1/ad1 = x @ Wa.
// A-tile (64 rows x 256 k) staged in LDS in fragment order (conflict-free
// ds_read_b128 at lane*16); B streams from global (L2-resident).
// ---------------------------------------------------------------------------
#define GEMM_BLOCKS ((N_NODES + 63) / 64)

__global__ __launch_bounds__(256) void gemm1_mfma(const ushort* __restrict__ Xb,
                                                  const ushort* __restrict__ W1t,
                                                  unsigned char* __restrict__ h1f8,
                                                  float* __restrict__ as1,
                                                  float* __restrict__ ad1) {
  __shared__ ushort As[32][64][8];   // [tile = mi*8+ks][lane][8 bf16] = 32 KB
  int wid = threadIdx.x >> 6, lane = threadIdx.x & 63;
  int r = lane & 15, kg = lane >> 4;
  int m0 = blockIdx.x * 64;
  int n0 = wid * 64;
  bool extra = (wid == 3);

  // cooperative A staging: wave w stages the 8 k-tiles of mi = w
  {
    int mi = wid;
    int row = m0 + mi * 16 + r;
    if (row >= N_NODES) row = 0;
    const ushort* src = Xb + (size_t)row * 256 + kg * 8;
    bf16x8 v0 = *reinterpret_cast<const bf16x8*>(src);
    bf16x8 v1 = *reinterpret_cast<const bf16x8*>(src + 32);
    bf16x8 v2 = *reinterpret_cast<const bf16x8*>(src + 64);
    bf16x8 v3 = *reinterpret_cast<const bf16x8*>(src + 96);
    bf16x8 v4 = *reinterpret_cast<const bf16x8*>(src + 128);
    bf16x8 v5 = *reinterpret_cast<const bf16x8*>(src + 160);
    bf16x8 v6 = *reinterpret_cast<const bf16x8*>(src + 192);
    bf16x8 v7 = *reinterpret_cast<const bf16x8*>(src + 224);
    *reinterpret_cast<bf16x8*>(&As[mi * 8 + 0][lane][0]) = v0;
    *reinterpret_cast<bf16x8*>(&As[mi * 8 + 1][lane][0]) = v1;
    *reinterpret_cast<bf16x8*>(&As[mi * 8 + 2][lane][0]) = v2;
    *reinterpret_cast<bf16x8*>(&As[mi * 8 + 3][lane][0]) = v3;
    *reinterpret_cast<bf16x8*>(&As[mi * 8 + 4][lane][0]) = v4;
    *reinterpret_cast<bf16x8*>(&As[mi * 8 + 5][lane][0]) = v5;
    *reinterpret_cast<bf16x8*>(&As[mi * 8 + 6][lane][0]) = v6;
    *reinterpret_cast<bf16x8*>(&As[mi * 8 + 7][lane][0]) = v7;
  }
  __syncthreads();

  f32x4 acc[4][4];
  f32x4 accE[4];
#pragma unroll
  for (int mi = 0; mi < 4; ++mi) {
#pragma unroll
    for (int ni = 0; ni < 4; ++ni) acc[mi][ni] = 0;
    accE[mi] = 0;
  }

  const ushort* bptr[4];
#pragma unroll
  for (int ni = 0; ni < 4; ++ni)
    bptr[ni] = W1t + (size_t)(n0 + ni * 16 + r) * 256 + kg * 8;
  const ushort* bptrE = W1t + (size_t)(256 + r) * 256 + kg * 8;

#pragma unroll 2
  for (int ks = 0; ks < 8; ++ks) {
    int k0 = ks * 32;
    bf16x8 a[4], b[4], bE;
#pragma unroll
    for (int ni = 0; ni < 4; ++ni)
      b[ni] = *reinterpret_cast<const bf16x8*>(bptr[ni] + k0);
    if (extra) bE = *reinterpret_cast<const bf16x8*>(bptrE + k0);
#pragma unroll
    for (int mi = 0; mi < 4; ++mi)
      a[mi] = *reinterpret_cast<const bf16x8*>(&As[mi * 8 + ks][lane][0]);
#pragma unroll
    for (int mi = 0; mi < 4; ++mi) {
#pragma unroll
      for (int ni = 0; ni < 4; ++ni)
        acc[mi][ni] = __builtin_amdgcn_mfma_f32_16x16x32_bf16(a[mi], b[ni], acc[mi][ni], 0, 0, 0);
      if (extra)
        accE[mi] = __builtin_amdgcn_mfma_f32_16x16x32_bf16(a[mi], bE, accE[mi], 0, 0, 0);
    }
  }

#pragma unroll
  for (int mi = 0; mi < 4; ++mi) {
#pragma unroll
    for (int q = 0; q < 4; ++q) {
      int row = m0 + mi * 16 + kg * 4 + q;
      if (row < N_NODES) {
#pragma unroll
        for (int ni = 0; ni < 4; ++ni)
          h1f8[(size_t)row * 256 + n0 + ni * 16 + r] = enc8(acc[mi][ni][q]);
        if (extra) {
          float* dst = (r < 8) ? (as1 + row * 8 + r) : (ad1 + row * 8 + (r & 7));
          *dst = accE[mi][q];
        }
      }
    }
  }
}

// ---------------------------------------------------------------------------
// Atomic-free CSR build: two-level counting sort (LDS atomics only)
// ---------------------------------------------------------------------------
__global__ __launch_bounds__(256) void k_hist(const int* __restrict__ ei,
                                              int* __restrict__ histg) {
  __shared__ int h[NBKT];
  int tid = threadIdx.x;
  for (int j = tid; j < NBKT; j += 256) h[j] = 0;
  __syncthreads();
  int base = blockIdx.x * EPB;
#pragma unroll
  for (int t = 0; t < 4; ++t) {
    int i = base + t * 256 + tid;
    if (i < E_TOT) {
      int d = (i < N_EDGES) ? ei[N_EDGES + i] : (i - N_EDGES);
      atomicAdd(&h[d >> 8], 1);
    }
  }
  __syncthreads();
  for (int j = tid; j < NBKT; j += 256) histg[j * NB1 + blockIdx.x] = h[j];
}

// per-bucket exclusive scan over the NB1 block counts (in place) + totals
__global__ __launch_bounds__(256) void k_scan(int* __restrict__ histg,
                                              int* __restrict__ tot) {
  __shared__ int sh[256];
  int b = blockIdx.x, tid = threadIdx.x;
  int carry = 0;
  for (int c = 0; c < (NB1 + 255) / 256; ++c) {
    int j = c * 256 + tid;
    int v = (j < NB1) ? histg[b * NB1 + j] : 0;
    sh[tid] = v;
    __syncthreads();
    for (int d = 1; d < 256; d <<= 1) {
      int t = (tid >= d) ? sh[tid - d] : 0;
      __syncthreads();
      sh[tid] += t;
      __syncthreads();
    }
    if (j < NB1) histg[b * NB1 + j] = carry + sh[tid] - v;  // exclusive
    carry += sh[255];
    __syncthreads();
  }
  if (tid == 0) tot[b] = carry;
}

__global__ __launch_bounds__(256) void k_base(const int* __restrict__ tot,
                                              int* __restrict__ baseg) {
  __shared__ int sh[256];
  int tid = threadIdx.x;
  int v = (tid < NBKT) ? tot[tid] : 0;
  sh[tid] = v;
  __syncthreads();
  for (int d = 1; d < 256; d <<= 1) {
    int t = (tid >= d) ? sh[tid - d] : 0;
    __syncthreads();
    sh[tid] += t;
    __syncthreads();
  }
  if (tid < NBKT) baseg[tid] = sh[tid] - v;
  if (tid == 255) baseg[NBKT] = sh[255];
}

// place edges into coarse-sorted array, packed (dst<<16)|src (both < 65536)
__global__ __launch_bounds__(256) void k_place(const int* __restrict__ ei,
                                               const int* __restrict__ histg,
                                               const int* __restrict__ baseg,
                                               unsigned int* __restrict__ cs) {
  __shared__ int h[NBKT];
  __shared__ int basec[NBKT];
  int tid = threadIdx.x;
  for (int j = tid; j < NBKT; j += 256) {
    h[j] = 0;
    basec[j] = baseg[j] + histg[j * NB1 + blockIdx.x];
  }
  __syncthreads();
  int base = blockIdx.x * EPB;
#pragma unroll
  for (int t = 0; t < 4; ++t) {
    int i = base + t * 256 + tid;
    if (i < E_TOT) {
      int s = (i < N_EDGES) ? ei[i] : (i - N_EDGES);
      int d = (i < N_EDGES) ? ei[N_EDGES + i] : (i - N_EDGES);
      int bk = d >> 8;
      int r = atomicAdd(&h[bk], 1);
      cs[basec[bk] + r] = ((unsigned)d << 16) | (unsigned)s;
    }
  }
}

// fine pass: one block per coarse bucket; emit off[] and csr[]
__global__ __launch_bounds__(256) void k_fine(const unsigned int* __restrict__ cs,
                                              const int* __restrict__ baseg,
                                              int* __restrict__ csr,
                                              int* __restrict__ off) {
  __shared__ int cnt[256];
  __shared__ int sh[256];
  __shared__ int scn[256];
  __shared__ int cur[256];
  int b = blockIdx.x, tid = threadIdx.x;
  int lo = baseg[b], hi = baseg[b + 1];
  cnt[tid] = 0;
  cur[tid] = 0;
  __syncthreads();
  for (int i = lo + tid; i < hi; i += 256) atomicAdd(&cnt[(cs[i] >> 16) & 255], 1);
  __syncthreads();
  int v = cnt[tid];
  sh[tid] = v;
  __syncthreads();
  for (int d = 1; d < 256; d <<= 1) {
    int t = (tid >= d) ? sh[tid - d] : 0;
    __syncthreads();
    sh[tid] += t;
    __syncthreads();
  }
  scn[tid] = sh[tid] - v;  // exclusive scan of dst-low-byte counts
  int idx = b * 256 + tid;
  if (idx <= N_NODES) off[idx] = lo + scn[tid];
  __syncthreads();
  for (int i = lo + tid; i < hi; i += 256) {
    unsigned e = cs[i];
    int dl = (e >> 16) & 255;
    int r = atomicAdd(&cur[dl], 1);
    csr[lo + scn[dl] + r] = (int)(e & 0xFFFFu);
  }
}

// ---------------------------------------------------------------------------
// layer-1 aggregation + bias + elu -> h2 (bf16). h1 gathered as FP8 e4m3,
// decoded with hardware cvt_pk_f32_fp8. 4 edge slots x 16 ch lanes, 2-unroll.
// ---------------------------------------------------------------------------
__global__ __launch_bounds__(256) void agg1_kernel(const unsigned char* __restrict__ h1f8,
                                                   const float* __restrict__ as1,
                                                   const float* __restrict__ ad1,
                                                   const int* __restrict__ off,
                                                   const int* __restrict__ csr,
                                                   const float* __restrict__ b1,
                                                   ushort* __restrict__ h2b) {
  int n = (blockIdx.x * 256 + threadIdx.x) >> 6;
  int lane = threadIdx.x & 63;
  int p0 = off[n], p1 = off[n + 1];

  int sl = lane >> 4;          // edge slot 0..3
  int cl = lane & 15;          // channel group
  int cb = cl * 16;            // channel base (16 channels per lane)
  int h = cl >> 1;             // head = channel/32
  float ad = ad1[n * 8 + h];

  float ssum = 0.f;
  float acc[16] = {};

  int p = p0 + sl;
  for (; p + 4 < p1; p += 8) {
    int sA = csr[p], sB = csr[p + 4];
    float eA = as1[sA * 8 + h] + ad;
    float eB = as1[sB * 8 + h] + ad;
    uint4 rA = *reinterpret_cast<const uint4*>(h1f8 + (size_t)sA * 256 + cb);
    uint4 rB = *reinterpret_cast<const uint4*>(h1f8 + (size_t)sB * 256 + cb);
    eA = eA > 0.f ? eA : 0.2f * eA;
    eB = eB > 0.f ? eB : 0.2f * eB;
    float wA = __expf(eA), wB = __expf(eB);
    ssum += wA + wB;
    fma4(wA, rA.x, acc);      fma4(wB, rB.x, acc);
    fma4(wA, rA.y, acc + 4);  fma4(wB, rB.y, acc + 4);
    fma4(wA, rA.z, acc + 8);  fma4(wB, rB.z, acc + 8);
    fma4(wA, rA.w, acc + 12); fma4(wB, rB.w, acc + 12);
  }
  for (; p < p1; p += 4) {
    int sA = csr[p];
    float eA = as1[sA * 8 + h] + ad;
    uint4 rA = *reinterpret_cast<const uint4*>(h1f8 + (size_t)sA * 256 + cb);
    eA = eA > 0.f ? eA : 0.2f * eA;
    float wA = __expf(eA);
    ssum += wA;
    fma4(wA, rA.x, acc);
    fma4(wA, rA.y, acc + 4);
    fma4(wA, rA.z, acc + 8);
    fma4(wA, rA.w, acc + 12);
  }

  // reduce across the 4 edge slots
  ssum += __shfl_xor(ssum, 16); ssum += __shfl_xor(ssum, 32);
#pragma unroll
  for (int c = 0; c < 16; ++c) {
    acc[c] += __shfl_xor(acc[c], 16);
    acc[c] += __shfl_xor(acc[c], 32);
  }

  if (sl == 0) {
    float inv = 1.f / ssum;
    float o[16];
    float4 b0 = *reinterpret_cast<const float4*>(b1 + cb);
    float4 b1v = *reinterpret_cast<const float4*>(b1 + cb + 4);
    float4 b2v = *reinterpret_cast<const float4*>(b1 + cb + 8);
    float4 b3v = *reinterpret_cast<const float4*>(b1 + cb + 12);
    float bb[16] = {b0.x, b0.y, b0.z, b0.w, b1v.x, b1v.y, b1v.z, b1v.w,
                    b2v.x, b2v.y, b2v.z, b2v.w, b3v.x, b3v.y, b3v.z, b3v.w};
#pragma unroll
    for (int c = 0; c < 16; ++c) {
      float v = acc[c] * inv + bb[c];
      o[c] = v > 0.f ? v : __expf(v) - 1.f;
    }
    int4 o0, o1;
    o0.x = (int)(((unsigned)f2bf(o[1]) << 16) | f2bf(o[0]));
    o0.y = (int)(((unsigned)f2bf(o[3]) << 16) | f2bf(o[2]));
    o0.z = (int)(((unsigned)f2bf(o[5]) << 16) | f2bf(o[4]));
    o0.w = (int)(((unsigned)f2bf(o[7]) << 16) | f2bf(o[6]));
    o1.x = (int)(((unsigned)f2bf(o[9]) << 16) | f2bf(o[8]));
    o1.y = (int)(((unsigned)f2bf(o[11]) << 16) | f2bf(o[10]));
    o1.z = (int)(((unsigned)f2bf(o[13]) << 16) | f2bf(o[12]));
    o1.w = (int)(((unsigned)f2bf(o[15]) << 16) | f2bf(o[14]));
    *reinterpret_cast<int4*>(h2b + (size_t)n * 256 + cb) = o0;
    *reinterpret_cast<int4*>(h2b + (size_t)n * 256 + cb + 8) = o1;
  }
}

// ---------------------------------------------------------------------------
// layer-2 projection via MFMA: pj2p[50000][16] = h2 @ W2tp^T, + as2/ad2
// ---------------------------------------------------------------------------
__global__ __launch_bounds__(256) void proj2_mfma(const ushort* __restrict__ h2b,
                                                  const ushort* __restrict__ W2tp,
                                                  const float* __restrict__ asrc2,
                                                  const float* __restrict__ adst2,
                                                  float* __restrict__ pj2p,
                                                  float* __restrict__ as2,
                                                  float* __restrict__ ad2) {
  int wid = threadIdx.x >> 6, lane = threadIdx.x & 63;
  int r = lane & 15, kg = lane >> 4;
  int rb = blockIdx.x * 64 + wid * 16;
  int row_a = rb + r;
  if (row_a >= N_NODES) row_a = 0;
  const ushort* ap = h2b + (size_t)row_a * 256 + kg * 8;
  const ushort* bp = W2tp + (size_t)r * 256 + kg * 8;
  f32x4 acc = 0;
#pragma unroll
  for (int k0 = 0; k0 < 256; k0 += 32)
    acc = __builtin_amdgcn_mfma_f32_16x16x32_bf16(
        *reinterpret_cast<const bf16x8*>(ap + k0),
        *reinterpret_cast<const bf16x8*>(bp + k0), acc, 0, 0, 0);

  float av = (r < NCLS) ? asrc2[r] : 0.f;
  float dv = (r < NCLS) ? adst2[r] : 0.f;
#pragma unroll
  for (int q = 0; q < 4; ++q) {
    int row = rb + kg * 4 + q;
    float v = acc[q];
    if (row < N_NODES) pj2p[row * 16 + r] = v;
    float s = v * av, d = v * dv;
    s += __shfl_xor(s, 1); s += __shfl_xor(s, 2); s += __shfl_xor(s, 4); s += __shfl_xor(s, 8);
    d += __shfl_xor(d, 1); d += __shfl_xor(d, 2); d += __shfl_xor(d, 4); d += __shfl_xor(d, 8);
    if (r == 0 && row < N_NODES) { as2[row] = s; ad2[row] = d; }
  }
}

// ---------------------------------------------------------------------------
// layer-2 aggregation: single pass, 4 edge slots x 16 channel lanes, 4-deep
// ---------------------------------------------------------------------------
__global__ __launch_bounds__(256) void agg2_kernel(const float* __restrict__ pj2p,
                                                   const float* __restrict__ as2,
                                                   const float* __restrict__ ad2,
                                                   const int* __restrict__ off,
                                                   const int* __restrict__ csr,
                                                   const float* __restrict__ b2,
                                                   float* __restrict__ out2p) {
  int n = (blockIdx.x * 256 + threadIdx.x) >> 6;
  int lane = threadIdx.x & 63;
  int p0 = off[n], p1 = off[n + 1];
  float ad = ad2[n];
  int es = lane >> 4, c = lane & 15;
  float ssum = 0.f, acc = 0.f;
  int p = p0 + es;
  for (; p + 12 < p1; p += 16) {
    int s0 = csr[p], s1 = csr[p + 4], s2 = csr[p + 8], s3 = csr[p + 12];
    float e0 = as2[s0] + ad, e1 = as2[s1] + ad, e2 = as2[s2] + ad, e3 = as2[s3] + ad;
    float v0 = pj2p[s0 * 16 + c], v1 = pj2p[s1 * 16 + c];
    float v2 = pj2p[s2 * 16 + c], v3 = pj2p[s3 * 16 + c];
    e0 = e0 > 0.f ? e0 : 0.2f * e0;
    e1 = e1 > 0.f ? e1 : 0.2f * e1;
    e2 = e2 > 0.f ? e2 : 0.2f * e2;
    e3 = e3 > 0.f ? e3 : 0.2f * e3;
    float w0 = __expf(e0), w1 = __expf(e1), w2 = __expf(e2), w3 = __expf(e3);
    ssum += (w0 + w1) + (w2 + w3);
    acc += (w0 * v0 + w1 * v1) + (w2 * v2 + w3 * v3);
  }
  for (; p < p1; p += 4) {
    int sA = csr[p];
    float eA = as2[sA] + ad;
    float vA = pj2p[sA * 16 + c];
    eA = eA > 0.f ? eA : 0.2f * eA;
    float wA = __expf(eA);
    ssum += wA;
    acc += wA * vA;
  }
  acc += __shfl_xor(acc, 16); acc += __shfl_xor(acc, 32);
  ssum += __shfl_xor(ssum, 16); ssum += __shfl_xor(ssum, 32);
  if (lane < 16) {
    float bc = (lane < NCLS) ? b2[lane] : 0.f;
    out2p[n * 16 + lane] = acc / ssum + bc;
  }
}

// ---------------------------------------------------------------------------
// global mean pool
// ---------------------------------------------------------------------------
__global__ __launch_bounds__(256) void pool_kernel(const float* __restrict__ out2p,
                                                   const int* __restrict__ batch,
                                                   float* __restrict__ outp) {
  __shared__ float red[256];
  int g = blockIdx.x;
  int lo = 0, hi = N_NODES;
  while (lo < hi) { int mid = (lo + hi) >> 1; if (batch[mid] < g) lo = mid + 1; else hi = mid; }
  int start = lo;
  hi = N_NODES;
  while (lo < hi) { int mid = (lo + hi) >> 1; if (batch[mid] < g + 1) lo = mid + 1; else hi = mid; }
  int end = lo;
  int t = threadIdx.x;
  int c = t & 15, nsl = t >> 4;
  float loc = 0.f;
  for (int nn = start + nsl; nn < end; nn += 16) loc += out2p[nn * 16 + c];
  red[t] = loc;
  __syncthreads();
  for (int s = 128; s >= 16; s >>= 1) {
    if (t < s) red[t] += red[t + s];
    __syncthreads();
  }
  if (t < NCLS) {
    float denom = fmaxf((float)(end - start), 1.f);
    outp[g * NCLS + t] = red[t] / denom;
  }
}

// ---------------------------------------------------------------------------
extern "C" void kernel_launch(void* const* d_in, const int* in_sizes, int n_in,
                              void* d_out, int out_size, void* d_ws, size_t ws_size,
                              hipStream_t stream) {
  const float* x      = (const float*)d_in[0];
  const float* W1     = (const float*)d_in[1];
  const float* a_src1 = (const float*)d_in[2];
  const float* a_dst1 = (const float*)d_in[3];
  const float* b1     = (const float*)d_in[4];
  const float* W2     = (const float*)d_in[5];
  const float* a_src2 = (const float*)d_in[6];
  const float* a_dst2 = (const float*)d_in[7];
  const float* b2     = (const float*)d_in[8];
  const int*   ei     = (const int*)d_in[9];
  const int*   batch  = (const int*)d_in[10];

  char* ws = (char*)d_ws;
  size_t o = 0;
  auto alloc = [&](size_t bytes) {
    char* p = ws + o;
    o = (o + bytes + 255) & ~(size_t)255;
    return p;
  };
  ushort* xb   = (ushort*)alloc((size_t)N_NODES * 256 * 2);
  ushort* w1t  = (ushort*)alloc((size_t)272 * 256 * 2);
  ushort* w2tp = (ushort*)alloc((size_t)16 * 256 * 2);
  unsigned char* h1f8 = (unsigned char*)alloc((size_t)N_NODES * 256);
  ushort* h2b  = (ushort*)alloc((size_t)N_NODES * 256 * 2);
  float* as1   = (float*)alloc((size_t)N_NODES * 8 * 4);
  float* ad1   = (float*)alloc((size_t)N_NODES * 8 * 4);
  float* pj2p  = (float*)alloc((size_t)N_NODES * 16 * 4);
  float* as2   = (float*)alloc((size_t)N_NODES * 4);
  float* ad2   = (float*)alloc((size_t)N_NODES * 4);
  float* out2p = (float*)alloc((size_t)N_NODES * 16 * 4);
  int*   histg = (int*)alloc((size_t)NBKT * NB1 * 4);
  int*   tot   = (int*)alloc((size_t)NBKT * 4);
  int*   baseg = (int*)alloc((size_t)(NBKT + 1) * 4);
  unsigned int* cs = (unsigned int*)alloc((size_t)E_TOT * 4);
  int*   csr   = (int*)alloc((size_t)E_TOT * 4);
  int*   off   = (int*)alloc((size_t)(N_NODES + 1) * 4);

  prep_kernel<<<PREP_BLOCKS, 256, 0, stream>>>((const float4*)x, (ushort4*)xb,
                                               W1, w1t, W2, w2tp, a_src1, a_dst1);
  gemm1_mfma<<<GEMM_BLOCKS, 256, 0, stream>>>(xb, w1t, h1f8, as1, ad1);

  k_hist<<<NB1, 256, 0, stream>>>(ei, histg);
  k_scan<<<NBKT, 256, 0, stream>>>(histg, tot);
  k_base<<<1, 256, 0, stream>>>(tot, baseg);
  k_place<<<NB1, 256, 0, stream>>>(ei, histg, baseg, cs);
  k_fine<<<NBKT, 256, 0, stream>>>(cs, baseg, csr, off);

  agg1_kernel<<<N_NODES / 4, 256, 0, stream>>>(h1f8, as1, ad1, off, csr, b1, h2b);
  proj2_mfma<<<GEMM_BLOCKS, 256, 0, stream>>>(h2b, w2tp, a_src2, a_dst2,
                                              pj2p, as2, ad2);
  agg2_kernel<<<N_NODES / 4, 256, 0, stream>>>(pj2p, as2, ad2, off, csr, b2, out2p);
  pool_kernel<<<NGRP, 256, 0, stream>>>(out2p, batch, (float*)d_out);
}

// Round 10
// 264.901 us; speedup vs baseline: 2.0546x; 1.0183x over previous
//
#include <hip/hip_runtime.h>
#include <hip/hip_bf16.h>
#include <math.h>

#define N_NODES 50000
#define N_EDGES 800000
#define E_TOT   (N_EDGES + N_NODES)   /* 850000 with self loops */
#define NCLS 10
#define NGRP 128

#define NBKT 196                       /* coarse buckets: dst>>8, dst<50000 */
#define EPB  1024                      /* edges per hist/place block */
#define NB1  ((E_TOT + EPB - 1) / EPB) /* 831 */

typedef __attribute__((ext_vector_type(8))) short bf16x8;
typedef __attribute__((ext_vector_type(4))) float f32x4;
typedef __attribute__((ext_vector_type(2))) float f32x2;

static __device__ __forceinline__ ushort f2bf(float f) {
  union { float f; unsigned u; } v; v.f = f;
  unsigned r = v.u + 0x7fffu + ((v.u >> 16) & 1u);   // round-to-nearest-even
  return (ushort)(r >> 16);
}
// hardware OCP e4m3 encode: 1 inst + extract
static __device__ __forceinline__ unsigned char enc8(float v) {
  int p = __builtin_amdgcn_cvt_pk_fp8_f32(v, v, 0, false);
  return (unsigned char)(p & 0xFF);
}
// hardware decode of 4 packed fp8 -> 2x f32x2, packed fma into acc
static __device__ __forceinline__ void fma4p(float w, unsigned u, f32x2* a) {
  f32x2 w2; w2[0] = w; w2[1] = w;
  a[0] += w2 * __builtin_amdgcn_cvt_pk_f32_fp8(u, false);
  a[1] += w2 * __builtin_amdgcn_cvt_pk_f32_fp8(u, true);
}

// ---------------------------------------------------------------------------
// prep: cast x -> bf16 (grid-stride) | W1 -> W1t bf16 rows [0,256) |
//       W2 -> W2tp bf16 [16][256] | Wa -> W1t rows [256,272) | edge histogram
// ---------------------------------------------------------------------------
#define CAST_BLOCKS 2048
#define NX4 (N_NODES * 64)            /* 3.2M float4 elements in x */
#define W1T_BASE CAST_BLOCKS
#define W2T_BASE (W1T_BASE + 64)
#define WA_BASE  (W2T_BASE + 1)
#define HIST_BASE (WA_BASE + 1)
#define PREP_BLOCKS (HIST_BASE + NB1)

__global__ __launch_bounds__(256) void prep_kernel(const float4* __restrict__ X4,
                                                   ushort4* __restrict__ Xb,
                                                   const float* __restrict__ W1,
                                                   ushort* __restrict__ W1t,
                                                   const float* __restrict__ W2,
                                                   ushort* __restrict__ W2tp,
                                                   const float* __restrict__ asrc1,
                                                   const float* __restrict__ adst1,
                                                   const int* __restrict__ ei,
                                                   int* __restrict__ histg) {
  int b = blockIdx.x;
  int tid = threadIdx.x;
  if (b < CAST_BLOCKS) {
    for (int i = b * 256 + tid; i < NX4; i += CAST_BLOCKS * 256) {
      float4 v = X4[i];
      ushort4 o;
      o.x = f2bf(v.x); o.y = f2bf(v.y); o.z = f2bf(v.z); o.w = f2bf(v.w);
      Xb[i] = o;
    }
  } else if (b < W2T_BASE) {
    __shared__ float t[32][33];
    int bb = b - W1T_BASE;
    int k0 = (bb >> 3) * 32, n0 = (bb & 7) * 32;
    int tx = tid & 31, ty = tid >> 5;  // ty 0..7
    for (int r = 0; r < 32; r += 8)
      t[ty + r][tx] = W1[(k0 + ty + r) * 256 + n0 + tx];
    __syncthreads();
    for (int r = 0; r < 32; r += 8)
      W1t[(n0 + ty + r) * 256 + k0 + tx] = f2bf(t[tx][ty + r]);
  } else if (b == W2T_BASE) {
    int k = tid;  // 0..255
#pragma unroll
    for (int c = 0; c < 16; ++c)
      W2tp[c * 256 + k] = (c < NCLS) ? f2bf(W2[k * NCLS + c]) : (ushort)0;
  } else if (b == WA_BASE) {
    int k = tid;  // 0..255
    const float* wrow = W1 + k * 256;
#pragma unroll
    for (int h = 0; h < 8; ++h) {
      float s = 0.f, d = 0.f;
#pragma unroll
      for (int c = 0; c < 32; ++c) {
        float w = wrow[h * 32 + c];
        s += w * asrc1[h * 32 + c];
        d += w * adst1[h * 32 + c];
      }
      W1t[(256 + h) * 256 + k] = f2bf(s);
      W1t[(264 + h) * 256 + k] = f2bf(d);
    }
  } else {
    // fused edge histogram (independent of prep outputs)
    __shared__ int h[NBKT];
    int bb = b - HIST_BASE;
    for (int j = tid; j < NBKT; j += 256) h[j] = 0;
    __syncthreads();
    int base = bb * EPB;
#pragma unroll
    for (int t = 0; t < 4; ++t) {
      int i = base + t * 256 + tid;
      if (i < E_TOT) {
        int d = (i < N_EDGES) ? ei[N_EDGES + i] : (i - N_EDGES);
        atomicAdd(&h[d >> 8], 1);
      }
    }
    __syncthreads();
    for (int j = tid; j < NBKT; j += 256) histg[j * NB1 + bb] = h[j];
  }
}

// ---------------------------------------------------------------------------
// GEMM1 MFMA: h1 = x @ W1 (bf16 in, FP8 e4m3 out), + fused as1/ad1 = x @ Wa.
// A-tile staged in LDS in fragment order; B streams from global (L2-resident).
// ---------------------------------------------------------------------------
#define GEMM_BLOCKS ((N_NODES + 63) / 64)

__global__ __launch_bounds__(256) void gemm1_mfma(const ushort* __restrict__ Xb,
                                                  const ushort* __restrict__ W1t,
                                                  unsigned char* __restrict__ h1f8,
                                                  float* __restrict__ as1,
                                                  float* __restrict__ ad1) {
  __shared__ ushort As[32][64][8];   // [tile = mi*8+ks][lane][8 bf16] = 32 KB
  int wid = threadIdx.x >> 6, lane = threadIdx.x & 63;
  int r = lane & 15, kg = lane >> 4;
  int m0 = blockIdx.x * 64;
  int n0 = wid * 64;
  bool extra = (wid == 3);

  // cooperative A staging: wave w stages the 8 k-tiles of mi = w
  {
    int mi = wid;
    int row = m0 + mi * 16 + r;
    if (row >= N_NODES) row = 0;
    const ushort* src = Xb + (size_t)row * 256 + kg * 8;
    bf16x8 v0 = *reinterpret_cast<const bf16x8*>(src);
    bf16x8 v1 = *reinterpret_cast<const bf16x8*>(src + 32);
    bf16x8 v2 = *reinterpret_cast<const bf16x8*>(src + 64);
    bf16x8 v3 = *reinterpret_cast<const bf16x8*>(src + 96);
    bf16x8 v4 = *reinterpret_cast<const bf16x8*>(src + 128);
    bf16x8 v5 = *reinterpret_cast<const bf16x8*>(src + 160);
    bf16x8 v6 = *reinterpret_cast<const bf16x8*>(src + 192);
    bf16x8 v7 = *reinterpret_cast<const bf16x8*>(src + 224);
    *reinterpret_cast<bf16x8*>(&As[mi * 8 + 0][lane][0]) = v0;
    *reinterpret_cast<bf16x8*>(&As[mi * 8 + 1][lane][0]) = v1;
    *reinterpret_cast<bf16x8*>(&As[mi * 8 + 2][lane][0]) = v2;
    *reinterpret_cast<bf16x8*>(&As[mi * 8 + 3][lane][0]) = v3;
    *reinterpret_cast<bf16x8*>(&As[mi * 8 + 4][lane][0]) = v4;
    *reinterpret_cast<bf16x8*>(&As[mi * 8 + 5][lane][0]) = v5;
    *reinterpret_cast<bf16x8*>(&As[mi * 8 + 6][lane][0]) = v6;
    *reinterpret_cast<bf16x8*>(&As[mi * 8 + 7][lane][0]) = v7;
  }
  __syncthreads();

  f32x4 acc[4][4];
  f32x4 accE[4];
#pragma unroll
  for (int mi = 0; mi < 4; ++mi) {
#pragma unroll
    for (int ni = 0; ni < 4; ++ni) acc[mi][ni] = 0;
    accE[mi] = 0;
  }

  const ushort* bptr[4];
#pragma unroll
  for (int ni = 0; ni < 4; ++ni)
    bptr[ni] = W1t + (size_t)(n0 + ni * 16 + r) * 256 + kg * 8;
  const ushort* bptrE = W1t + (size_t)(256 + r) * 256 + kg * 8;

#pragma unroll 2
  for (int ks = 0; ks < 8; ++ks) {
    int k0 = ks * 32;
    bf16x8 a[4], b[4], bE;
#pragma unroll
    for (int ni = 0; ni < 4; ++ni)
      b[ni] = *reinterpret_cast<const bf16x8*>(bptr[ni] + k0);
    if (extra) bE = *reinterpret_cast<const bf16x8*>(bptrE + k0);
#pragma unroll
    for (int mi = 0; mi < 4; ++mi)
      a[mi] = *reinterpret_cast<const bf16x8*>(&As[mi * 8 + ks][lane][0]);
#pragma unroll
    for (int mi = 0; mi < 4; ++mi) {
#pragma unroll
      for (int ni = 0; ni < 4; ++ni)
        acc[mi][ni] = __builtin_amdgcn_mfma_f32_16x16x32_bf16(a[mi], b[ni], acc[mi][ni], 0, 0, 0);
      if (extra)
        accE[mi] = __builtin_amdgcn_mfma_f32_16x16x32_bf16(a[mi], bE, accE[mi], 0, 0, 0);
    }
  }

#pragma unroll
  for (int mi = 0; mi < 4; ++mi) {
#pragma unroll
    for (int q = 0; q < 4; ++q) {
      int row = m0 + mi * 16 + kg * 4 + q;
      if (row < N_NODES) {
#pragma unroll
        for (int ni = 0; ni < 4; ++ni)
          h1f8[(size_t)row * 256 + n0 + ni * 16 + r] = enc8(acc[mi][ni][q]);
        if (extra) {
          float* dst = (r < 8) ? (as1 + row * 8 + r) : (ad1 + row * 8 + (r & 7));
          *dst = accE[mi][q];
        }
      }
    }
  }
}

// ---------------------------------------------------------------------------
// Atomic-free CSR build (cont.): scan, base, place, fine
// ---------------------------------------------------------------------------
__global__ __launch_bounds__(256) void k_scan(int* __restrict__ histg,
                                              int* __restrict__ tot) {
  __shared__ int sh[256];
  int b = blockIdx.x, tid = threadIdx.x;
  int carry = 0;
  for (int c = 0; c < (NB1 + 255) / 256; ++c) {
    int j = c * 256 + tid;
    int v = (j < NB1) ? histg[b * NB1 + j] : 0;
    sh[tid] = v;
    __syncthreads();
    for (int d = 1; d < 256; d <<= 1) {
      int t = (tid >= d) ? sh[tid - d] : 0;
      __syncthreads();
      sh[tid] += t;
      __syncthreads();
    }
    if (j < NB1) histg[b * NB1 + j] = carry + sh[tid] - v;  // exclusive
    carry += sh[255];
    __syncthreads();
  }
  if (tid == 0) tot[b] = carry;
}

__global__ __launch_bounds__(256) void k_base(const int* __restrict__ tot,
                                              int* __restrict__ baseg) {
  __shared__ int sh[256];
  int tid = threadIdx.x;
  int v = (tid < NBKT) ? tot[tid] : 0;
  sh[tid] = v;
  __syncthreads();
  for (int d = 1; d < 256; d <<= 1) {
    int t = (tid >= d) ? sh[tid - d] : 0;
    __syncthreads();
    sh[tid] += t;
    __syncthreads();
  }
  if (tid < NBKT) baseg[tid] = sh[tid] - v;
  if (tid == 255) baseg[NBKT] = sh[255];
}

// place edges into coarse-sorted array, packed (dst<<16)|src (both < 65536)
__global__ __launch_bounds__(256) void k_place(const int* __restrict__ ei,
                                               const int* __restrict__ histg,
                                               const int* __restrict__ baseg,
                                               unsigned int* __restrict__ cs) {
  __shared__ int h[NBKT];
  __shared__ int basec[NBKT];
  int tid = threadIdx.x;
  for (int j = tid; j < NBKT; j += 256) {
    h[j] = 0;
    basec[j] = baseg[j] + histg[j * NB1 + blockIdx.x];
  }
  __syncthreads();
  int base = blockIdx.x * EPB;
#pragma unroll
  for (int t = 0; t < 4; ++t) {
    int i = base + t * 256 + tid;
    if (i < E_TOT) {
      int s = (i < N_EDGES) ? ei[i] : (i - N_EDGES);
      int d = (i < N_EDGES) ? ei[N_EDGES + i] : (i - N_EDGES);
      int bk = d >> 8;
      int r = atomicAdd(&h[bk], 1);
      cs[basec[bk] + r] = ((unsigned)d << 16) | (unsigned)s;
    }
  }
}

// fine pass: one block per coarse bucket; emit off[] and csr[] (csr = src*256)
__global__ __launch_bounds__(256) void k_fine(const unsigned int* __restrict__ cs,
                                              const int* __restrict__ baseg,
                                              int* __restrict__ csr,
                                              int* __restrict__ off) {
  __shared__ int cnt[256];
  __shared__ int sh[256];
  __shared__ int scn[256];
  __shared__ int cur[256];
  int b = blockIdx.x, tid = threadIdx.x;
  int lo = baseg[b], hi = baseg[b + 1];
  cnt[tid] = 0;
  cur[tid] = 0;
  __syncthreads();
  for (int i = lo + tid; i < hi; i += 256) atomicAdd(&cnt[(cs[i] >> 16) & 255], 1);
  __syncthreads();
  int v = cnt[tid];
  sh[tid] = v;
  __syncthreads();
  for (int d = 1; d < 256; d <<= 1) {
    int t = (tid >= d) ? sh[tid - d] : 0;
    __syncthreads();
    sh[tid] += t;
    __syncthreads();
  }
  scn[tid] = sh[tid] - v;  // exclusive scan of dst-low-byte counts
  int idx = b * 256 + tid;
  if (idx <= N_NODES) off[idx] = lo + scn[tid];
  __syncthreads();
  for (int i = lo + tid; i < hi; i += 256) {
    unsigned e = cs[i];
    int dl = (e >> 16) & 255;
    int r = atomicAdd(&cur[dl], 1);
    csr[lo + scn[dl] + r] = (int)((e & 0xFFFFu) << 8);   // src*256
  }
}

// ---------------------------------------------------------------------------
// layer-1 aggregation + bias + elu -> h2 (bf16). h1 gathered as FP8 e4m3,
// HW cvt + packed f32x2 fma. csr holds src*256 (as1 idx = v>>5).
// 4 edge slots x 16 channel lanes, 2-unroll (8 edges in flight).
// ---------------------------------------------------------------------------
__global__ __launch_bounds__(256) void agg1_kernel(const unsigned char* __restrict__ h1f8,
                                                   const float* __restrict__ as1,
                                                   const float* __restrict__ ad1,
                                                   const int* __restrict__ off,
                                                   const int* __restrict__ csr,
                                                   const float* __restrict__ b1,
                                                   ushort* __restrict__ h2b) {
  int n = (blockIdx.x * 256 + threadIdx.x) >> 6;
  int lane = threadIdx.x & 63;
  int p0 = off[n], p1 = off[n + 1];

  int sl = lane >> 4;          // edge slot 0..3
  int cl = lane & 15;          // channel group
  int cb = cl * 16;            // channel base (16 channels per lane)
  int h = cl >> 1;             // head = channel/32
  float ad = ad1[n * 8 + h];

  float ssum = 0.f;
  f32x2 acc2[8];
#pragma unroll
  for (int j = 0; j < 8; ++j) { acc2[j][0] = 0.f; acc2[j][1] = 0.f; }

  int p = p0 + sl;
  for (; p + 4 < p1; p += 8) {
    int vA = csr[p], vB = csr[p + 4];          // src*256
    float eA = as1[(vA >> 5) + h] + ad;
    float eB = as1[(vB >> 5) + h] + ad;
    uint4 rA = *reinterpret_cast<const uint4*>(h1f8 + vA + cb);
    uint4 rB = *reinterpret_cast<const uint4*>(h1f8 + vB + cb);
    eA = eA > 0.f ? eA : 0.2f * eA;
    eB = eB > 0.f ? eB : 0.2f * eB;
    float wA = __expf(eA), wB = __expf(eB);
    ssum += wA + wB;
    fma4p(wA, rA.x, acc2 + 0); fma4p(wB, rB.x, acc2 + 0);
    fma4p(wA, rA.y, acc2 + 2); fma4p(wB, rB.y, acc2 + 2);
    fma4p(wA, rA.z, acc2 + 4); fma4p(wB, rB.z, acc2 + 4);
    fma4p(wA, rA.w, acc2 + 6); fma4p(wB, rB.w, acc2 + 6);
  }
  for (; p < p1; p += 4) {
    int vA = csr[p];
    float eA = as1[(vA >> 5) + h] + ad;
    uint4 rA = *reinterpret_cast<const uint4*>(h1f8 + vA + cb);
    eA = eA > 0.f ? eA : 0.2f * eA;
    float wA = __expf(eA);
    ssum += wA;
    fma4p(wA, rA.x, acc2 + 0);
    fma4p(wA, rA.y, acc2 + 2);
    fma4p(wA, rA.z, acc2 + 4);
    fma4p(wA, rA.w, acc2 + 6);
  }

  // reduce across the 4 edge slots
  ssum += __shfl_xor(ssum, 16); ssum += __shfl_xor(ssum, 32);
#pragma unroll
  for (int j = 0; j < 8; ++j) {
    acc2[j][0] += __shfl_xor(acc2[j][0], 16);
    acc2[j][0] += __shfl_xor(acc2[j][0], 32);
    acc2[j][1] += __shfl_xor(acc2[j][1], 16);
    acc2[j][1] += __shfl_xor(acc2[j][1], 32);
  }

  if (sl == 0) {
    float inv = 1.f / ssum;
    float o[16];
    float4 b0 = *reinterpret_cast<const float4*>(b1 + cb);
    float4 b1v = *reinterpret_cast<const float4*>(b1 + cb + 4);
    float4 b2v = *reinterpret_cast<const float4*>(b1 + cb + 8);
    float4 b3v = *reinterpret_cast<const float4*>(b1 + cb + 12);
    float bb[16] = {b0.x, b0.y, b0.z, b0.w, b1v.x, b1v.y, b1v.z, b1v.w,
                    b2v.x, b2v.y, b2v.z, b2v.w, b3v.x, b3v.y, b3v.z, b3v.w};
#pragma unroll
    for (int c = 0; c < 16; ++c) {
      float v = acc2[c >> 1][c & 1] * inv + bb[c];
      o[c] = v > 0.f ? v : __expf(v) - 1.f;
    }
    int4 o0, o1;
    o0.x = (int)(((unsigned)f2bf(o[1]) << 16) | f2bf(o[0]));
    o0.y = (int)(((unsigned)f2bf(o[3]) << 16) | f2bf(o[2]));
    o0.z = (int)(((unsigned)f2bf(o[5]) << 16) | f2bf(o[4]));
    o0.w = (int)(((unsigned)f2bf(o[7]) << 16) | f2bf(o[6]));
    o1.x = (int)(((unsigned)f2bf(o[9]) << 16) | f2bf(o[8]));
    o1.y = (int)(((unsigned)f2bf(o[11]) << 16) | f2bf(o[10]));
    o1.z = (int)(((unsigned)f2bf(o[13]) << 16) | f2bf(o[12]));
    o1.w = (int)(((unsigned)f2bf(o[15]) << 16) | f2bf(o[14]));
    *reinterpret_cast<int4*>(h2b + (size_t)n * 256 + cb) = o0;
    *reinterpret_cast<int4*>(h2b + (size_t)n * 256 + cb + 8) = o1;
  }
}

// ---------------------------------------------------------------------------
// layer-2 projection via MFMA: pj2p[50000][16] = h2 @ W2tp^T, + as2/ad2
// ---------------------------------------------------------------------------
__global__ __launch_bounds__(256) void proj2_mfma(const ushort* __restrict__ h2b,
                                                  const ushort* __restrict__ W2tp,
                                                  const float* __restrict__ asrc2,
                                                  const float* __restrict__ adst2,
                                                  float* __restrict__ pj2p,
                                                  float* __restrict__ as2,
                                                  float* __restrict__ ad2) {
  int wid = threadIdx.x >> 6, lane = threadIdx.x & 63;
  int r = lane & 15, kg = lane >> 4;
  int rb = blockIdx.x * 64 + wid * 16;
  int row_a = rb + r;
  if (row_a >= N_NODES) row_a = 0;
  const ushort* ap = h2b + (size_t)row_a * 256 + kg * 8;
  const ushort* bp = W2tp + (size_t)r * 256 + kg * 8;
  f32x4 acc = 0;
#pragma unroll
  for (int k0 = 0; k0 < 256; k0 += 32)
    acc = __builtin_amdgcn_mfma_f32_16x16x32_bf16(
        *reinterpret_cast<const bf16x8*>(ap + k0),
        *reinterpret_cast<const bf16x8*>(bp + k0), acc, 0, 0, 0);

  float av = (r < NCLS) ? asrc2[r] : 0.f;
  float dv = (r < NCLS) ? adst2[r] : 0.f;
#pragma unroll
  for (int q = 0; q < 4; ++q) {
    int row = rb + kg * 4 + q;
    float v = acc[q];
    if (row < N_NODES) pj2p[row * 16 + r] = v;
    float s = v * av, d = v * dv;
    s += __shfl_xor(s, 1); s += __shfl_xor(s, 2); s += __shfl_xor(s, 4); s += __shfl_xor(s, 8);
    d += __shfl_xor(d, 1); d += __shfl_xor(d, 2); d += __shfl_xor(d, 4); d += __shfl_xor(d, 8);
    if (r == 0 && row < N_NODES) { as2[row] = s; ad2[row] = d; }
  }
}

// ---------------------------------------------------------------------------
// layer-2 aggregation: single pass, 4 edge slots x 16 channel lanes, 4-deep.
// csr holds src*256: as2 idx = v>>8, pj2p idx = (v>>4)+c.
// ---------------------------------------------------------------------------
__global__ __launch_bounds__(256) void agg2_kernel(const float* __restrict__ pj2p,
                                                   const float* __restrict__ as2,
                                                   const float* __restrict__ ad2,
                                                   const int* __restrict__ off,
                                                   const int* __restrict__ csr,
                                                   const float* __restrict__ b2,
                                                   float* __restrict__ out2p) {
  int n = (blockIdx.x * 256 + threadIdx.x) >> 6;
  int lane = threadIdx.x & 63;
  int p0 = off[n], p1 = off[n + 1];
  float ad = ad2[n];
  int es = lane >> 4, c = lane & 15;
  float ssum = 0.f, acc = 0.f;
  int p = p0 + es;
  for (; p + 12 < p1; p += 16) {
    int v0 = csr[p], v1 = csr[p + 4], v2 = csr[p + 8], v3 = csr[p + 12];
    float e0 = as2[v0 >> 8] + ad, e1 = as2[v1 >> 8] + ad;
    float e2 = as2[v2 >> 8] + ad, e3 = as2[v3 >> 8] + ad;
    float q0 = pj2p[(v0 >> 4) + c], q1 = pj2p[(v1 >> 4) + c];
    float q2 = pj2p[(v2 >> 4) + c], q3 = pj2p[(v3 >> 4) + c];
    e0 = e0 > 0.f ? e0 : 0.2f * e0;
    e1 = e1 > 0.f ? e1 : 0.2f * e1;
    e2 = e2 > 0.f ? e2 : 0.2f * e2;
    e3 = e3 > 0.f ? e3 : 0.2f * e3;
    float w0 = __expf(e0), w1 = __expf(e1), w2 = __expf(e2), w3 = __expf(e3);
    ssum += (w0 + w1) + (w2 + w3);
    acc += (w0 * q0 + w1 * q1) + (w2 * q2 + w3 * q3);
  }
  for (; p < p1; p += 4) {
    int vA = csr[p];
    float eA = as2[vA >> 8] + ad;
    float qA = pj2p[(vA >> 4) + c];
    eA = eA > 0.f ? eA : 0.2f * eA;
    float wA = __expf(eA);
    ssum += wA;
    acc += wA * qA;
  }
  acc += __shfl_xor(acc, 16); acc += __shfl_xor(acc, 32);
  ssum += __shfl_xor(ssum, 16); ssum += __shfl_xor(ssum, 32);
  if (lane < 16) {
    float bc = (lane < NCLS) ? b2[lane] : 0.f;
    out2p[n * 16 + lane] = acc / ssum + bc;
  }
}

// ---------------------------------------------------------------------------
// global mean pool
// ---------------------------------------------------------------------------
__global__ __launch_bounds__(256) void pool_kernel(const float* __restrict__ out2p,
                                                   const int* __restrict__ batch,
                                                   float* __restrict__ outp) {
  __shared__ float red[256];
  int g = blockIdx.x;
  int lo = 0, hi = N_NODES;
  while (lo < hi) { int mid = (lo + hi) >> 1; if (batch[mid] < g) lo = mid + 1; else hi = mid; }
  int start = lo;
  hi = N_NODES;
  while (lo < hi) { int mid = (lo + hi) >> 1; if (batch[mid] < g + 1) lo = mid + 1; else hi = mid; }
  int end = lo;
  int t = threadIdx.x;
  int c = t & 15, nsl = t >> 4;
  float loc = 0.f;
  for (int nn = start + nsl; nn < end; nn += 16) loc += out2p[nn * 16 + c];
  red[t] = loc;
  __syncthreads();
  for (int s = 128; s >= 16; s >>= 1) {
    if (t < s) red[t] += red[t + s];
    __syncthreads();
  }
  if (t < NCLS) {
    float denom = fmaxf((float)(end - start), 1.f);
    outp[g * NCLS + t] = red[t] / denom;
  }
}

// ---------------------------------------------------------------------------
extern "C" void kernel_launch(void* const* d_in, const int* in_sizes, int n_in,
                              void* d_out, int out_size, void* d_ws, size_t ws_size,
                              hipStream_t stream) {
  const float* x      = (const float*)d_in[0];
  const float* W1     = (const float*)d_in[1];
  const float* a_src1 = (const float*)d_in[2];
  const float* a_dst1 = (const float*)d_in[3];
  const float* b1     = (const float*)d_in[4];
  const float* W2     = (const float*)d_in[5];
  const float* a_src2 = (const float*)d_in[6];
  const float* a_dst2 = (const float*)d_in[7];
  const float* b2     = (const float*)d_in[8];
  const int*   ei     = (const int*)d_in[9];
  const int*   batch  = (const int*)d_in[10];

  char* ws = (char*)d_ws;
  size_t o = 0;
  auto alloc = [&](size_t bytes) {
    char* p = ws + o;
    o = (o + bytes + 255) & ~(size_t)255;
    return p;
  };
  ushort* xb   = (ushort*)alloc((size_t)N_NODES * 256 * 2);
  ushort* w1t  = (ushort*)alloc((size_t)272 * 256 * 2);
  ushort* w2tp = (ushort*)alloc((size_t)16 * 256 * 2);
  unsigned char* h1f8 = (unsigned char*)alloc((size_t)N_NODES * 256);
  ushort* h2b  = (ushort*)alloc((size_t)N_NODES * 256 * 2);
  float* as1   = (float*)alloc((size_t)N_NODES * 8 * 4);
  float* ad1   = (float*)alloc((size_t)N_NODES * 8 * 4);
  float* pj2p  = (float*)alloc((size_t)N_NODES * 16 * 4);
  float* as2   = (float*)alloc((size_t)N_NODES * 4);
  float* ad2   = (float*)alloc((size_t)N_NODES * 4);
  float* out2p = (float*)alloc((size_t)N_NODES * 16 * 4);
  int*   histg = (int*)alloc((size_t)NBKT * NB1 * 4);
  int*   tot   = (int*)alloc((size_t)NBKT * 4);
  int*   baseg = (int*)alloc((size_t)(NBKT + 1) * 4);
  unsigned int* cs = (unsigned int*)alloc((size_t)E_TOT * 4);
  int*   csr   = (int*)alloc((size_t)E_TOT * 4);
  int*   off   = (int*)alloc((size_t)(N_NODES + 1) * 4);

  prep_kernel<<<PREP_BLOCKS, 256, 0, stream>>>((const float4*)x, (ushort4*)xb,
                                               W1, w1t, W2, w2tp, a_src1, a_dst1,
                                               ei, histg);
  gemm1_mfma<<<GEMM_BLOCKS, 256, 0, stream>>>(xb, w1t, h1f8, as1, ad1);

  k_scan<<<NBKT, 256, 0, stream>>>(histg, tot);
  k_base<<<1, 256, 0, stream>>>(tot, baseg);
  k_place<<<NB1, 256, 0, stream>>>(ei, histg, baseg, cs);
  k_fine<<<NBKT, 256, 0, stream>>>(cs, baseg, csr, off);

  agg1_kernel<<<N_NODES / 4, 256, 0, stream>>>(h1f8, as1, ad1, off, csr, b1, h2b);
  proj2_mfma<<<GEMM_BLOCKS, 256, 0, stream>>>(h2b, w2tp, a_src2, a_dst2,
                                              pj2p, as2, ad2);
  agg2_kernel<<<N_NODES / 4, 256, 0, stream>>>(pj2p, as2, ad2, off, csr, b2, out2p);
  pool_kernel<<<NGRP, 256, 0, stream>>>(out2p, batch, (float*)d_out);
}

// Round 11
// 261.209 us; speedup vs baseline: 2.0837x; 1.0141x over previous
//
#include <hip/hip_runtime.h>
#include <hip/hip_bf16.h>
#include <math.h>

#define N_NODES 50000
#define N_EDGES 800000
#define E_TOT   (N_EDGES + N_NODES)   /* 850000 with self loops */
#define NCLS 10
#define NGRP 128

#define NBKT 196                       /* coarse buckets: dst>>8, dst<50000 */
#define EPB  1024                      /* edges per hist/place block */
#define NB1  ((E_TOT + EPB - 1) / EPB) /* 831 */

typedef __attribute__((ext_vector_type(8))) short bf16x8;
typedef __attribute__((ext_vector_type(4))) float f32x4;
typedef __attribute__((ext_vector_type(2))) float f32x2;

static __device__ __forceinline__ ushort f2bf(float f) {
  union { float f; unsigned u; } v; v.f = f;
  unsigned r = v.u + 0x7fffu + ((v.u >> 16) & 1u);   // round-to-nearest-even
  return (ushort)(r >> 16);
}
// hardware OCP e4m3 encode: 1 inst + extract
static __device__ __forceinline__ unsigned char enc8(float v) {
  int p = __builtin_amdgcn_cvt_pk_fp8_f32(v, v, 0, false);
  return (unsigned char)(p & 0xFF);
}
// hardware decode of 4 packed fp8 -> 4 floats, fma into acc (scalar adds:
// lower VGPR pressure than packed f32x2 — r10 showed occupancy > inst count)
static __device__ __forceinline__ void fma4(float w, unsigned u, float* a) {
  f32x2 lo = __builtin_amdgcn_cvt_pk_f32_fp8(u, false);
  f32x2 hi = __builtin_amdgcn_cvt_pk_f32_fp8(u, true);
  a[0] += w * lo[0]; a[1] += w * lo[1]; a[2] += w * hi[0]; a[3] += w * hi[1];
}

// ---------------------------------------------------------------------------
// prep: cast x -> bf16 (grid-stride) | W1 -> W1t bf16 rows [0,256) |
//       W2 -> W2tp bf16 [16][256] | Wa -> W1t rows [256,272) | edge histogram
// ---------------------------------------------------------------------------
#define CAST_BLOCKS 2048
#define NX4 (N_NODES * 64)            /* 3.2M float4 elements in x */
#define W1T_BASE CAST_BLOCKS
#define W2T_BASE (W1T_BASE + 64)
#define WA_BASE  (W2T_BASE + 1)
#define HIST_BASE (WA_BASE + 1)
#define PREP_BLOCKS (HIST_BASE + NB1)

__global__ __launch_bounds__(256) void prep_kernel(const float4* __restrict__ X4,
                                                   ushort4* __restrict__ Xb,
                                                   const float* __restrict__ W1,
                                                   ushort* __restrict__ W1t,
                                                   const float* __restrict__ W2,
                                                   ushort* __restrict__ W2tp,
                                                   const float* __restrict__ asrc1,
                                                   const float* __restrict__ adst1,
                                                   const int* __restrict__ ei,
                                                   int* __restrict__ histg) {
  int b = blockIdx.x;
  int tid = threadIdx.x;
  if (b < CAST_BLOCKS) {
    for (int i = b * 256 + tid; i < NX4; i += CAST_BLOCKS * 256) {
      float4 v = X4[i];
      ushort4 o;
      o.x = f2bf(v.x); o.y = f2bf(v.y); o.z = f2bf(v.z); o.w = f2bf(v.w);
      Xb[i] = o;
    }
  } else if (b < W2T_BASE) {
    __shared__ float t[32][33];
    int bb = b - W1T_BASE;
    int k0 = (bb >> 3) * 32, n0 = (bb & 7) * 32;
    int tx = tid & 31, ty = tid >> 5;  // ty 0..7
    for (int r = 0; r < 32; r += 8)
      t[ty + r][tx] = W1[(k0 + ty + r) * 256 + n0 + tx];
    __syncthreads();
    for (int r = 0; r < 32; r += 8)
      W1t[(n0 + ty + r) * 256 + k0 + tx] = f2bf(t[tx][ty + r]);
  } else if (b == W2T_BASE) {
    int k = tid;  // 0..255
#pragma unroll
    for (int c = 0; c < 16; ++c)
      W2tp[c * 256 + k] = (c < NCLS) ? f2bf(W2[k * NCLS + c]) : (ushort)0;
  } else if (b == WA_BASE) {
    int k = tid;  // 0..255
    const float* wrow = W1 + k * 256;
#pragma unroll
    for (int h = 0; h < 8; ++h) {
      float s = 0.f, d = 0.f;
#pragma unroll
      for (int c = 0; c < 32; ++c) {
        float w = wrow[h * 32 + c];
        s += w * asrc1[h * 32 + c];
        d += w * adst1[h * 32 + c];
      }
      W1t[(256 + h) * 256 + k] = f2bf(s);
      W1t[(264 + h) * 256 + k] = f2bf(d);
    }
  } else {
    // fused edge histogram (independent of prep outputs)
    __shared__ int h[NBKT];
    int bb = b - HIST_BASE;
    for (int j = tid; j < NBKT; j += 256) h[j] = 0;
    __syncthreads();
    int base = bb * EPB;
#pragma unroll
    for (int t = 0; t < 4; ++t) {
      int i = base + t * 256 + tid;
      if (i < E_TOT) {
        int d = (i < N_EDGES) ? ei[N_EDGES + i] : (i - N_EDGES);
        atomicAdd(&h[d >> 8], 1);
      }
    }
    __syncthreads();
    for (int j = tid; j < NBKT; j += 256) histg[j * NB1 + bb] = h[j];
  }
}

// ---------------------------------------------------------------------------
// per-bucket exclusive scan over the NB1 block counts (in place) + totals
// ---------------------------------------------------------------------------
__global__ __launch_bounds__(256) void k_scan(int* __restrict__ histg,
                                              int* __restrict__ tot) {
  __shared__ int sh[256];
  int b = blockIdx.x, tid = threadIdx.x;
  int carry = 0;
  for (int c = 0; c < (NB1 + 255) / 256; ++c) {
    int j = c * 256 + tid;
    int v = (j < NB1) ? histg[b * NB1 + j] : 0;
    sh[tid] = v;
    __syncthreads();
    for (int d = 1; d < 256; d <<= 1) {
      int t = (tid >= d) ? sh[tid - d] : 0;
      __syncthreads();
      sh[tid] += t;
      __syncthreads();
    }
    if (j < NB1) histg[b * NB1 + j] = carry + sh[tid] - v;  // exclusive
    carry += sh[255];
    __syncthreads();
  }
  if (tid == 0) tot[b] = carry;
}

// ---------------------------------------------------------------------------
// FUSED: blocks [0, GEMM_BLOCKS) = GEMM1 MFMA (h1 fp8 + as1/ad1)
//        blocks [GEMM_BLOCKS, +NB1) = k_place (coarse-sorted edge array)
// Disjoint resources (MFMA/LDS vs memory/line traffic) -> real overlap,
// unlike the r6 atomic-bound scatter fusion (which conserved machine time).
// Place blocks re-derive bucket bases from tot[] via an LDS scan (k_base gone).
// ---------------------------------------------------------------------------
#define GEMM_BLOCKS ((N_NODES + 63) / 64)
#define GP_BLOCKS (GEMM_BLOCKS + NB1)

__global__ __launch_bounds__(256) void gemm_place(const ushort* __restrict__ Xb,
                                                  const ushort* __restrict__ W1t,
                                                  unsigned char* __restrict__ h1f8,
                                                  float* __restrict__ as1,
                                                  float* __restrict__ ad1,
                                                  const int* __restrict__ ei,
                                                  const int* __restrict__ histg,
                                                  const int* __restrict__ tot,
                                                  unsigned int* __restrict__ cs) {
  __shared__ ushort As[32][64][8];   // 32 KB (gemm); aliased by place path
  int tid = threadIdx.x;

  if (blockIdx.x >= GEMM_BLOCKS) {
    // ---------------- place path ----------------
    int bb = blockIdx.x - GEMM_BLOCKS;
    int* L = (int*)As;
    int* h     = L;         // [256]
    int* basec = L + 256;   // [256]
    int* sh    = L + 512;   // [256]
    int tv = (tid < NBKT) ? tot[tid] : 0;
    sh[tid] = tv;
    __syncthreads();
    for (int d = 1; d < 256; d <<= 1) {
      int t = (tid >= d) ? sh[tid - d] : 0;
      __syncthreads();
      sh[tid] += t;
      __syncthreads();
    }
    if (tid < NBKT) {
      basec[tid] = (sh[tid] - tv) + histg[tid * NB1 + bb];
      h[tid] = 0;
    }
    __syncthreads();
    int base = bb * EPB;
#pragma unroll
    for (int t = 0; t < 4; ++t) {
      int i = base + t * 256 + tid;
      if (i < E_TOT) {
        int s = (i < N_EDGES) ? ei[i] : (i - N_EDGES);
        int d = (i < N_EDGES) ? ei[N_EDGES + i] : (i - N_EDGES);
        int bk = d >> 8;
        int r = atomicAdd(&h[bk], 1);
        cs[basec[bk] + r] = ((unsigned)d << 16) | (unsigned)s;
      }
    }
    return;
  }

  // ---------------- gemm path ----------------
  int wid = tid >> 6, lane = tid & 63;
  int r = lane & 15, kg = lane >> 4;
  int m0 = blockIdx.x * 64;
  int n0 = wid * 64;
  bool extra = (wid == 3);

  // cooperative A staging: wave w stages the 8 k-tiles of mi = w
  {
    int mi = wid;
    int row = m0 + mi * 16 + r;
    if (row >= N_NODES) row = 0;
    const ushort* src = Xb + (size_t)row * 256 + kg * 8;
    bf16x8 v0 = *reinterpret_cast<const bf16x8*>(src);
    bf16x8 v1 = *reinterpret_cast<const bf16x8*>(src + 32);
    bf16x8 v2 = *reinterpret_cast<const bf16x8*>(src + 64);
    bf16x8 v3 = *reinterpret_cast<const bf16x8*>(src + 96);
    bf16x8 v4 = *reinterpret_cast<const bf16x8*>(src + 128);
    bf16x8 v5 = *reinterpret_cast<const bf16x8*>(src + 160);
    bf16x8 v6 = *reinterpret_cast<const bf16x8*>(src + 192);
    bf16x8 v7 = *reinterpret_cast<const bf16x8*>(src + 224);
    *reinterpret_cast<bf16x8*>(&As[mi * 8 + 0][lane][0]) = v0;
    *reinterpret_cast<bf16x8*>(&As[mi * 8 + 1][lane][0]) = v1;
    *reinterpret_cast<bf16x8*>(&As[mi * 8 + 2][lane][0]) = v2;
    *reinterpret_cast<bf16x8*>(&As[mi * 8 + 3][lane][0]) = v3;
    *reinterpret_cast<bf16x8*>(&As[mi * 8 + 4][lane][0]) = v4;
    *reinterpret_cast<bf16x8*>(&As[mi * 8 + 5][lane][0]) = v5;
    *reinterpret_cast<bf16x8*>(&As[mi * 8 + 6][lane][0]) = v6;
    *reinterpret_cast<bf16x8*>(&As[mi * 8 + 7][lane][0]) = v7;
  }
  __syncthreads();

  f32x4 acc[4][4];
  f32x4 accE[4];
#pragma unroll
  for (int mi = 0; mi < 4; ++mi) {
#pragma unroll
    for (int ni = 0; ni < 4; ++ni) acc[mi][ni] = 0;
    accE[mi] = 0;
  }

  const ushort* bptr[4];
#pragma unroll
  for (int ni = 0; ni < 4; ++ni)
    bptr[ni] = W1t + (size_t)(n0 + ni * 16 + r) * 256 + kg * 8;
  const ushort* bptrE = W1t + (size_t)(256 + r) * 256 + kg * 8;

#pragma unroll 2
  for (int ks = 0; ks < 8; ++ks) {
    int k0 = ks * 32;
    bf16x8 a[4], b[4], bE;
#pragma unroll
    for (int ni = 0; ni < 4; ++ni)
      b[ni] = *reinterpret_cast<const bf16x8*>(bptr[ni] + k0);
    if (extra) bE = *reinterpret_cast<const bf16x8*>(bptrE + k0);
#pragma unroll
    for (int mi = 0; mi < 4; ++mi)
      a[mi] = *reinterpret_cast<const bf16x8*>(&As[mi * 8 + ks][lane][0]);
#pragma unroll
    for (int mi = 0; mi < 4; ++mi) {
#pragma unroll
      for (int ni = 0; ni < 4; ++ni)
        acc[mi][ni] = __builtin_amdgcn_mfma_f32_16x16x32_bf16(a[mi], b[ni], acc[mi][ni], 0, 0, 0);
      if (extra)
        accE[mi] = __builtin_amdgcn_mfma_f32_16x16x32_bf16(a[mi], bE, accE[mi], 0, 0, 0);
    }
  }

#pragma unroll
  for (int mi = 0; mi < 4; ++mi) {
#pragma unroll
    for (int q = 0; q < 4; ++q) {
      int row = m0 + mi * 16 + kg * 4 + q;
      if (row < N_NODES) {
#pragma unroll
        for (int ni = 0; ni < 4; ++ni)
          h1f8[(size_t)row * 256 + n0 + ni * 16 + r] = enc8(acc[mi][ni][q]);
        if (extra) {
          float* dst = (r < 8) ? (as1 + row * 8 + r) : (ad1 + row * 8 + (r & 7));
          *dst = accE[mi][q];
        }
      }
    }
  }
}

// ---------------------------------------------------------------------------
// fine pass: one block per coarse bucket; derives baseg locally from tot[];
// emits off[] and csr[] (csr = src*256)
// ---------------------------------------------------------------------------
__global__ __launch_bounds__(256) void k_fine(const unsigned int* __restrict__ cs,
                                              const int* __restrict__ tot,
                                              int* __restrict__ csr,
                                              int* __restrict__ off) {
  __shared__ int cnt[256];
  __shared__ int sh[256];
  __shared__ int scn[256];
  __shared__ int cur[256];
  int b = blockIdx.x, tid = threadIdx.x;

  // derive this bucket's [lo, hi) from a scan of tot
  int tv = (tid < NBKT) ? tot[tid] : 0;
  sh[tid] = tv;
  __syncthreads();
  for (int d = 1; d < 256; d <<= 1) {
    int t = (tid >= d) ? sh[tid - d] : 0;
    __syncthreads();
    sh[tid] += t;
    __syncthreads();
  }
  int hi = sh[b];             // inclusive prefix at b
  int lo = hi - tot[b];
  __syncthreads();

  cnt[tid] = 0;
  cur[tid] = 0;
  __syncthreads();
  for (int i = lo + tid; i < hi; i += 256) atomicAdd(&cnt[(cs[i] >> 16) & 255], 1);
  __syncthreads();
  int v = cnt[tid];
  sh[tid] = v;
  __syncthreads();
  for (int d = 1; d < 256; d <<= 1) {
    int t = (tid >= d) ? sh[tid - d] : 0;
    __syncthreads();
    sh[tid] += t;
    __syncthreads();
  }
  scn[tid] = sh[tid] - v;  // exclusive scan of dst-low-byte counts
  int idx = b * 256 + tid;
  if (idx <= N_NODES) off[idx] = lo + scn[tid];
  __syncthreads();
  for (int i = lo + tid; i < hi; i += 256) {
    unsigned e = cs[i];
    int dl = (e >> 16) & 255;
    int r = atomicAdd(&cur[dl], 1);
    csr[lo + scn[dl] + r] = (int)((e & 0xFFFFu) << 8);   // src*256
  }
}

// ---------------------------------------------------------------------------
// layer-1 aggregation + bias + elu -> h2 (bf16). h1 gathered as FP8 e4m3,
// HW cvt, scalar f32 acc (28 VGPR — occupancy beats packed math, r10 lesson).
// csr holds src*256 (as1 idx = v>>5). 4 edge slots x 16 ch lanes, 2-unroll.
// ---------------------------------------------------------------------------
__global__ __launch_bounds__(256) void agg1_kernel(const unsigned char* __restrict__ h1f8,
                                                   const float* __restrict__ as1,
                                                   const float* __restrict__ ad1,
                                                   const int* __restrict__ off,
                                                   const int* __restrict__ csr,
                                                   const float* __restrict__ b1,
                                                   ushort* __restrict__ h2b) {
  int n = (blockIdx.x * 256 + threadIdx.x) >> 6;
  int lane = threadIdx.x & 63;
  int p0 = off[n], p1 = off[n + 1];

  int sl = lane >> 4;          // edge slot 0..3
  int cl = lane & 15;          // channel group
  int cb = cl * 16;            // channel base (16 channels per lane)
  int h = cl >> 1;             // head = channel/32
  float ad = ad1[n * 8 + h];

  float ssum = 0.f;
  float acc[16] = {};

  int p = p0 + sl;
  for (; p + 4 < p1; p += 8) {
    int vA = csr[p], vB = csr[p + 4];          // src*256
    float eA = as1[(vA >> 5) + h] + ad;
    float eB = as1[(vB >> 5) + h] + ad;
    uint4 rA = *reinterpret_cast<const uint4*>(h1f8 + vA + cb);
    uint4 rB = *reinterpret_cast<const uint4*>(h1f8 + vB + cb);
    eA = eA > 0.f ? eA : 0.2f * eA;
    eB = eB > 0.f ? eB : 0.2f * eB;
    float wA = __expf(eA), wB = __expf(eB);
    ssum += wA + wB;
    fma4(wA, rA.x, acc);      fma4(wB, rB.x, acc);
    fma4(wA, rA.y, acc + 4);  fma4(wB, rB.y, acc + 4);
    fma4(wA, rA.z, acc + 8);  fma4(wB, rB.z, acc + 8);
    fma4(wA, rA.w, acc + 12); fma4(wB, rB.w, acc + 12);
  }
  for (; p < p1; p += 4) {
    int vA = csr[p];
    float eA = as1[(vA >> 5) + h] + ad;
    uint4 rA = *reinterpret_cast<const uint4*>(h1f8 + vA + cb);
    eA = eA > 0.f ? eA : 0.2f * eA;
    float wA = __expf(eA);
    ssum += wA;
    fma4(wA, rA.x, acc);
    fma4(wA, rA.y, acc + 4);
    fma4(wA, rA.z, acc + 8);
    fma4(wA, rA.w, acc + 12);
  }

  // reduce across the 4 edge slots
  ssum += __shfl_xor(ssum, 16); ssum += __shfl_xor(ssum, 32);
#pragma unroll
  for (int c = 0; c < 16; ++c) {
    acc[c] += __shfl_xor(acc[c], 16);
    acc[c] += __shfl_xor(acc[c], 32);
  }

  if (sl == 0) {
    float inv = 1.f / ssum;
    float o[16];
    float4 b0 = *reinterpret_cast<const float4*>(b1 + cb);
    float4 b1v = *reinterpret_cast<const float4*>(b1 + cb + 4);
    float4 b2v = *reinterpret_cast<const float4*>(b1 + cb + 8);
    float4 b3v = *reinterpret_cast<const float4*>(b1 + cb + 12);
    float bb[16] = {b0.x, b0.y, b0.z, b0.w, b1v.x, b1v.y, b1v.z, b1v.w,
                    b2v.x, b2v.y, b2v.z, b2v.w, b3v.x, b3v.y, b3v.z, b3v.w};
#pragma unroll
    for (int c = 0; c < 16; ++c) {
      float v = acc[c] * inv + bb[c];
      o[c] = v > 0.f ? v : __expf(v) - 1.f;
    }
    int4 o0, o1;
    o0.x = (int)(((unsigned)f2bf(o[1]) << 16) | f2bf(o[0]));
    o0.y = (int)(((unsigned)f2bf(o[3]) << 16) | f2bf(o[2]));
    o0.z = (int)(((unsigned)f2bf(o[5]) << 16) | f2bf(o[4]));
    o0.w = (int)(((unsigned)f2bf(o[7]) << 16) | f2bf(o[6]));
    o1.x = (int)(((unsigned)f2bf(o[9]) << 16) | f2bf(o[8]));
    o1.y = (int)(((unsigned)f2bf(o[11]) << 16) | f2bf(o[10]));
    o1.z = (int)(((unsigned)f2bf(o[13]) << 16) | f2bf(o[12]));
    o1.w = (int)(((unsigned)f2bf(o[15]) << 16) | f2bf(o[14]));
    *reinterpret_cast<int4*>(h2b + (size_t)n * 256 + cb) = o0;
    *reinterpret_cast<int4*>(h2b + (size_t)n * 256 + cb + 8) = o1;
  }
}

// ---------------------------------------------------------------------------
// layer-2 projection via MFMA: pj2p[50000][16] = h2 @ W2tp^T, + as2/ad2
// ---------------------------------------------------------------------------
__global__ __launch_bounds__(256) void proj2_mfma(const ushort* __restrict__ h2b,
                                                  const ushort* __restrict__ W2tp,
                                                  const float* __restrict__ asrc2,
                                                  const float* __restrict__ adst2,
                                                  float* __restrict__ pj2p,
                                                  float* __restrict__ as2,
                                                  float* __restrict__ ad2) {
  int wid = threadIdx.x >> 6, lane = threadIdx.x & 63;
  int r = lane & 15, kg = lane >> 4;
  int rb = blockIdx.x * 64 + wid * 16;
  int row_a = rb + r;
  if (row_a >= N_NODES) row_a = 0;
  const ushort* ap = h2b + (size_t)row_a * 256 + kg * 8;
  const ushort* bp = W2tp + (size_t)r * 256 + kg * 8;
  f32x4 acc = 0;
#pragma unroll
  for (int k0 = 0; k0 < 256; k0 += 32)
    acc = __builtin_amdgcn_mfma_f32_16x16x32_bf16(
        *reinterpret_cast<const bf16x8*>(ap + k0),
        *reinterpret_cast<const bf16x8*>(bp + k0), acc, 0, 0, 0);

  float av = (r < NCLS) ? asrc2[r] : 0.f;
  float dv = (r < NCLS) ? adst2[r] : 0.f;
#pragma unroll
  for (int q = 0; q < 4; ++q) {
    int row = rb + kg * 4 + q;
    float v = acc[q];
    if (row < N_NODES) pj2p[row * 16 + r] = v;
    float s = v * av, d = v * dv;
    s += __shfl_xor(s, 1); s += __shfl_xor(s, 2); s += __shfl_xor(s, 4); s += __shfl_xor(s, 8);
    d += __shfl_xor(d, 1); d += __shfl_xor(d, 2); d += __shfl_xor(d, 4); d += __shfl_xor(d, 8);
    if (r == 0 && row < N_NODES) { as2[row] = s; ad2[row] = d; }
  }
}

// ---------------------------------------------------------------------------
// layer-2 aggregation: single pass, 4 edge slots x 16 channel lanes, 4-deep.
// csr holds src*256: as2 idx = v>>8, pj2p idx = (v>>4)+c.
// ---------------------------------------------------------------------------
__global__ __launch_bounds__(256) void agg2_kernel(const float* __restrict__ pj2p,
                                                   const float* __restrict__ as2,
                                                   const float* __restrict__ ad2,
                                                   const int* __restrict__ off,
                                                   const int* __restrict__ csr,
                                                   const float* __restrict__ b2,
                                                   float* __restrict__ out2p) {
  int n = (blockIdx.x * 256 + threadIdx.x) >> 6;
  int lane = threadIdx.x & 63;
  int p0 = off[n], p1 = off[n + 1];
  float ad = ad2[n];
  int es = lane >> 4, c = lane & 15;
  float ssum = 0.f, acc = 0.f;
  int p = p0 + es;
  for (; p + 12 < p1; p += 16) {
    int v0 = csr[p], v1 = csr[p + 4], v2 = csr[p + 8], v3 = csr[p + 12];
    float e0 = as2[v0 >> 8] + ad, e1 = as2[v1 >> 8] + ad;
    float e2 = as2[v2 >> 8] + ad, e3 = as2[v3 >> 8] + ad;
    float q0 = pj2p[(v0 >> 4) + c], q1 = pj2p[(v1 >> 4) + c];
    float q2 = pj2p[(v2 >> 4) + c], q3 = pj2p[(v3 >> 4) + c];
    e0 = e0 > 0.f ? e0 : 0.2f * e0;
    e1 = e1 > 0.f ? e1 : 0.2f * e1;
    e2 = e2 > 0.f ? e2 : 0.2f * e2;
    e3 = e3 > 0.f ? e3 : 0.2f * e3;
    float w0 = __expf(e0), w1 = __expf(e1), w2 = __expf(e2), w3 = __expf(e3);
    ssum += (w0 + w1) + (w2 + w3);
    acc += (w0 * q0 + w1 * q1) + (w2 * q2 + w3 * q3);
  }
  for (; p < p1; p += 4) {
    int vA = csr[p];
    float eA = as2[vA >> 8] + ad;
    float qA = pj2p[(vA >> 4) + c];
    eA = eA > 0.f ? eA : 0.2f * eA;
    float wA = __expf(eA);
    ssum += wA;
    acc += wA * qA;
  }
  acc += __shfl_xor(acc, 16); acc += __shfl_xor(acc, 32);
  ssum += __shfl_xor(ssum, 16); ssum += __shfl_xor(ssum, 32);
  if (lane < 16) {
    float bc = (lane < NCLS) ? b2[lane] : 0.f;
    out2p[n * 16 + lane] = acc / ssum + bc;
  }
}

// ---------------------------------------------------------------------------
// global mean pool
// ---------------------------------------------------------------------------
__global__ __launch_bounds__(256) void pool_kernel(const float* __restrict__ out2p,
                                                   const int* __restrict__ batch,
                                                   float* __restrict__ outp) {
  __shared__ float red[256];
  int g = blockIdx.x;
  int lo = 0, hi = N_NODES;
  while (lo < hi) { int mid = (lo + hi) >> 1; if (batch[mid] < g) lo = mid + 1; else hi = mid; }
  int start = lo;
  hi = N_NODES;
  while (lo < hi) { int mid = (lo + hi) >> 1; if (batch[mid] < g + 1) lo = mid + 1; else hi = mid; }
  int end = lo;
  int t = threadIdx.x;
  int c = t & 15, nsl = t >> 4;
  float loc = 0.f;
  for (int nn = start + nsl; nn < end; nn += 16) loc += out2p[nn * 16 + c];
  red[t] = loc;
  __syncthreads();
  for (int s = 128; s >= 16; s >>= 1) {
    if (t < s) red[t] += red[t + s];
    __syncthreads();
  }
  if (t < NCLS) {
    float denom = fmaxf((float)(end - start), 1.f);
    outp[g * NCLS + t] = red[t] / denom;
  }
}

// ---------------------------------------------------------------------------
extern "C" void kernel_launch(void* const* d_in, const int* in_sizes, int n_in,
                              void* d_out, int out_size, void* d_ws, size_t ws_size,
                              hipStream_t stream) {
  const float* x      = (const float*)d_in[0];
  const float* W1     = (const float*)d_in[1];
  const float* a_src1 = (const float*)d_in[2];
  const float* a_dst1 = (const float*)d_in[3];
  const float* b1     = (const float*)d_in[4];
  const float* W2     = (const float*)d_in[5];
  const float* a_src2 = (const float*)d_in[6];
  const float* a_dst2 = (const float*)d_in[7];
  const float* b2     = (const float*)d_in[8];
  const int*   ei     = (const int*)d_in[9];
  const int*   batch  = (const int*)d_in[10];

  char* ws = (char*)d_ws;
  size_t o = 0;
  auto alloc = [&](size_t bytes) {
    char* p = ws + o;
    o = (o + bytes + 255) & ~(size_t)255;
    return p;
  };
  ushort* xb   = (ushort*)alloc((size_t)N_NODES * 256 * 2);
  ushort* w1t  = (ushort*)alloc((size_t)272 * 256 * 2);
  ushort* w2tp = (ushort*)alloc((size_t)16 * 256 * 2);
  unsigned char* h1f8 = (unsigned char*)alloc((size_t)N_NODES * 256);
  ushort* h2b  = (ushort*)alloc((size_t)N_NODES * 256 * 2);
  float* as1   = (float*)alloc((size_t)N_NODES * 8 * 4);
  float* ad1   = (float*)alloc((size_t)N_NODES * 8 * 4);
  float* pj2p  = (float*)alloc((size_t)N_NODES * 16 * 4);
  float* as2   = (float*)alloc((size_t)N_NODES * 4);
  float* ad2   = (float*)alloc((size_t)N_NODES * 4);
  float* out2p = (float*)alloc((size_t)N_NODES * 16 * 4);
  int*   histg = (int*)alloc((size_t)NBKT * NB1 * 4);
  int*   tot   = (int*)alloc((size_t)NBKT * 4);
  unsigned int* cs = (unsigned int*)alloc((size_t)E_TOT * 4);
  int*   csr   = (int*)alloc((size_t)E_TOT * 4);
  int*   off   = (int*)alloc((size_t)(N_NODES + 1) * 4);

  prep_kernel<<<PREP_BLOCKS, 256, 0, stream>>>((const float4*)x, (ushort4*)xb,
                                               W1, w1t, W2, w2tp, a_src1, a_dst1,
                                               ei, histg);
  k_scan<<<NBKT, 256, 0, stream>>>(histg, tot);
  gemm_place<<<GP_BLOCKS, 256, 0, stream>>>(xb, w1t, h1f8, as1, ad1,
                                            ei, histg, tot, cs);
  k_fine<<<NBKT, 256, 0, stream>>>(cs, tot, csr, off);

  agg1_kernel<<<N_NODES / 4, 256, 0, stream>>>(h1f8, as1, ad1, off, csr, b1, h2b);
  proj2_mfma<<<GEMM_BLOCKS, 256, 0, stream>>>(h2b, w2tp, a_src2, a_dst2,
                                              pj2p, as2, ad2);
  agg2_kernel<<<N_NODES / 4, 256, 0, stream>>>(pj2p, as2, ad2, off, csr, b2, out2p);
  pool_kernel<<<NGRP, 256, 0, stream>>>(out2p, batch, (float*)d_out);
}